// Round 1
// baseline (5708.849 us; speedup 1.0000x reference)
//
#include <hip/hip_runtime.h>
#include <hip/hip_bf16.h>
#include <math.h>

#define BATCH 32
#define SEQL  512
#define TT    511          // T = L-1
#define DMODEL 256
#define DIN   512          // DI = EXP*D
#define DSN   16           // DS
#define NSK   500
#define NTOK  (BATCH*TT)   // 16352

// ---------------------------------------------------------------- embeddings
__global__ __launch_bounds__(256) void embed_kernel(
    const int* __restrict__ skills, const int* __restrict__ responses,
    const float* __restrict__ embC, const float* __restrict__ embA,
    const float* __restrict__ embT, const float* __restrict__ embF,
    float* __restrict__ o_state, float* __restrict__ o_st, float* __restrict__ o_sf)
{
    int idx = blockIdx.x * 256 + threadIdx.x;      // < NTOK*256
    int n = idx >> 8, j = idx & 255;
    int b = n / TT, t = n % TT;
    int c = skills[b * SEQL + t];
    int r = responses[b * SEQL + t];
    r = (r > -1) ? r : 0;                          // masked_r
    o_state[idx] = embA[r * DMODEL + j] + embC[c * DMODEL + j];
    o_st[idx]    = embT[(r * (c + NSK)) * DMODEL + j];
    o_sf[idx]    = embF[(c * (1 - r)) * DMODEL + j];
}

// ---------------------------------------------------------------- generic GEMM
// C[M,N] = act(A[M,K](lda) @ W[N,K]^T + bias[N]);  K%16==0, N%4==0
template<int ACT>   // 0 none, 1 tanh, 2 softplus, 3 gelu(exact)
__global__ __launch_bounds__(256) void gemm_kernel(
    const float* __restrict__ A, int lda,
    const float* __restrict__ W,
    const float* __restrict__ bias,
    float* __restrict__ C, int ldc,
    int M, int N, int K)
{
    __shared__ float As[64][17];
    __shared__ float Ws[64][17];
    const int tx = threadIdx.x;
    const int rowBase = blockIdx.y * 64;
    const int colBase = blockIdx.x * 64;
    const int lr = tx >> 2;
    const int lk = (tx & 3) << 2;
    const int tr = (tx >> 4) << 2;
    const int tc = (tx & 15) << 2;
    float acc[4][4] = {};

    for (int k0 = 0; k0 < K; k0 += 16) {
        float4 av = make_float4(0.f, 0.f, 0.f, 0.f);
        int ar = rowBase + lr;
        if (ar < M) av = *reinterpret_cast<const float4*>(A + (size_t)ar * lda + k0 + lk);
        As[lr][lk] = av.x; As[lr][lk + 1] = av.y; As[lr][lk + 2] = av.z; As[lr][lk + 3] = av.w;
        float4 wv = make_float4(0.f, 0.f, 0.f, 0.f);
        int wr = colBase + lr;
        if (wr < N) wv = *reinterpret_cast<const float4*>(W + (size_t)wr * K + k0 + lk);
        Ws[lr][lk] = wv.x; Ws[lr][lk + 1] = wv.y; Ws[lr][lk + 2] = wv.z; Ws[lr][lk + 3] = wv.w;
        __syncthreads();
        #pragma unroll
        for (int k = 0; k < 16; ++k) {
            float a0 = As[tr][k], a1 = As[tr + 1][k], a2 = As[tr + 2][k], a3 = As[tr + 3][k];
            float b0 = Ws[tc][k], b1 = Ws[tc + 1][k], b2 = Ws[tc + 2][k], b3 = Ws[tc + 3][k];
            acc[0][0] += a0 * b0; acc[0][1] += a0 * b1; acc[0][2] += a0 * b2; acc[0][3] += a0 * b3;
            acc[1][0] += a1 * b0; acc[1][1] += a1 * b1; acc[1][2] += a1 * b2; acc[1][3] += a1 * b3;
            acc[2][0] += a2 * b0; acc[2][1] += a2 * b1; acc[2][2] += a2 * b2; acc[2][3] += a2 * b3;
            acc[3][0] += a3 * b0; acc[3][1] += a3 * b1; acc[3][2] += a3 * b2; acc[3][3] += a3 * b3;
        }
        __syncthreads();
    }

    #pragma unroll
    for (int i = 0; i < 4; ++i) {
        int r = rowBase + tr + i;
        if (r >= M) break;
        int cb = colBase + tc;
        if (cb >= N) continue;                 // N%4==0 -> whole float4 in/out
        float4 v;
        float* vp = &v.x;
        #pragma unroll
        for (int j = 0; j < 4; ++j) {
            float x = acc[i][j];
            if (bias) x += bias[cb + j];
            if (ACT == 1) x = tanhf(x);
            else if (ACT == 2) x = fmaxf(x, 0.f) + log1pf(expf(-fabsf(x)));              // softplus
            else if (ACT == 3) x = 0.5f * x * (1.f + erff(x * 0.70710678118654752440f)); // gelu exact
            vp[j] = x;
        }
        *reinterpret_cast<float4*>(C + (size_t)r * ldc + cb) = v;
    }
}

// ---------------------------------------------------------------- conv1d(4, causal, depthwise) + silu
__global__ __launch_bounds__(256) void conv_silu_kernel(
    const float* __restrict__ xz,   // (NTOK,1024), xc part = cols 0..511
    const float* __restrict__ cW,   // (512,4)
    const float* __restrict__ cb,   // (512)
    float* __restrict__ xc)         // (NTOK,512)
{
    int idx = blockIdx.x * 256 + threadIdx.x;     // < NTOK*512
    int d = idx & 511;
    int n = idx >> 9;
    int b = n / TT, t = n % TT;
    float w0 = cW[d * 4], w1 = cW[d * 4 + 1], w2 = cW[d * 4 + 2], w3 = cW[d * 4 + 3];
    const float* base = xz + (size_t)(b * TT) * 1024 + d;
    float acc = cb[d];
    if (t >= 3) acc += w0 * base[(size_t)(t - 3) * 1024];
    if (t >= 2) acc += w1 * base[(size_t)(t - 2) * 1024];
    if (t >= 1) acc += w2 * base[(size_t)(t - 1) * 1024];
    acc += w3 * base[(size_t)t * 1024];
    xc[idx] = acc / (1.f + expf(-acc));           // silu
}

// ---------------------------------------------------------------- selective scan (+ fused D-term and silu(z) gate)
__global__ __launch_bounds__(256) void scan_kernel(
    float* __restrict__ dt_ym,        // (NTOK,512) in: dt, out: ym (in-place)
    const float* __restrict__ xc,     // (NTOK,512)
    const float* __restrict__ xdbl,   // (NTOK,48): [dtr(16) | B(16) | C(16)]
    const float* __restrict__ xz,     // (NTOK,1024): z = cols 512..1023
    const float* __restrict__ Alog,   // (512,16)
    const float* __restrict__ Dpv)    // (512)
{
    int idx = blockIdx.x * 256 + threadIdx.x;   // 0..16383
    int d = idx & 511;
    int b = idx >> 9;
    float A[DSN], h[DSN];
    #pragma unroll
    for (int s = 0; s < DSN; ++s) { A[s] = -expf(Alog[d * DSN + s]); h[s] = 0.f; }
    float Dv = Dpv[d];
    for (int t = 0; t < TT; ++t) {
        size_t n = (size_t)b * TT + t;
        float dtt = dt_ym[n * 512 + d];
        float xt  = xc[n * 512 + d];
        float zz  = xz[n * 1024 + 512 + d];
        const float* br = xdbl + n * 48;
        float dx = dtt * xt;
        float y = 0.f;
        #pragma unroll
        for (int s = 0; s < DSN; ++s) {
            h[s] = expf(dtt * A[s]) * h[s] + dx * br[16 + s];
            y += h[s] * br[32 + s];
        }
        float ym = (y + xt * Dv) * (zz / (1.f + expf(-zz)));
        dt_ym[n * 512 + d] = ym;
    }
}

// ---------------------------------------------------------------- rmsnorm(a+b)*w
__global__ __launch_bounds__(256) void rmsnorm_kernel(
    const float* __restrict__ a, const float* __restrict__ b,
    const float* __restrict__ w, float* __restrict__ out)
{
    __shared__ float red[256];
    int n = blockIdx.x, j = threadIdx.x;
    float v = a[(size_t)n * 256 + j] + b[(size_t)n * 256 + j];
    red[j] = v * v;
    __syncthreads();
    for (int s = 128; s > 0; s >>= 1) { if (j < s) red[j] += red[j + s]; __syncthreads(); }
    float scale = rsqrtf(red[0] / 256.0f + 1e-12f);
    out[(size_t)n * 256 + j] = v * scale * w[j];
}

// ---------------------------------------------------------------- copy y into ycin[:, 0:256] (stride 768)
__global__ __launch_bounds__(256) void copy_ycin_kernel(
    const float* __restrict__ y, float* __restrict__ ycin)
{
    int idx = blockIdx.x * 256 + threadIdx.x;
    int n = idx >> 8, j = idx & 255;
    ycin[(size_t)n * 768 + j] = y[idx];
}

// ---------------------------------------------------------------- dual attention, one block per (b,h,q)
__global__ __launch_bounds__(256) void attn_kernel(
    const float* __restrict__ y,    // (B,TT,256) q = k
    const float* __restrict__ st,   // v1
    const float* __restrict__ sf,   // v2
    float* __restrict__ ycin)       // (B,TT,768), writes cols 256..767
{
    __shared__ float sc[TT];
    __shared__ float qv[32];
    __shared__ float red[256];
    __shared__ float part[4][64];
    int bid = blockIdx.x;
    int q = bid % TT;
    int bh = bid / TT;
    int h = bh & 7;
    int b = bh >> 3;
    int tx = threadIdx.x;
    const float* ybase = y + (size_t)(b * TT) * 256 + h * 32;
    if (tx < 32) qv[tx] = ybase[(size_t)q * 256 + tx];
    __syncthreads();
    const float scale = 0.17677669529663687f;   // 1/sqrt(32)
    for (int k = tx; k < TT; k += 256) {
        const float* krow = ybase + (size_t)k * 256;
        float s = 0.f;
        #pragma unroll
        for (int j = 0; j < 32; ++j) s += qv[j] * krow[j];
        sc[k] = (k < q) ? s * scale : -1e9f;
    }
    __syncthreads();
    // row max
    float m = -INFINITY;
    for (int k = tx; k < TT; k += 256) m = fmaxf(m, sc[k]);
    red[tx] = m; __syncthreads();
    for (int s = 128; s > 0; s >>= 1) { if (tx < s) red[tx] = fmaxf(red[tx], red[tx + s]); __syncthreads(); }
    m = red[0];
    __syncthreads();
    // exp + sum
    float sum = 0.f;
    for (int k = tx; k < TT; k += 256) { float e = expf(sc[k] - m); sc[k] = e; sum += e; }
    red[tx] = sum; __syncthreads();
    for (int s = 128; s > 0; s >>= 1) { if (tx < s) red[tx] += red[tx + s]; __syncthreads(); }
    float inv = 1.0f / red[0];
    __syncthreads();
    // PV: 64 output dims (o1:0..31 -> v1, o2:32..63 -> v2), 4 k-chunks
    int dim = tx & 63;
    int chunk = tx >> 6;
    int d0 = dim & 31;
    const float* v = (dim < 32) ? st : sf;
    const float* vbase = v + (size_t)(b * TT) * 256 + h * 32 + d0;
    int k0 = chunk * 128;
    int k1 = (chunk == 3) ? TT : (k0 + 128);
    float p = 0.f;
    for (int k = k0; k < k1; ++k) p += sc[k] * vbase[(size_t)k * 256];
    part[chunk][dim] = p;
    __syncthreads();
    if (tx < 64) {
        float o = (part[0][tx] + part[1][tx] + part[2][tx] + part[3][tx]) * inv;
        int col = (tx < 32) ? (256 + h * 32 + tx) : (512 + h * 32 + (tx - 32));
        ycin[(size_t)(b * TT + q) * 768 + col] = o;
    }
}

// ---------------------------------------------------------------- gathered logit + sigmoid
__global__ __launch_bounds__(256) void pred_kernel(
    const float* __restrict__ yc,     // (NTOK,256)
    const int* __restrict__ skills,
    const float* __restrict__ outW,   // (500,256)
    const float* __restrict__ outB,   // (500)
    float* __restrict__ out)          // (NTOK)
{
    int n = blockIdx.x * 4 + (threadIdx.x >> 6);
    if (n >= NTOK) return;
    int lane = threadIdx.x & 63;
    int b = n / TT, t = n % TT;
    int c = skills[b * SEQL + t + 1];            // cshft
    const float* wrow = outW + (size_t)c * 256;
    const float* xrow = yc + (size_t)n * 256;
    float s = 0.f;
    for (int j = lane; j < 256; j += 64) s += xrow[j] * wrow[j];
    #pragma unroll
    for (int off = 32; off > 0; off >>= 1) s += __shfl_down(s, off);
    if (lane == 0) out[n] = 1.0f / (1.0f + expf(-(s + outB[c])));
}

// ---------------------------------------------------------------- host
static inline void gemm(const float* A, int lda, const float* W, const float* bias,
                        float* C, int ldc, int M, int N, int K, int act, hipStream_t s)
{
    dim3 g((N + 63) / 64, (M + 63) / 64), b(256);
    switch (act) {
        case 0: gemm_kernel<0><<<g, b, 0, s>>>(A, lda, W, bias, C, ldc, M, N, K); break;
        case 1: gemm_kernel<1><<<g, b, 0, s>>>(A, lda, W, bias, C, ldc, M, N, K); break;
        case 2: gemm_kernel<2><<<g, b, 0, s>>>(A, lda, W, bias, C, ldc, M, N, K); break;
        case 3: gemm_kernel<3><<<g, b, 0, s>>>(A, lda, W, bias, C, ldc, M, N, K); break;
    }
}

extern "C" void kernel_launch(void* const* d_in, const int* in_sizes, int n_in,
                              void* d_out, int out_size, void* d_ws, size_t ws_size,
                              hipStream_t stream)
{
    const int*   skills    = (const int*)d_in[0];
    const int*   responses = (const int*)d_in[2];
    const float* embC  = (const float*)d_in[3];
    const float* embA  = (const float*)d_in[4];
    const float* embT  = (const float*)d_in[5];
    const float* embF  = (const float*)d_in[6];
    const float* mlpW1 = (const float*)d_in[9];
    const float* mlpb1 = (const float*)d_in[10];
    const float* mlpW2 = (const float*)d_in[11];
    const float* mlpb2 = (const float*)d_in[12];
    const float* inW   = (const float*)d_in[13];
    const float* convW = (const float*)d_in[14];
    const float* convb = (const float*)d_in[15];
    const float* xpW   = (const float*)d_in[16];
    const float* dtW   = (const float*)d_in[17];
    const float* dtb   = (const float*)d_in[18];
    const float* Alog  = (const float*)d_in[19];
    const float* Dp    = (const float*)d_in[20];
    const float* opW   = (const float*)d_in[21];
    const float* mnw   = (const float*)d_in[22];
    const float* fW1   = (const float*)d_in[23];
    const float* fb1   = (const float*)d_in[24];
    const float* fW2   = (const float*)d_in[25];
    const float* fb2   = (const float*)d_in[26];
    const float* fnw   = (const float*)d_in[27];
    const float* finW  = (const float*)d_in[28];
    const float* finb  = (const float*)d_in[29];
    const float* outW  = (const float*)d_in[30];
    const float* outb  = (const float*)d_in[31];

    const size_t NT = NTOK;
    float* ws   = (float*)d_ws;
    float* y    = ws;                   // NT*256
    float* st   = y    + NT * 256;      // NT*256
    float* sf   = st   + NT * 256;      // NT*256
    float* t1   = sf   + NT * 256;      // NT*256 (mlp hidden / opW out / yc)
    float* h1   = t1   + NT * 256;      // NT*256
    float* bufA = h1   + NT * 256;      // NT*1024 (xz / ffn mid / ycin)
    float* xc   = bufA + NT * 1024;     // NT*512
    float* dt   = xc   + NT * 512;      // NT*512 (dt then ym in-place)
    float* xdbl = dt   + NT * 512;      // NT*48

    // 1) embeddings
    embed_kernel<<<NTOK, 256, 0, stream>>>(skills, responses, embC, embA, embT, embF, y, st, sf);

    // 2) three MLPs (tanh hidden)
    gemm(y,  256, mlpW1, mlpb1, t1, 256, NTOK, 256, 256, 1, stream);
    gemm(t1, 256, mlpW2, mlpb2, y,  256, NTOK, 256, 256, 0, stream);
    gemm(st, 256, mlpW1, mlpb1, t1, 256, NTOK, 256, 256, 1, stream);
    gemm(t1, 256, mlpW2, mlpb2, st, 256, NTOK, 256, 256, 0, stream);
    gemm(sf, 256, mlpW1, mlpb1, t1, 256, NTOK, 256, 256, 1, stream);
    gemm(t1, 256, mlpW2, mlpb2, sf, 256, NTOK, 256, 256, 0, stream);

    // 3) two mamba layers
    for (int i = 0; i < 2; ++i) {
        gemm(y, 256, inW + (size_t)i * 1024 * 256, nullptr, bufA, 1024, NTOK, 1024, 256, 0, stream);
        conv_silu_kernel<<<(NTOK * 512) / 256, 256, 0, stream>>>(bufA, convW + i * 512 * 4, convb + i * 512, xc);
        gemm(xc, 512, xpW + (size_t)i * 48 * 512, nullptr, xdbl, 48, NTOK, 48, 512, 0, stream);
        gemm(xdbl, 48, dtW + (size_t)i * 512 * 16, dtb + i * 512, dt, 512, NTOK, 512, 16, 2, stream);
        scan_kernel<<<(BATCH * 512) / 256, 256, 0, stream>>>(dt, xc, xdbl, bufA, Alog + i * 512 * 16, Dp + i * 512);
        gemm(dt, 512, opW + (size_t)i * 256 * 512, nullptr, t1, 256, NTOK, 256, 512, 0, stream);
        rmsnorm_kernel<<<NTOK, 256, 0, stream>>>(t1, y, mnw + i * 256, h1);
        gemm(h1, 256, fW1 + (size_t)i * 1024 * 256, fb1 + i * 1024, bufA, 1024, NTOK, 1024, 256, 3, stream);
        gemm(bufA, 1024, fW2 + (size_t)i * 256 * 1024, fb2 + i * 256, t1, 256, NTOK, 256, 1024, 0, stream);
        rmsnorm_kernel<<<NTOK, 256, 0, stream>>>(t1, h1, fnw + i * 256, y);
    }

    // 4) dual attention into ycin = bufA (stride 768)
    copy_ycin_kernel<<<NTOK, 256, 0, stream>>>(y, bufA);
    attn_kernel<<<BATCH * 8 * TT, 256, 0, stream>>>(y, st, sf, bufA);

    // 5) final projection + gathered sigmoid
    gemm(bufA, 768, finW, finb, t1, 256, NTOK, 256, 768, 0, stream);
    pred_kernel<<<NTOK / 4, 256, 0, stream>>>(t1, skills, outW, outb, (float*)d_out);
}

// Round 2
// 3946.265 us; speedup vs baseline: 1.4466x; 1.4466x over previous
//
#include <hip/hip_runtime.h>
#include <hip/hip_bf16.h>
#include <math.h>

#define BATCH 32
#define SEQL  512
#define TT    511          // T = L-1
#define DMODEL 256
#define DIN   512          // DI = EXP*D
#define DSN   16           // DS
#define NSK   500
#define NTOK  (BATCH*TT)   // 16352

// ---------------------------------------------------------------- embeddings
__global__ __launch_bounds__(256) void embed_kernel(
    const int* __restrict__ skills, const int* __restrict__ responses,
    const float* __restrict__ embC, const float* __restrict__ embA,
    const float* __restrict__ embT, const float* __restrict__ embF,
    float* __restrict__ o_state, float* __restrict__ o_st, float* __restrict__ o_sf)
{
    int idx = blockIdx.x * 256 + threadIdx.x;      // < NTOK*256
    int n = idx >> 8, j = idx & 255;
    int b = n / TT, t = n % TT;
    int c = skills[b * SEQL + t];
    int r = responses[b * SEQL + t];
    r = (r > -1) ? r : 0;                          // masked_r
    o_state[idx] = embA[r * DMODEL + j] + embC[c * DMODEL + j];
    o_st[idx]    = embT[(r * (c + NSK)) * DMODEL + j];
    o_sf[idx]    = embF[(c * (1 - r)) * DMODEL + j];
}

// ---------------------------------------------------------------- generic GEMM
// C[M,N] = act(A[M,K](lda) @ W[N,K]^T + bias[N]);  K%16==0, N%4==0
template<int ACT>   // 0 none, 1 tanh, 2 softplus, 3 gelu(exact)
__global__ __launch_bounds__(256) void gemm_kernel(
    const float* __restrict__ A, int lda,
    const float* __restrict__ W,
    const float* __restrict__ bias,
    float* __restrict__ C, int ldc,
    int M, int N, int K)
{
    __shared__ float As[64][17];
    __shared__ float Ws[64][17];
    const int tx = threadIdx.x;
    const int rowBase = blockIdx.y * 64;
    const int colBase = blockIdx.x * 64;
    const int lr = tx >> 2;
    const int lk = (tx & 3) << 2;
    const int tr = (tx >> 4) << 2;
    const int tc = (tx & 15) << 2;
    float acc[4][4] = {};

    for (int k0 = 0; k0 < K; k0 += 16) {
        float4 av = make_float4(0.f, 0.f, 0.f, 0.f);
        int ar = rowBase + lr;
        if (ar < M) av = *reinterpret_cast<const float4*>(A + (size_t)ar * lda + k0 + lk);
        As[lr][lk] = av.x; As[lr][lk + 1] = av.y; As[lr][lk + 2] = av.z; As[lr][lk + 3] = av.w;
        float4 wv = make_float4(0.f, 0.f, 0.f, 0.f);
        int wr = colBase + lr;
        if (wr < N) wv = *reinterpret_cast<const float4*>(W + (size_t)wr * K + k0 + lk);
        Ws[lr][lk] = wv.x; Ws[lr][lk + 1] = wv.y; Ws[lr][lk + 2] = wv.z; Ws[lr][lk + 3] = wv.w;
        __syncthreads();
        #pragma unroll
        for (int k = 0; k < 16; ++k) {
            float a0 = As[tr][k], a1 = As[tr + 1][k], a2 = As[tr + 2][k], a3 = As[tr + 3][k];
            float b0 = Ws[tc][k], b1 = Ws[tc + 1][k], b2 = Ws[tc + 2][k], b3 = Ws[tc + 3][k];
            acc[0][0] += a0 * b0; acc[0][1] += a0 * b1; acc[0][2] += a0 * b2; acc[0][3] += a0 * b3;
            acc[1][0] += a1 * b0; acc[1][1] += a1 * b1; acc[1][2] += a1 * b2; acc[1][3] += a1 * b3;
            acc[2][0] += a2 * b0; acc[2][1] += a2 * b1; acc[2][2] += a2 * b2; acc[2][3] += a2 * b3;
            acc[3][0] += a3 * b0; acc[3][1] += a3 * b1; acc[3][2] += a3 * b2; acc[3][3] += a3 * b3;
        }
        __syncthreads();
    }

    #pragma unroll
    for (int i = 0; i < 4; ++i) {
        int r = rowBase + tr + i;
        if (r >= M) break;
        int cb = colBase + tc;
        if (cb >= N) continue;                 // N%4==0 -> whole float4 in/out
        float4 v;
        float* vp = &v.x;
        #pragma unroll
        for (int j = 0; j < 4; ++j) {
            float x = acc[i][j];
            if (bias) x += bias[cb + j];
            if (ACT == 1) x = tanhf(x);
            else if (ACT == 2) x = fmaxf(x, 0.f) + log1pf(expf(-fabsf(x)));              // softplus
            else if (ACT == 3) x = 0.5f * x * (1.f + erff(x * 0.70710678118654752440f)); // gelu exact
            vp[j] = x;
        }
        *reinterpret_cast<float4*>(C + (size_t)r * ldc + cb) = v;
    }
}

// ---------------------------------------------------------------- conv1d(4, causal, depthwise) + silu
__global__ __launch_bounds__(256) void conv_silu_kernel(
    const float* __restrict__ xz,   // (NTOK,1024), xc part = cols 0..511
    const float* __restrict__ cW,   // (512,4)
    const float* __restrict__ cb,   // (512)
    float* __restrict__ xc)         // (NTOK,512)
{
    int idx = blockIdx.x * 256 + threadIdx.x;     // < NTOK*512
    int d = idx & 511;
    int n = idx >> 9;
    int b = n / TT, t = n % TT;
    float w0 = cW[d * 4], w1 = cW[d * 4 + 1], w2 = cW[d * 4 + 2], w3 = cW[d * 4 + 3];
    const float* base = xz + (size_t)(b * TT) * 1024 + d;
    float acc = cb[d];
    if (t >= 3) acc += w0 * base[(size_t)(t - 3) * 1024];
    if (t >= 2) acc += w1 * base[(size_t)(t - 2) * 1024];
    if (t >= 1) acc += w2 * base[(size_t)(t - 1) * 1024];
    acc += w3 * base[(size_t)t * 1024];
    xc[idx] = acc / (1.f + expf(-acc));           // silu
}

// ---------------------------------------------------------------- selective scan (+ fused D-term and silu(z) gate)
__global__ __launch_bounds__(256) void scan_kernel(
    float* __restrict__ dt_ym,        // (NTOK,512) in: dt, out: ym (in-place)
    const float* __restrict__ xc,     // (NTOK,512)
    const float* __restrict__ xdbl,   // (NTOK,48): [dtr(16) | B(16) | C(16)]
    const float* __restrict__ xz,     // (NTOK,1024): z = cols 512..1023
    const float* __restrict__ Alog,   // (512,16)
    const float* __restrict__ Dpv)    // (512)
{
    int idx = blockIdx.x * 256 + threadIdx.x;   // 0..16383
    int d = idx & 511;
    int b = idx >> 9;
    float A[DSN], h[DSN];
    #pragma unroll
    for (int s = 0; s < DSN; ++s) { A[s] = -expf(Alog[d * DSN + s]); h[s] = 0.f; }
    float Dv = Dpv[d];
    for (int t = 0; t < TT; ++t) {
        size_t n = (size_t)b * TT + t;
        float dtt = dt_ym[n * 512 + d];
        float xt  = xc[n * 512 + d];
        float zz  = xz[n * 1024 + 512 + d];
        const float* br = xdbl + n * 48;
        float dx = dtt * xt;
        float y = 0.f;
        #pragma unroll
        for (int s = 0; s < DSN; ++s) {
            h[s] = expf(dtt * A[s]) * h[s] + dx * br[16 + s];
            y += h[s] * br[32 + s];
        }
        float ym = (y + xt * Dv) * (zz / (1.f + expf(-zz)));
        dt_ym[n * 512 + d] = ym;
    }
}

// ---------------------------------------------------------------- rmsnorm(a+b)*w
__global__ __launch_bounds__(256) void rmsnorm_kernel(
    const float* __restrict__ a, const float* __restrict__ b,
    const float* __restrict__ w, float* __restrict__ out)
{
    __shared__ float red[256];
    int n = blockIdx.x, j = threadIdx.x;
    float v = a[(size_t)n * 256 + j] + b[(size_t)n * 256 + j];
    red[j] = v * v;
    __syncthreads();
    for (int s = 128; s > 0; s >>= 1) { if (j < s) red[j] += red[j + s]; __syncthreads(); }
    float scale = rsqrtf(red[0] / 256.0f + 1e-12f);
    out[(size_t)n * 256 + j] = v * scale * w[j];
}

// ---------------------------------------------------------------- copy y into ycin[:, 0:256] (stride 768)
__global__ __launch_bounds__(256) void copy_ycin_kernel(
    const float* __restrict__ y, float* __restrict__ ycin)
{
    int idx = blockIdx.x * 256 + threadIdx.x;
    int n = idx >> 8, j = idx & 255;
    ycin[(size_t)n * 768 + j] = y[idx];
}

// ---------------------------------------------------------------- tiled dual attention
// block = 256 threads, handles (b, h, q-tile of 64). Flash-style online softmax.
// Exactness notes vs reference:
//  * mask value is exactly -1e9 for 0<=k<TT, k>=q (matches jnp.where).
//  * q==0 row: ALL 511 scores are -1e9 -> uniform softmax over 511 keys.
//    q-tile 0 therefore iterates all 8 k-tiles; for rows>=1 the extra tiles
//    contribute exp(-1e9 - m)==0 exactly (m >= O(1) real score).
//  * phantom key k==511 gets -INF so exp() is 0 even when the whole row is
//    at the -1e9 floor (keeps row-0 denominator at 511, not 512).
__global__ __launch_bounds__(256) void attn_kernel(
    const float* __restrict__ y,    // (B,TT,256) q = k
    const float* __restrict__ st,   // v1
    const float* __restrict__ sf,   // v2
    float* __restrict__ ycin)       // (B,TT,768), writes cols 256..767
{
    __shared__ float Qs[64][33];
    __shared__ float Ks[64][33];
    __shared__ float V1s[64][33];
    __shared__ float V2s[64][33];
    __shared__ float sc[64][65];

    const int bid = blockIdx.x;          // ((b*8)+h)*8 + qt
    const int qt = bid & 7;
    const int h  = (bid >> 3) & 7;
    const int b  = bid >> 6;
    const int tx = threadIdx.x;
    const int q0 = qt * 64;

    const float* ybase  = y  + (size_t)(b * TT) * 256 + h * 32;
    const float* v1base = st + (size_t)(b * TT) * 256 + h * 32;
    const float* v2base = sf + (size_t)(b * TT) * 256 + h * 32;

    // stage Q tile (64x32): 4 threads per row, 8 floats each
    {
        int r = tx >> 2, c = (tx & 3) * 8;
        int qg = q0 + r;
        if (qg < TT) {
            const float* src = ybase + (size_t)qg * 256 + c;
            float4 a = *reinterpret_cast<const float4*>(src);
            float4 d = *reinterpret_cast<const float4*>(src + 4);
            Qs[r][c] = a.x; Qs[r][c+1] = a.y; Qs[r][c+2] = a.z; Qs[r][c+3] = a.w;
            Qs[r][c+4] = d.x; Qs[r][c+5] = d.y; Qs[r][c+6] = d.z; Qs[r][c+7] = d.w;
        } else {
            #pragma unroll
            for (int i = 0; i < 8; ++i) Qs[r][c+i] = 0.f;
        }
    }

    // softmax/PV thread mapping: 4 consecutive lanes own one q row
    const int q_l  = tx >> 2;
    const int part = tx & 3;
    const int dsel = part & 1;   // which 16-dim half of the 32-dim head
    const int vsel = part >> 1;  // 0 -> v1(st), 1 -> v2(sf)
    float m = -INFINITY, l = 0.f;
    float o[16];
    #pragma unroll
    for (int i = 0; i < 16; ++i) o[i] = 0.f;

    // score-GEMM thread mapping (4x4 per thread)
    const int tr = (tx >> 4) << 2;
    const int tc = (tx & 15) << 2;
    const float scale = 0.17677669529663687f;   // 1/sqrt(32)

    const int nkt = (qt == 0) ? 8 : (qt + 1);
    for (int kt = 0; kt < nkt; ++kt) {
        const int k0 = kt * 64;
        __syncthreads();   // previous iteration's LDS reads complete
        // stage K, V1, V2 tiles
        {
            int r = tx >> 2, c = (tx & 3) * 8;
            int kg = k0 + r;
            if (kg < TT) {
                const float* ks = ybase  + (size_t)kg * 256 + c;
                const float* v1 = v1base + (size_t)kg * 256 + c;
                const float* v2 = v2base + (size_t)kg * 256 + c;
                float4 a0 = *reinterpret_cast<const float4*>(ks);
                float4 a1 = *reinterpret_cast<const float4*>(ks + 4);
                float4 b0 = *reinterpret_cast<const float4*>(v1);
                float4 b1 = *reinterpret_cast<const float4*>(v1 + 4);
                float4 c0 = *reinterpret_cast<const float4*>(v2);
                float4 c1 = *reinterpret_cast<const float4*>(v2 + 4);
                Ks[r][c]=a0.x; Ks[r][c+1]=a0.y; Ks[r][c+2]=a0.z; Ks[r][c+3]=a0.w;
                Ks[r][c+4]=a1.x; Ks[r][c+5]=a1.y; Ks[r][c+6]=a1.z; Ks[r][c+7]=a1.w;
                V1s[r][c]=b0.x; V1s[r][c+1]=b0.y; V1s[r][c+2]=b0.z; V1s[r][c+3]=b0.w;
                V1s[r][c+4]=b1.x; V1s[r][c+5]=b1.y; V1s[r][c+6]=b1.z; V1s[r][c+7]=b1.w;
                V2s[r][c]=c0.x; V2s[r][c+1]=c0.y; V2s[r][c+2]=c0.z; V2s[r][c+3]=c0.w;
                V2s[r][c+4]=c1.x; V2s[r][c+5]=c1.y; V2s[r][c+6]=c1.z; V2s[r][c+7]=c1.w;
            } else {
                #pragma unroll
                for (int i = 0; i < 8; ++i) { Ks[r][c+i]=0.f; V1s[r][c+i]=0.f; V2s[r][c+i]=0.f; }
            }
        }
        __syncthreads();
        // 64x64 score tile, 4x4 per thread
        float acc[4][4] = {};
        #pragma unroll
        for (int j = 0; j < 32; ++j) {
            float a0 = Qs[tr][j], a1 = Qs[tr+1][j], a2 = Qs[tr+2][j], a3 = Qs[tr+3][j];
            float b0 = Ks[tc][j], b1 = Ks[tc+1][j], b2 = Ks[tc+2][j], b3 = Ks[tc+3][j];
            acc[0][0] += a0*b0; acc[0][1] += a0*b1; acc[0][2] += a0*b2; acc[0][3] += a0*b3;
            acc[1][0] += a1*b0; acc[1][1] += a1*b1; acc[1][2] += a1*b2; acc[1][3] += a1*b3;
            acc[2][0] += a2*b0; acc[2][1] += a2*b1; acc[2][2] += a2*b2; acc[2][3] += a2*b3;
            acc[3][0] += a3*b0; acc[3][1] += a3*b1; acc[3][2] += a3*b2; acc[3][3] += a3*b3;
        }
        #pragma unroll
        for (int i = 0; i < 4; ++i) {
            int qq = q0 + tr + i;
            #pragma unroll
            for (int j = 0; j < 4; ++j) {
                int kk = k0 + tc + j;
                float s;
                if (kk < qq)      s = acc[i][j] * scale;
                else if (kk < TT) s = -1e9f;
                else              s = -INFINITY;
                sc[tr + i][tc + j] = s;
            }
        }
        __syncthreads();
        // online softmax: 4 lanes per row, each owns 16 columns
        float pv[16];
        float tm = -INFINITY;
        #pragma unroll
        for (int i = 0; i < 16; ++i) { pv[i] = sc[q_l][part * 16 + i]; tm = fmaxf(tm, pv[i]); }
        tm = fmaxf(tm, __shfl_xor(tm, 1));
        tm = fmaxf(tm, __shfl_xor(tm, 2));
        float mn = fmaxf(m, tm);
        float rescale = expf(m - mn);          // m==-inf -> 0
        float ts = 0.f;
        #pragma unroll
        for (int i = 0; i < 16; ++i) { float e = expf(pv[i] - mn); pv[i] = e; ts += e; }
        #pragma unroll
        for (int i = 0; i < 16; ++i) sc[q_l][part * 16 + i] = pv[i];
        ts += __shfl_xor(ts, 1);
        ts += __shfl_xor(ts, 2);
        l = l * rescale + ts;
        m = mn;
        #pragma unroll
        for (int i = 0; i < 16; ++i) o[i] *= rescale;
        __syncthreads();
        // PV: each thread accumulates its 16 dims over the 64 keys
        const float (*Vs)[33] = vsel ? V2s : V1s;
        const int dbase = dsel * 16;
        for (int k = 0; k < 64; ++k) {
            float p = sc[q_l][k];
            #pragma unroll
            for (int i = 0; i < 16; ++i) o[i] += p * Vs[k][dbase + i];
        }
    }

    // write out: thread's 16 dims of o1/o2
    int qg = q0 + q_l;
    if (qg < TT) {
        float inv = 1.0f / l;
        int col = 256 + vsel * 256 + h * 32 + dsel * 16;
        float* dst = ycin + (size_t)(b * TT + qg) * 768 + col;
        #pragma unroll
        for (int i = 0; i < 4; ++i) {
            float4 v = make_float4(o[i*4] * inv, o[i*4+1] * inv, o[i*4+2] * inv, o[i*4+3] * inv);
            *reinterpret_cast<float4*>(dst + i * 4) = v;
        }
    }
}

// ---------------------------------------------------------------- gathered logit + sigmoid
__global__ __launch_bounds__(256) void pred_kernel(
    const float* __restrict__ yc,     // (NTOK,256)
    const int* __restrict__ skills,
    const float* __restrict__ outW,   // (500,256)
    const float* __restrict__ outB,   // (500)
    float* __restrict__ out)          // (NTOK)
{
    int n = blockIdx.x * 4 + (threadIdx.x >> 6);
    if (n >= NTOK) return;
    int lane = threadIdx.x & 63;
    int b = n / TT, t = n % TT;
    int c = skills[b * SEQL + t + 1];            // cshft
    const float* wrow = outW + (size_t)c * 256;
    const float* xrow = yc + (size_t)n * 256;
    float s = 0.f;
    for (int j = lane; j < 256; j += 64) s += xrow[j] * wrow[j];
    #pragma unroll
    for (int off = 32; off > 0; off >>= 1) s += __shfl_down(s, off);
    if (lane == 0) out[n] = 1.0f / (1.0f + expf(-(s + outB[c])));
}

// ---------------------------------------------------------------- host
static inline void gemm(const float* A, int lda, const float* W, const float* bias,
                        float* C, int ldc, int M, int N, int K, int act, hipStream_t s)
{
    dim3 g((N + 63) / 64, (M + 63) / 64), b(256);
    switch (act) {
        case 0: gemm_kernel<0><<<g, b, 0, s>>>(A, lda, W, bias, C, ldc, M, N, K); break;
        case 1: gemm_kernel<1><<<g, b, 0, s>>>(A, lda, W, bias, C, ldc, M, N, K); break;
        case 2: gemm_kernel<2><<<g, b, 0, s>>>(A, lda, W, bias, C, ldc, M, N, K); break;
        case 3: gemm_kernel<3><<<g, b, 0, s>>>(A, lda, W, bias, C, ldc, M, N, K); break;
    }
}

extern "C" void kernel_launch(void* const* d_in, const int* in_sizes, int n_in,
                              void* d_out, int out_size, void* d_ws, size_t ws_size,
                              hipStream_t stream)
{
    const int*   skills    = (const int*)d_in[0];
    const int*   responses = (const int*)d_in[2];
    const float* embC  = (const float*)d_in[3];
    const float* embA  = (const float*)d_in[4];
    const float* embT  = (const float*)d_in[5];
    const float* embF  = (const float*)d_in[6];
    const float* mlpW1 = (const float*)d_in[9];
    const float* mlpb1 = (const float*)d_in[10];
    const float* mlpW2 = (const float*)d_in[11];
    const float* mlpb2 = (const float*)d_in[12];
    const float* inW   = (const float*)d_in[13];
    const float* convW = (const float*)d_in[14];
    const float* convb = (const float*)d_in[15];
    const float* xpW   = (const float*)d_in[16];
    const float* dtW   = (const float*)d_in[17];
    const float* dtb   = (const float*)d_in[18];
    const float* Alog  = (const float*)d_in[19];
    const float* Dp    = (const float*)d_in[20];
    const float* opW   = (const float*)d_in[21];
    const float* mnw   = (const float*)d_in[22];
    const float* fW1   = (const float*)d_in[23];
    const float* fb1   = (const float*)d_in[24];
    const float* fW2   = (const float*)d_in[25];
    const float* fb2   = (const float*)d_in[26];
    const float* fnw   = (const float*)d_in[27];
    const float* finW  = (const float*)d_in[28];
    const float* finb  = (const float*)d_in[29];
    const float* outW  = (const float*)d_in[30];
    const float* outb  = (const float*)d_in[31];

    const size_t NT = NTOK;
    float* ws   = (float*)d_ws;
    float* y    = ws;                   // NT*256
    float* st   = y    + NT * 256;      // NT*256
    float* sf   = st   + NT * 256;      // NT*256
    float* t1   = sf   + NT * 256;      // NT*256 (mlp hidden / opW out / yc)
    float* h1   = t1   + NT * 256;      // NT*256
    float* bufA = h1   + NT * 256;      // NT*1024 (xz / ffn mid / ycin)
    float* xc   = bufA + NT * 1024;     // NT*512
    float* dt   = xc   + NT * 512;      // NT*512 (dt then ym in-place)
    float* xdbl = dt   + NT * 512;      // NT*48

    // 1) embeddings
    embed_kernel<<<NTOK, 256, 0, stream>>>(skills, responses, embC, embA, embT, embF, y, st, sf);

    // 2) three MLPs (tanh hidden)
    gemm(y,  256, mlpW1, mlpb1, t1, 256, NTOK, 256, 256, 1, stream);
    gemm(t1, 256, mlpW2, mlpb2, y,  256, NTOK, 256, 256, 0, stream);
    gemm(st, 256, mlpW1, mlpb1, t1, 256, NTOK, 256, 256, 1, stream);
    gemm(t1, 256, mlpW2, mlpb2, st, 256, NTOK, 256, 256, 0, stream);
    gemm(sf, 256, mlpW1, mlpb1, t1, 256, NTOK, 256, 256, 1, stream);
    gemm(t1, 256, mlpW2, mlpb2, sf, 256, NTOK, 256, 256, 0, stream);

    // 3) two mamba layers
    for (int i = 0; i < 2; ++i) {
        gemm(y, 256, inW + (size_t)i * 1024 * 256, nullptr, bufA, 1024, NTOK, 1024, 256, 0, stream);
        conv_silu_kernel<<<(NTOK * 512) / 256, 256, 0, stream>>>(bufA, convW + i * 512 * 4, convb + i * 512, xc);
        gemm(xc, 512, xpW + (size_t)i * 48 * 512, nullptr, xdbl, 48, NTOK, 48, 512, 0, stream);
        gemm(xdbl, 48, dtW + (size_t)i * 512 * 16, dtb + i * 512, dt, 512, NTOK, 512, 16, 2, stream);
        scan_kernel<<<(BATCH * 512) / 256, 256, 0, stream>>>(dt, xc, xdbl, bufA, Alog + i * 512 * 16, Dp + i * 512);
        gemm(dt, 512, opW + (size_t)i * 256 * 512, nullptr, t1, 256, NTOK, 256, 512, 0, stream);
        rmsnorm_kernel<<<NTOK, 256, 0, stream>>>(t1, y, mnw + i * 256, h1);
        gemm(h1, 256, fW1 + (size_t)i * 1024 * 256, fb1 + i * 1024, bufA, 1024, NTOK, 1024, 256, 3, stream);
        gemm(bufA, 1024, fW2 + (size_t)i * 256 * 1024, fb2 + i * 256, t1, 256, NTOK, 256, 1024, 0, stream);
        rmsnorm_kernel<<<NTOK, 256, 0, stream>>>(t1, h1, fnw + i * 256, y);
    }

    // 4) dual attention into ycin = bufA (stride 768)
    copy_ycin_kernel<<<NTOK, 256, 0, stream>>>(y, bufA);
    attn_kernel<<<BATCH * 8 * 8, 256, 0, stream>>>(y, st, sf, bufA);

    // 5) final projection + gathered sigmoid
    gemm(bufA, 768, finW, finb, t1, 256, NTOK, 256, 768, 0, stream);
    pred_kernel<<<NTOK / 4, 256, 0, stream>>>(t1, skills, outW, outb, (float*)d_out);
}

// Round 3
// 2948.803 us; speedup vs baseline: 1.9360x; 1.3383x over previous
//
#include <hip/hip_runtime.h>
#include <hip/hip_bf16.h>
#include <math.h>
#include <string.h>

#define BATCH 32
#define SEQL  512
#define TT    511          // T = L-1
#define DMODEL 256
#define DIN   512          // DI = EXP*D
#define DSN   16           // DS
#define NSK   500
#define NTOK  (BATCH*TT)   // 16352

typedef __hip_bfloat16 bf16;
typedef __attribute__((ext_vector_type(8))) short short8;
typedef __attribute__((ext_vector_type(4))) float f32x4;

__device__ inline float bf2f_bits(short s) {
    unsigned int u = ((unsigned int)(unsigned short)s) << 16;
    float f; memcpy(&f, &u, 4); return f;
}

// ---------------------------------------------------------------- fp32 -> bf16 weight conversion
__global__ __launch_bounds__(256) void f2bf_kernel(const float* __restrict__ in, bf16* __restrict__ out, int n)
{
    int i = blockIdx.x * 256 + threadIdx.x;
    if (i < n) out[i] = __float2bfloat16(in[i]);
}

// ---------------------------------------------------------------- embeddings (bf16 out)
__global__ __launch_bounds__(256) void embed_kernel(
    const int* __restrict__ skills, const int* __restrict__ responses,
    const float* __restrict__ embC, const float* __restrict__ embA,
    const float* __restrict__ embT, const float* __restrict__ embF,
    bf16* __restrict__ o_state, bf16* __restrict__ o_st, bf16* __restrict__ o_sf)
{
    int idx = blockIdx.x * 256 + threadIdx.x;      // < NTOK*256
    int n = idx >> 8, j = idx & 255;
    int b = n / TT, t = n % TT;
    int c = skills[b * SEQL + t];
    int r = responses[b * SEQL + t];
    r = (r > -1) ? r : 0;                          // masked_r
    o_state[idx] = __float2bfloat16(embA[r * DMODEL + j] + embC[c * DMODEL + j]);
    o_st[idx]    = __float2bfloat16(embT[(r * (c + NSK)) * DMODEL + j]);
    o_sf[idx]    = __float2bfloat16(embF[(c * (1 - r)) * DMODEL + j]);
}

// ---------------------------------------------------------------- MFMA bf16 GEMM
// C[M,N] = act(A[M,K](lda,bf16) @ W[N,K]^T(bf16) + bias[N]); K%32==0, N%128==0
// block 256 = 4 waves (2x2 of 64x64), tile 128x128, BK=32.
// LDS stride 40 shorts (80B): frag ds_read_b128 is 2-way bank aliased = free.
template<int ACT, typename OUTT>   // ACT: 0 none, 1 tanh, 3 gelu-exact
__global__ __launch_bounds__(256) void gemm_mfma(
    const bf16* __restrict__ A, int lda,
    const bf16* __restrict__ W,
    const float* __restrict__ bias,
    OUTT* __restrict__ C, int ldc,
    int M, int N, int K)
{
    __shared__ short As[128 * 40];
    __shared__ short Ws[128 * 40];
    const int tx = threadIdx.x;
    const int lane = tx & 63;
    const int wv = tx >> 6;
    const int rowBase = blockIdx.y * 128;
    const int colBase = blockIdx.x * 128;
    const int wrb = (wv >> 1) * 64;
    const int wcb = (wv & 1) * 64;

    f32x4 acc[4][4];
    #pragma unroll
    for (int m = 0; m < 4; ++m)
        #pragma unroll
        for (int n = 0; n < 4; ++n)
            acc[m][n] = (f32x4){0.f, 0.f, 0.f, 0.f};

    const int srow = tx >> 1;
    const int scol = (tx & 1) * 16;
    const bool arow_ok = (rowBase + srow) < M;
    const bf16* Ag = A + (size_t)(rowBase + srow) * lda + scol;
    const bf16* Wg = W + (size_t)(colBase + srow) * K + scol;

    const int kq = (lane >> 4) * 8;      // k-offset of this lane's 8 elems
    const int rl = lane & 15;            // row (A) / col (W) within fragment

    for (int k0 = 0; k0 < K; k0 += 32) {
        short8 av0 = {}, av1 = {};
        if (arow_ok) {
            av0 = *(const short8*)(Ag + k0);
            av1 = *(const short8*)(Ag + k0 + 8);
        }
        short8 wv0 = *(const short8*)(Wg + k0);
        short8 wv1 = *(const short8*)(Wg + k0 + 8);
        __syncthreads();                       // previous iter's LDS reads done
        *(short8*)&As[srow * 40 + scol]     = av0;
        *(short8*)&As[srow * 40 + scol + 8] = av1;
        *(short8*)&Ws[srow * 40 + scol]     = wv0;
        *(short8*)&Ws[srow * 40 + scol + 8] = wv1;
        __syncthreads();
        short8 af[4], bfr[4];
        #pragma unroll
        for (int m = 0; m < 4; ++m) af[m]  = *(const short8*)&As[(wrb + m * 16 + rl) * 40 + kq];
        #pragma unroll
        for (int n = 0; n < 4; ++n) bfr[n] = *(const short8*)&Ws[(wcb + n * 16 + rl) * 40 + kq];
        #pragma unroll
        for (int m = 0; m < 4; ++m)
            #pragma unroll
            for (int n = 0; n < 4; ++n)
                acc[m][n] = __builtin_amdgcn_mfma_f32_16x16x32_bf16(af[m], bfr[n], acc[m][n], 0, 0, 0);
    }

    // epilogue: C/D layout col=lane&15, row=(lane>>4)*4+reg  [m89/m91]
    const int rq = (lane >> 4) * 4;
    const int cl = lane & 15;
    #pragma unroll
    for (int m = 0; m < 4; ++m) {
        #pragma unroll
        for (int i = 0; i < 4; ++i) {
            int row = rowBase + wrb + m * 16 + rq + i;
            if (row >= M) continue;
            #pragma unroll
            for (int n = 0; n < 4; ++n) {
                int col = colBase + wcb + n * 16 + cl;
                float x = acc[m][n][i];
                if (bias) x += bias[col];
                if (ACT == 1) x = tanhf(x);
                else if (ACT == 3) x = 0.5f * x * (1.f + erff(x * 0.70710678118654752440f));
                C[(size_t)row * ldc + col] = OUTT(x);
            }
        }
    }
}

// ---------------------------------------------------------------- small VALU GEMM (xproj N=48, dtproj K=16)
__device__ inline float4 loadA4(const float* p) { return *reinterpret_cast<const float4*>(p); }
__device__ inline float4 loadA4(const bf16* p) {
    return make_float4(__bfloat162float(p[0]), __bfloat162float(p[1]),
                       __bfloat162float(p[2]), __bfloat162float(p[3]));
}

template<int ACT, typename TA>   // 0 none, 2 softplus
__global__ __launch_bounds__(256) void gemm_kernel(
    const TA* __restrict__ A, int lda,
    const float* __restrict__ W,
    const float* __restrict__ bias,
    float* __restrict__ C, int ldc,
    int M, int N, int K)
{
    __shared__ float As[64][17];
    __shared__ float Ws[64][17];
    const int tx = threadIdx.x;
    const int rowBase = blockIdx.y * 64;
    const int colBase = blockIdx.x * 64;
    const int lr = tx >> 2;
    const int lk = (tx & 3) << 2;
    const int tr = (tx >> 4) << 2;
    const int tc = (tx & 15) << 2;
    float acc[4][4] = {};

    for (int k0 = 0; k0 < K; k0 += 16) {
        float4 av = make_float4(0.f, 0.f, 0.f, 0.f);
        int ar = rowBase + lr;
        if (ar < M) av = loadA4(A + (size_t)ar * lda + k0 + lk);
        As[lr][lk] = av.x; As[lr][lk + 1] = av.y; As[lr][lk + 2] = av.z; As[lr][lk + 3] = av.w;
        float4 wvv = make_float4(0.f, 0.f, 0.f, 0.f);
        int wr = colBase + lr;
        if (wr < N) wvv = *reinterpret_cast<const float4*>(W + (size_t)wr * K + k0 + lk);
        Ws[lr][lk] = wvv.x; Ws[lr][lk + 1] = wvv.y; Ws[lr][lk + 2] = wvv.z; Ws[lr][lk + 3] = wvv.w;
        __syncthreads();
        #pragma unroll
        for (int k = 0; k < 16; ++k) {
            float a0 = As[tr][k], a1 = As[tr + 1][k], a2 = As[tr + 2][k], a3 = As[tr + 3][k];
            float b0 = Ws[tc][k], b1 = Ws[tc + 1][k], b2 = Ws[tc + 2][k], b3 = Ws[tc + 3][k];
            acc[0][0] += a0 * b0; acc[0][1] += a0 * b1; acc[0][2] += a0 * b2; acc[0][3] += a0 * b3;
            acc[1][0] += a1 * b0; acc[1][1] += a1 * b1; acc[1][2] += a1 * b2; acc[1][3] += a1 * b3;
            acc[2][0] += a2 * b0; acc[2][1] += a2 * b1; acc[2][2] += a2 * b2; acc[2][3] += a2 * b3;
            acc[3][0] += a3 * b0; acc[3][1] += a3 * b1; acc[3][2] += a3 * b2; acc[3][3] += a3 * b3;
        }
        __syncthreads();
    }

    #pragma unroll
    for (int i = 0; i < 4; ++i) {
        int r = rowBase + tr + i;
        if (r >= M) break;
        int cb = colBase + tc;
        if (cb >= N) continue;
        float4 v;
        float* vp = &v.x;
        #pragma unroll
        for (int j = 0; j < 4; ++j) {
            float x = acc[i][j];
            if (bias) x += bias[cb + j];
            if (ACT == 2) x = fmaxf(x, 0.f) + log1pf(expf(-fabsf(x)));   // softplus
            vp[j] = x;
        }
        *reinterpret_cast<float4*>(C + (size_t)r * ldc + cb) = v;
    }
}

// ---------------------------------------------------------------- conv1d(4, causal, depthwise) + silu (bf16 io)
__global__ __launch_bounds__(256) void conv_silu_kernel(
    const bf16* __restrict__ xz,    // (NTOK,1024), xc part = cols 0..511
    const float* __restrict__ cW,   // (512,4)
    const float* __restrict__ cb,   // (512)
    bf16* __restrict__ xc)          // (NTOK,512)
{
    int idx = blockIdx.x * 256 + threadIdx.x;     // < NTOK*512
    int d = idx & 511;
    int n = idx >> 9;
    int b = n / TT, t = n % TT;
    float w0 = cW[d * 4], w1 = cW[d * 4 + 1], w2 = cW[d * 4 + 2], w3 = cW[d * 4 + 3];
    const bf16* base = xz + (size_t)(b * TT) * 1024 + d;
    float acc = cb[d];
    if (t >= 3) acc += w0 * __bfloat162float(base[(size_t)(t - 3) * 1024]);
    if (t >= 2) acc += w1 * __bfloat162float(base[(size_t)(t - 2) * 1024]);
    if (t >= 1) acc += w2 * __bfloat162float(base[(size_t)(t - 1) * 1024]);
    acc += w3 * __bfloat162float(base[(size_t)t * 1024]);
    xc[idx] = __float2bfloat16(acc / (1.f + expf(-acc)));   // silu
}

// ---------------------------------------------------------------- selective scan (fp32 state; bf16 x/z; bf16 ym out)
__global__ __launch_bounds__(256) void scan_kernel(
    const float* __restrict__ dt,     // (NTOK,512)
    const bf16* __restrict__ xc,      // (NTOK,512)
    const float* __restrict__ xdbl,   // (NTOK,48): [dtr(16) | B(16) | C(16)]
    const bf16* __restrict__ xz,      // (NTOK,1024): z = cols 512..1023
    const float* __restrict__ Alog,   // (512,16)
    const float* __restrict__ Dpv,    // (512)
    bf16* __restrict__ ym)            // (NTOK,512)
{
    int idx = blockIdx.x * 256 + threadIdx.x;   // 0..16383
    int d = idx & 511;
    int b = idx >> 9;
    float A[DSN], h[DSN];
    #pragma unroll
    for (int s = 0; s < DSN; ++s) { A[s] = -expf(Alog[d * DSN + s]); h[s] = 0.f; }
    float Dv = Dpv[d];
    for (int t = 0; t < TT; ++t) {
        size_t n = (size_t)b * TT + t;
        float dtt = dt[n * 512 + d];
        float xt  = __bfloat162float(xc[n * 512 + d]);
        float zz  = __bfloat162float(xz[n * 1024 + 512 + d]);
        const float* br = xdbl + n * 48;
        float dx = dtt * xt;
        float y = 0.f;
        #pragma unroll
        for (int s = 0; s < DSN; ++s) {
            h[s] = expf(dtt * A[s]) * h[s] + dx * br[16 + s];
            y += h[s] * br[32 + s];
        }
        float v = (y + xt * Dv) * (zz / (1.f + expf(-zz)));
        ym[n * 512 + d] = __float2bfloat16(v);
    }
}

// ---------------------------------------------------------------- rmsnorm(a+b)*w  (bf16 io, fp32 math)
__global__ __launch_bounds__(256) void rmsnorm_kernel(
    const bf16* __restrict__ a, const bf16* __restrict__ b,
    const float* __restrict__ w, bf16* __restrict__ out)
{
    __shared__ float red[256];
    int n = blockIdx.x, j = threadIdx.x;
    float v = __bfloat162float(a[(size_t)n * 256 + j]) + __bfloat162float(b[(size_t)n * 256 + j]);
    red[j] = v * v;
    __syncthreads();
    for (int s = 128; s > 0; s >>= 1) { if (j < s) red[j] += red[j + s]; __syncthreads(); }
    float scale = rsqrtf(red[0] / 256.0f + 1e-12f);
    out[(size_t)n * 256 + j] = __float2bfloat16(v * scale * w[j]);
}

// ---------------------------------------------------------------- copy y into ycin[:, 0:256] (stride 768)
__global__ __launch_bounds__(256) void copy_ycin_kernel(
    const bf16* __restrict__ y, bf16* __restrict__ ycin)
{
    int idx = blockIdx.x * 256 + threadIdx.x;
    int n = idx >> 8, j = idx & 255;
    ycin[(size_t)n * 768 + j] = y[idx];
}

// ---------------------------------------------------------------- tiled dual attention (bf16 in, bf16 out, fp32 math)
__global__ __launch_bounds__(256) void attn_kernel(
    const bf16* __restrict__ y,    // (B,TT,256) q = k
    const bf16* __restrict__ st,   // v1
    const bf16* __restrict__ sf,   // v2
    bf16* __restrict__ ycin)       // (B,TT,768), writes cols 256..767
{
    __shared__ float Qs[64][33];
    __shared__ float Ks[64][33];
    __shared__ float V1s[64][33];
    __shared__ float V2s[64][33];
    __shared__ float sc[64][65];

    const int bid = blockIdx.x;          // ((b*8)+h)*8 + qt
    const int qt = bid & 7;
    const int h  = (bid >> 3) & 7;
    const int b  = bid >> 6;
    const int tx = threadIdx.x;
    const int q0 = qt * 64;

    const bf16* ybase  = y  + (size_t)(b * TT) * 256 + h * 32;
    const bf16* v1base = st + (size_t)(b * TT) * 256 + h * 32;
    const bf16* v2base = sf + (size_t)(b * TT) * 256 + h * 32;

    // stage Q tile (64x32): 4 threads per row, 8 bf16 each (16B load)
    {
        int r = tx >> 2, c = (tx & 3) * 8;
        int qg = q0 + r;
        if (qg < TT) {
            short8 v = *(const short8*)(ybase + (size_t)qg * 256 + c);
            #pragma unroll
            for (int i = 0; i < 8; ++i) Qs[r][c + i] = bf2f_bits(v[i]);
        } else {
            #pragma unroll
            for (int i = 0; i < 8; ++i) Qs[r][c + i] = 0.f;
        }
    }

    const int q_l  = tx >> 2;
    const int part = tx & 3;
    const int dsel = part & 1;
    const int vsel = part >> 1;
    float m = -INFINITY, l = 0.f;
    float o[16];
    #pragma unroll
    for (int i = 0; i < 16; ++i) o[i] = 0.f;

    const int tr = (tx >> 4) << 2;
    const int tc = (tx & 15) << 2;
    const float scale = 0.17677669529663687f;   // 1/sqrt(32)

    const int nkt = (qt == 0) ? 8 : (qt + 1);
    for (int kt = 0; kt < nkt; ++kt) {
        const int k0 = kt * 64;
        __syncthreads();
        {
            int r = tx >> 2, c = (tx & 3) * 8;
            int kg = k0 + r;
            if (kg < TT) {
                short8 a = *(const short8*)(ybase  + (size_t)kg * 256 + c);
                short8 b1 = *(const short8*)(v1base + (size_t)kg * 256 + c);
                short8 c1 = *(const short8*)(v2base + (size_t)kg * 256 + c);
                #pragma unroll
                for (int i = 0; i < 8; ++i) {
                    Ks[r][c + i]  = bf2f_bits(a[i]);
                    V1s[r][c + i] = bf2f_bits(b1[i]);
                    V2s[r][c + i] = bf2f_bits(c1[i]);
                }
            } else {
                #pragma unroll
                for (int i = 0; i < 8; ++i) { Ks[r][c+i]=0.f; V1s[r][c+i]=0.f; V2s[r][c+i]=0.f; }
            }
        }
        __syncthreads();
        float acc[4][4] = {};
        #pragma unroll
        for (int j = 0; j < 32; ++j) {
            float a0 = Qs[tr][j], a1 = Qs[tr+1][j], a2 = Qs[tr+2][j], a3 = Qs[tr+3][j];
            float b0 = Ks[tc][j], b1 = Ks[tc+1][j], b2 = Ks[tc+2][j], b3 = Ks[tc+3][j];
            acc[0][0] += a0*b0; acc[0][1] += a0*b1; acc[0][2] += a0*b2; acc[0][3] += a0*b3;
            acc[1][0] += a1*b0; acc[1][1] += a1*b1; acc[1][2] += a1*b2; acc[1][3] += a1*b3;
            acc[2][0] += a2*b0; acc[2][1] += a2*b1; acc[2][2] += a2*b2; acc[2][3] += a2*b3;
            acc[3][0] += a3*b0; acc[3][1] += a3*b1; acc[3][2] += a3*b2; acc[3][3] += a3*b3;
        }
        #pragma unroll
        for (int i = 0; i < 4; ++i) {
            int qq = q0 + tr + i;
            #pragma unroll
            for (int j = 0; j < 4; ++j) {
                int kk = k0 + tc + j;
                float s;
                if (kk < qq)      s = acc[i][j] * scale;
                else if (kk < TT) s = -1e9f;
                else              s = -INFINITY;
                sc[tr + i][tc + j] = s;
            }
        }
        __syncthreads();
        float pv[16];
        float tm = -INFINITY;
        #pragma unroll
        for (int i = 0; i < 16; ++i) { pv[i] = sc[q_l][part * 16 + i]; tm = fmaxf(tm, pv[i]); }
        tm = fmaxf(tm, __shfl_xor(tm, 1));
        tm = fmaxf(tm, __shfl_xor(tm, 2));
        float mn = fmaxf(m, tm);
        float rescale = expf(m - mn);
        float ts = 0.f;
        #pragma unroll
        for (int i = 0; i < 16; ++i) { float e = expf(pv[i] - mn); pv[i] = e; ts += e; }
        #pragma unroll
        for (int i = 0; i < 16; ++i) sc[q_l][part * 16 + i] = pv[i];
        ts += __shfl_xor(ts, 1);
        ts += __shfl_xor(ts, 2);
        l = l * rescale + ts;
        m = mn;
        #pragma unroll
        for (int i = 0; i < 16; ++i) o[i] *= rescale;
        __syncthreads();
        const float (*Vs)[33] = vsel ? V2s : V1s;
        const int dbase = dsel * 16;
        for (int k = 0; k < 64; ++k) {
            float p = sc[q_l][k];
            #pragma unroll
            for (int i = 0; i < 16; ++i) o[i] += p * Vs[k][dbase + i];
        }
    }

    int qg = q0 + q_l;
    if (qg < TT) {
        float inv = 1.0f / l;
        int col = 256 + vsel * 256 + h * 32 + dsel * 16;
        bf16* dst = ycin + (size_t)(b * TT + qg) * 768 + col;
        #pragma unroll
        for (int i = 0; i < 16; ++i) dst[i] = __float2bfloat16(o[i] * inv);
    }
}

// ---------------------------------------------------------------- gathered logit + sigmoid
__global__ __launch_bounds__(256) void pred_kernel(
    const float* __restrict__ yc,     // (NTOK,256)
    const int* __restrict__ skills,
    const float* __restrict__ outW,   // (500,256)
    const float* __restrict__ outB,   // (500)
    float* __restrict__ out)          // (NTOK)
{
    int n = blockIdx.x * 4 + (threadIdx.x >> 6);
    if (n >= NTOK) return;
    int lane = threadIdx.x & 63;
    int b = n / TT, t = n % TT;
    int c = skills[b * SEQL + t + 1];            // cshft
    const float* wrow = outW + (size_t)c * 256;
    const float* xrow = yc + (size_t)n * 256;
    float s = 0.f;
    for (int j = lane; j < 256; j += 64) s += xrow[j] * wrow[j];
    #pragma unroll
    for (int off = 32; off > 0; off >>= 1) s += __shfl_down(s, off);
    if (lane == 0) out[n] = 1.0f / (1.0f + expf(-(s + outB[c])));
}

// ---------------------------------------------------------------- host
static inline void gemmb(const bf16* A, int lda, const bf16* W, const float* bias,
                         bf16* C, int ldc, int M, int N, int K, int act, hipStream_t s)
{
    dim3 g(N / 128, (M + 127) / 128), b(256);
    switch (act) {
        case 0: gemm_mfma<0, bf16><<<g, b, 0, s>>>(A, lda, W, bias, C, ldc, M, N, K); break;
        case 1: gemm_mfma<1, bf16><<<g, b, 0, s>>>(A, lda, W, bias, C, ldc, M, N, K); break;
        case 3: gemm_mfma<3, bf16><<<g, b, 0, s>>>(A, lda, W, bias, C, ldc, M, N, K); break;
    }
}

extern "C" void kernel_launch(void* const* d_in, const int* in_sizes, int n_in,
                              void* d_out, int out_size, void* d_ws, size_t ws_size,
                              hipStream_t stream)
{
    const int*   skills    = (const int*)d_in[0];
    const int*   responses = (const int*)d_in[2];
    const float* embC  = (const float*)d_in[3];
    const float* embA  = (const float*)d_in[4];
    const float* embT  = (const float*)d_in[5];
    const float* embF  = (const float*)d_in[6];
    const float* mlpW1 = (const float*)d_in[9];
    const float* mlpb1 = (const float*)d_in[10];
    const float* mlpW2 = (const float*)d_in[11];
    const float* mlpb2 = (const float*)d_in[12];
    const float* inW   = (const float*)d_in[13];
    const float* convW = (const float*)d_in[14];
    const float* convb = (const float*)d_in[15];
    const float* xpW   = (const float*)d_in[16];
    const float* dtW   = (const float*)d_in[17];
    const float* dtb   = (const float*)d_in[18];
    const float* Alog  = (const float*)d_in[19];
    const float* Dp    = (const float*)d_in[20];
    const float* opW   = (const float*)d_in[21];
    const float* mnw   = (const float*)d_in[22];
    const float* fW1   = (const float*)d_in[23];
    const float* fb1   = (const float*)d_in[24];
    const float* fW2   = (const float*)d_in[25];
    const float* fb2   = (const float*)d_in[26];
    const float* fnw   = (const float*)d_in[27];
    const float* finW  = (const float*)d_in[28];
    const float* finb  = (const float*)d_in[29];
    const float* outW  = (const float*)d_in[30];
    const float* outb  = (const float*)d_in[31];

    const size_t NT = NTOK;
    // fp32 region
    float* t1   = (float*)d_ws;          // NT*256 (final gemm out)
    float* dt   = t1 + NT * 256;         // NT*512
    float* xdbl = dt + NT * 512;         // NT*48
    // bf16 region
    bf16* y    = (bf16*)(xdbl + NT * 48);
    bf16* st   = y    + NT * 256;
    bf16* sf   = st   + NT * 256;
    bf16* h1   = sf   + NT * 256;
    bf16* thid = h1   + NT * 256;        // temp (mlp hidden / outproj / ffn2 out)
    bf16* bufA = thid + NT * 256;        // NT*1024: xz / ffnmid / ycin(768)
    bf16* xc   = bufA + NT * 1024;       // NT*512
    bf16* ym   = xc   + NT * 512;        // NT*512
    // bf16 weights
    bf16* wMlp1 = ym    + NT * 512;      // 65536
    bf16* wMlp2 = wMlp1 + 65536;         // 65536
    bf16* wIn   = wMlp2 + 65536;         // 2*262144
    bf16* wOp   = wIn   + 2 * 262144;    // 2*131072
    bf16* wF1   = wOp   + 2 * 131072;    // 2*262144
    bf16* wF2   = wF1   + 2 * 262144;    // 2*262144
    bf16* wFin  = wF2   + 2 * 262144;    // 196608

    // 0) weight conversions
    f2bf_kernel<<<(65536 + 255) / 256, 256, 0, stream>>>(mlpW1, wMlp1, 65536);
    f2bf_kernel<<<(65536 + 255) / 256, 256, 0, stream>>>(mlpW2, wMlp2, 65536);
    f2bf_kernel<<<(524288 + 255) / 256, 256, 0, stream>>>(inW, wIn, 524288);
    f2bf_kernel<<<(262144 + 255) / 256, 256, 0, stream>>>(opW, wOp, 262144);
    f2bf_kernel<<<(524288 + 255) / 256, 256, 0, stream>>>(fW1, wF1, 524288);
    f2bf_kernel<<<(524288 + 255) / 256, 256, 0, stream>>>(fW2, wF2, 524288);
    f2bf_kernel<<<(196608 + 255) / 256, 256, 0, stream>>>(finW, wFin, 196608);

    // 1) embeddings
    embed_kernel<<<NTOK, 256, 0, stream>>>(skills, responses, embC, embA, embT, embF, y, st, sf);

    // 2) three MLPs (tanh hidden)
    gemmb(y,  256, wMlp1, mlpb1, thid, 256, NTOK, 256, 256, 1, stream);
    gemmb(thid, 256, wMlp2, mlpb2, y,  256, NTOK, 256, 256, 0, stream);
    gemmb(st, 256, wMlp1, mlpb1, thid, 256, NTOK, 256, 256, 1, stream);
    gemmb(thid, 256, wMlp2, mlpb2, st, 256, NTOK, 256, 256, 0, stream);
    gemmb(sf, 256, wMlp1, mlpb1, thid, 256, NTOK, 256, 256, 1, stream);
    gemmb(thid, 256, wMlp2, mlpb2, sf, 256, NTOK, 256, 256, 0, stream);

    // 3) two mamba layers
    for (int i = 0; i < 2; ++i) {
        gemmb(y, 256, wIn + (size_t)i * 262144, nullptr, bufA, 1024, NTOK, 1024, 256, 0, stream);
        conv_silu_kernel<<<(NTOK * 512) / 256, 256, 0, stream>>>(bufA, convW + i * 2048, convb + i * 512, xc);
        {   // xproj: N=48, VALU path, bf16 A
            dim3 g((48 + 63) / 64, (NTOK + 63) / 64);
            gemm_kernel<0, bf16><<<g, 256, 0, stream>>>(xc, 512, xpW + (size_t)i * 48 * 512, nullptr, xdbl, 48, NTOK, 48, 512);
        }
        {   // dtproj: K=16, VALU path, fp32 A, softplus
            dim3 g((512 + 63) / 64, (NTOK + 63) / 64);
            gemm_kernel<2, float><<<g, 256, 0, stream>>>(xdbl, 48, dtW + (size_t)i * 512 * 16, dtb + i * 512, dt, 512, NTOK, 512, 16);
        }
        scan_kernel<<<(BATCH * 512) / 256, 256, 0, stream>>>(dt, xc, xdbl, bufA, Alog + i * 8192, Dp + i * 512, ym);
        gemmb(ym, 512, wOp + (size_t)i * 131072, nullptr, thid, 256, NTOK, 256, 512, 0, stream);
        rmsnorm_kernel<<<NTOK, 256, 0, stream>>>(thid, y, mnw + i * 256, h1);
        gemmb(h1, 256, wF1 + (size_t)i * 262144, fb1 + i * 1024, bufA, 1024, NTOK, 1024, 256, 3, stream);
        gemmb(bufA, 1024, wF2 + (size_t)i * 262144, fb2 + i * 256, thid, 256, NTOK, 256, 1024, 0, stream);
        rmsnorm_kernel<<<NTOK, 256, 0, stream>>>(thid, h1, fnw + i * 256, y);
    }

    // 4) dual attention into ycin = bufA (stride 768)
    copy_ycin_kernel<<<NTOK, 256, 0, stream>>>(y, bufA);
    attn_kernel<<<BATCH * 8 * 8, 256, 0, stream>>>(y, st, sf, bufA);

    // 5) final projection + gathered sigmoid
    {
        dim3 g(256 / 128, (NTOK + 127) / 128);
        gemm_mfma<0, float><<<g, 256, 0, stream>>>(bufA, 768, wFin, finb, t1, 256, NTOK, 256, 768);
    }
    pred_kernel<<<NTOK / 4, 256, 0, stream>>>(t1, skills, outW, outb, (float*)d_out);
}

// Round 4
// 2328.025 us; speedup vs baseline: 2.4522x; 1.2667x over previous
//
#include <hip/hip_runtime.h>
#include <hip/hip_bf16.h>
#include <math.h>
#include <string.h>

#define BATCH 32
#define SEQL  512
#define TT    511          // T = L-1
#define DMODEL 256
#define DIN   512          // DI = EXP*D
#define DSN   16           // DS
#define NSK   500
#define NTOK  (BATCH*TT)   // 16352

typedef __hip_bfloat16 bf16;
typedef __attribute__((ext_vector_type(8))) short short8;
typedef __attribute__((ext_vector_type(4))) float f32x4;

__device__ inline float bf2f_bits(short s) {
    unsigned int u = ((unsigned int)(unsigned short)s) << 16;
    float f; memcpy(&f, &u, 4); return f;
}

// ---------------------------------------------------------------- fp32 -> bf16 weight conversion
__global__ __launch_bounds__(256) void f2bf_kernel(const float* __restrict__ in, bf16* __restrict__ out, int n)
{
    int i = blockIdx.x * 256 + threadIdx.x;
    if (i < n) out[i] = __float2bfloat16(in[i]);
}

// ---------------------------------------------------------------- embeddings (bf16 out)
__global__ __launch_bounds__(256) void embed_kernel(
    const int* __restrict__ skills, const int* __restrict__ responses,
    const float* __restrict__ embC, const float* __restrict__ embA,
    const float* __restrict__ embT, const float* __restrict__ embF,
    bf16* __restrict__ o_state, bf16* __restrict__ o_st, bf16* __restrict__ o_sf)
{
    int idx = blockIdx.x * 256 + threadIdx.x;      // < NTOK*256
    int n = idx >> 8, j = idx & 255;
    int b = n / TT, t = n % TT;
    int c = skills[b * SEQL + t];
    int r = responses[b * SEQL + t];
    r = (r > -1) ? r : 0;                          // masked_r
    o_state[idx] = __float2bfloat16(embA[r * DMODEL + j] + embC[c * DMODEL + j]);
    o_st[idx]    = __float2bfloat16(embT[(r * (c + NSK)) * DMODEL + j]);
    o_sf[idx]    = __float2bfloat16(embF[(c * (1 - r)) * DMODEL + j]);
}

// ---------------------------------------------------------------- MFMA bf16 GEMM
// C[M,N] = act(A[M,K](lda,bf16) @ W[N,K]^T(bf16) + bias[N]); K%32==0, N%128==0
template<int ACT, typename OUTT>   // ACT: 0 none, 1 tanh, 3 gelu-exact
__global__ __launch_bounds__(256) void gemm_mfma(
    const bf16* __restrict__ A, int lda,
    const bf16* __restrict__ W,
    const float* __restrict__ bias,
    OUTT* __restrict__ C, int ldc,
    int M, int N, int K)
{
    __shared__ short As[128 * 40];
    __shared__ short Ws[128 * 40];
    const int tx = threadIdx.x;
    const int lane = tx & 63;
    const int wv = tx >> 6;
    const int rowBase = blockIdx.y * 128;
    const int colBase = blockIdx.x * 128;
    const int wrb = (wv >> 1) * 64;
    const int wcb = (wv & 1) * 64;

    f32x4 acc[4][4];
    #pragma unroll
    for (int m = 0; m < 4; ++m)
        #pragma unroll
        for (int n = 0; n < 4; ++n)
            acc[m][n] = (f32x4){0.f, 0.f, 0.f, 0.f};

    const int srow = tx >> 1;
    const int scol = (tx & 1) * 16;
    const bool arow_ok = (rowBase + srow) < M;
    const bf16* Ag = A + (size_t)(rowBase + srow) * lda + scol;
    const bf16* Wg = W + (size_t)(colBase + srow) * K + scol;

    const int kq = (lane >> 4) * 8;      // k-offset of this lane's 8 elems
    const int rl = lane & 15;            // row (A) / col (W) within fragment

    for (int k0 = 0; k0 < K; k0 += 32) {
        short8 av0 = {}, av1 = {};
        if (arow_ok) {
            av0 = *(const short8*)(Ag + k0);
            av1 = *(const short8*)(Ag + k0 + 8);
        }
        short8 wv0 = *(const short8*)(Wg + k0);
        short8 wv1 = *(const short8*)(Wg + k0 + 8);
        __syncthreads();                       // previous iter's LDS reads done
        *(short8*)&As[srow * 40 + scol]     = av0;
        *(short8*)&As[srow * 40 + scol + 8] = av1;
        *(short8*)&Ws[srow * 40 + scol]     = wv0;
        *(short8*)&Ws[srow * 40 + scol + 8] = wv1;
        __syncthreads();
        short8 af[4], bfr[4];
        #pragma unroll
        for (int m = 0; m < 4; ++m) af[m]  = *(const short8*)&As[(wrb + m * 16 + rl) * 40 + kq];
        #pragma unroll
        for (int n = 0; n < 4; ++n) bfr[n] = *(const short8*)&Ws[(wcb + n * 16 + rl) * 40 + kq];
        #pragma unroll
        for (int m = 0; m < 4; ++m)
            #pragma unroll
            for (int n = 0; n < 4; ++n)
                acc[m][n] = __builtin_amdgcn_mfma_f32_16x16x32_bf16(af[m], bfr[n], acc[m][n], 0, 0, 0);
    }

    // epilogue: C/D layout col=lane&15, row=(lane>>4)*4+reg  [m89/m91]
    const int rq = (lane >> 4) * 4;
    const int cl = lane & 15;
    #pragma unroll
    for (int m = 0; m < 4; ++m) {
        #pragma unroll
        for (int i = 0; i < 4; ++i) {
            int row = rowBase + wrb + m * 16 + rq + i;
            if (row >= M) continue;
            #pragma unroll
            for (int n = 0; n < 4; ++n) {
                int col = colBase + wcb + n * 16 + cl;
                float x = acc[m][n][i];
                if (bias) x += bias[col];
                if (ACT == 1) x = tanhf(x);
                else if (ACT == 3) x = 0.5f * x * (1.f + erff(x * 0.70710678118654752440f));
                C[(size_t)row * ldc + col] = OUTT(x);
            }
        }
    }
}

// ---------------------------------------------------------------- small VALU GEMM (xproj N=48, dtproj K=16)
__device__ inline float4 loadA4(const float* p) { return *reinterpret_cast<const float4*>(p); }
__device__ inline float4 loadA4(const bf16* p) {
    return make_float4(__bfloat162float(p[0]), __bfloat162float(p[1]),
                       __bfloat162float(p[2]), __bfloat162float(p[3]));
}

template<int ACT, typename TA>   // 0 none, 2 softplus
__global__ __launch_bounds__(256) void gemm_kernel(
    const TA* __restrict__ A, int lda,
    const float* __restrict__ W,
    const float* __restrict__ bias,
    float* __restrict__ C, int ldc,
    int M, int N, int K)
{
    __shared__ float As[64][17];
    __shared__ float Ws[64][17];
    const int tx = threadIdx.x;
    const int rowBase = blockIdx.y * 64;
    const int colBase = blockIdx.x * 64;
    const int lr = tx >> 2;
    const int lk = (tx & 3) << 2;
    const int tr = (tx >> 4) << 2;
    const int tc = (tx & 15) << 2;
    float acc[4][4] = {};

    for (int k0 = 0; k0 < K; k0 += 16) {
        float4 av = make_float4(0.f, 0.f, 0.f, 0.f);
        int ar = rowBase + lr;
        if (ar < M) av = loadA4(A + (size_t)ar * lda + k0 + lk);
        As[lr][lk] = av.x; As[lr][lk + 1] = av.y; As[lr][lk + 2] = av.z; As[lr][lk + 3] = av.w;
        float4 wvv = make_float4(0.f, 0.f, 0.f, 0.f);
        int wr = colBase + lr;
        if (wr < N) wvv = *reinterpret_cast<const float4*>(W + (size_t)wr * K + k0 + lk);
        Ws[lr][lk] = wvv.x; Ws[lr][lk + 1] = wvv.y; Ws[lr][lk + 2] = wvv.z; Ws[lr][lk + 3] = wvv.w;
        __syncthreads();
        #pragma unroll
        for (int k = 0; k < 16; ++k) {
            float a0 = As[tr][k], a1 = As[tr + 1][k], a2 = As[tr + 2][k], a3 = As[tr + 3][k];
            float b0 = Ws[tc][k], b1 = Ws[tc + 1][k], b2 = Ws[tc + 2][k], b3 = Ws[tc + 3][k];
            acc[0][0] += a0 * b0; acc[0][1] += a0 * b1; acc[0][2] += a0 * b2; acc[0][3] += a0 * b3;
            acc[1][0] += a1 * b0; acc[1][1] += a1 * b1; acc[1][2] += a1 * b2; acc[1][3] += a1 * b3;
            acc[2][0] += a2 * b0; acc[2][1] += a2 * b1; acc[2][2] += a2 * b2; acc[2][3] += a2 * b3;
            acc[3][0] += a3 * b0; acc[3][1] += a3 * b1; acc[3][2] += a3 * b2; acc[3][3] += a3 * b3;
        }
        __syncthreads();
    }

    #pragma unroll
    for (int i = 0; i < 4; ++i) {
        int r = rowBase + tr + i;
        if (r >= M) break;
        int cb = colBase + tc;
        if (cb >= N) continue;
        float4 v;
        float* vp = &v.x;
        #pragma unroll
        for (int j = 0; j < 4; ++j) {
            float x = acc[i][j];
            if (bias) x += bias[cb + j];
            if (ACT == 2) x = fmaxf(x, 0.f) + log1pf(expf(-fabsf(x)));   // softplus
            vp[j] = x;
        }
        *reinterpret_cast<float4*>(C + (size_t)r * ldc + cb) = v;
    }
}

// ---------------------------------------------------------------- conv1d(4, causal, depthwise) + silu (bf16 io)
__global__ __launch_bounds__(256) void conv_silu_kernel(
    const bf16* __restrict__ xz,    // (NTOK,1024), xc part = cols 0..511
    const float* __restrict__ cW,   // (512,4)
    const float* __restrict__ cb,   // (512)
    bf16* __restrict__ xc)          // (NTOK,512)
{
    int idx = blockIdx.x * 256 + threadIdx.x;     // < NTOK*512
    int d = idx & 511;
    int n = idx >> 9;
    int b = n / TT, t = n % TT;
    float w0 = cW[d * 4], w1 = cW[d * 4 + 1], w2 = cW[d * 4 + 2], w3 = cW[d * 4 + 3];
    const bf16* base = xz + (size_t)(b * TT) * 1024 + d;
    float acc = cb[d];
    if (t >= 3) acc += w0 * __bfloat162float(base[(size_t)(t - 3) * 1024]);
    if (t >= 2) acc += w1 * __bfloat162float(base[(size_t)(t - 2) * 1024]);
    if (t >= 1) acc += w2 * __bfloat162float(base[(size_t)(t - 1) * 1024]);
    acc += w3 * __bfloat162float(base[(size_t)t * 1024]);
    xc[idx] = __float2bfloat16(acc / (1.f + expf(-acc)));   // silu
}

// ---------------------------------------------------------------- selective scan, state-parallel
// 16 lanes per (b,d): lane s owns state s. y = sum_s h_s*C_s via shfl tree.
// grid = BATCH*512*16/256 = 1024 blocks.
__global__ __launch_bounds__(256) void scan_kernel(
    const float* __restrict__ dt,     // (NTOK,512)
    const bf16* __restrict__ xc,      // (NTOK,512)
    const float* __restrict__ xdbl,   // (NTOK,48): [dtr(16) | B(16) | C(16)]
    const bf16* __restrict__ xz,      // (NTOK,1024): z = cols 512..1023
    const float* __restrict__ Alog,   // (512,16)
    const float* __restrict__ Dpv,    // (512)
    bf16* __restrict__ ym)            // (NTOK,512)
{
    const int gid = (blockIdx.x * 256 + threadIdx.x) >> 4;   // b*512 + d
    const int s = threadIdx.x & 15;
    const int d = gid & 511;
    const int b = gid >> 9;
    const float A = -expf(Alog[d * DSN + s]);
    const float Dv = Dpv[d];
    float h = 0.f;

    const float* dtp  = dt + (size_t)(b * TT) * 512 + d;
    const bf16*  xcp  = xc + (size_t)(b * TT) * 512 + d;
    const bf16*  zzp  = xz + (size_t)(b * TT) * 1024 + 512 + d;
    const float* bcp  = xdbl + (size_t)(b * TT) * 48 + 16 + s;
    bf16* ymp = ym + (size_t)(b * TT) * 512 + d;

    for (int t = 0; t < TT; ++t) {
        float dtt = dtp[(size_t)t * 512];                 // broadcast in group
        float xt  = __bfloat162float(xcp[(size_t)t * 512]);
        float Bs  = bcp[(size_t)t * 48];
        float Cs  = bcp[(size_t)t * 48 + 16];
        h = expf(dtt * A) * h + (dtt * xt) * Bs;
        float yp = h * Cs;
        yp += __shfl_xor(yp, 1);
        yp += __shfl_xor(yp, 2);
        yp += __shfl_xor(yp, 4);
        yp += __shfl_xor(yp, 8);
        if (s == 0) {
            float zz = __bfloat162float(zzp[(size_t)t * 1024]);
            float v = (yp + xt * Dv) * (zz / (1.f + expf(-zz)));
            ymp[(size_t)t * 512] = __float2bfloat16(v);
        }
    }
}

// ---------------------------------------------------------------- rmsnorm(a+b)*w  (bf16 io, fp32 math)
__global__ __launch_bounds__(256) void rmsnorm_kernel(
    const bf16* __restrict__ a, const bf16* __restrict__ b,
    const float* __restrict__ w, bf16* __restrict__ out)
{
    __shared__ float red[256];
    int n = blockIdx.x, j = threadIdx.x;
    float v = __bfloat162float(a[(size_t)n * 256 + j]) + __bfloat162float(b[(size_t)n * 256 + j]);
    red[j] = v * v;
    __syncthreads();
    for (int s = 128; s > 0; s >>= 1) { if (j < s) red[j] += red[j + s]; __syncthreads(); }
    float scale = rsqrtf(red[0] / 256.0f + 1e-12f);
    out[(size_t)n * 256 + j] = __float2bfloat16(v * scale * w[j]);
}

// ---------------------------------------------------------------- copy y into ycin[:, 0:256] (stride 768)
__global__ __launch_bounds__(256) void copy_ycin_kernel(
    const bf16* __restrict__ y, bf16* __restrict__ ycin)
{
    int idx = blockIdx.x * 256 + threadIdx.x;
    int n = idx >> 8, j = idx & 255;
    ycin[(size_t)n * 768 + j] = y[idx];
}

// ---------------------------------------------------------------- tiled dual attention (bf16 in, bf16 out, fp32 math)
__global__ __launch_bounds__(256) void attn_kernel(
    const bf16* __restrict__ y,    // (B,TT,256) q = k
    const bf16* __restrict__ st,   // v1
    const bf16* __restrict__ sf,   // v2
    bf16* __restrict__ ycin)       // (B,TT,768), writes cols 256..767
{
    __shared__ float Qs[64][33];
    __shared__ float Ks[64][33];
    __shared__ float V1s[64][33];
    __shared__ float V2s[64][33];
    __shared__ float sc[64][65];

    const int bid = blockIdx.x;          // ((b*8)+h)*8 + qt
    const int qt = bid & 7;
    const int h  = (bid >> 3) & 7;
    const int b  = bid >> 6;
    const int tx = threadIdx.x;
    const int q0 = qt * 64;

    const bf16* ybase  = y  + (size_t)(b * TT) * 256 + h * 32;
    const bf16* v1base = st + (size_t)(b * TT) * 256 + h * 32;
    const bf16* v2base = sf + (size_t)(b * TT) * 256 + h * 32;

    // stage Q tile (64x32): 4 threads per row, 8 bf16 each (16B load)
    {
        int r = tx >> 2, c = (tx & 3) * 8;
        int qg = q0 + r;
        if (qg < TT) {
            short8 v = *(const short8*)(ybase + (size_t)qg * 256 + c);
            #pragma unroll
            for (int i = 0; i < 8; ++i) Qs[r][c + i] = bf2f_bits(v[i]);
        } else {
            #pragma unroll
            for (int i = 0; i < 8; ++i) Qs[r][c + i] = 0.f;
        }
    }

    const int q_l  = tx >> 2;
    const int part = tx & 3;
    const int dsel = part & 1;
    const int vsel = part >> 1;
    float m = -INFINITY, l = 0.f;
    float o[16];
    #pragma unroll
    for (int i = 0; i < 16; ++i) o[i] = 0.f;

    const int tr = (tx >> 4) << 2;
    const int tc = (tx & 15) << 2;
    const float scale = 0.17677669529663687f;   // 1/sqrt(32)

    const int nkt = (qt == 0) ? 8 : (qt + 1);
    for (int kt = 0; kt < nkt; ++kt) {
        const int k0 = kt * 64;
        __syncthreads();
        {
            int r = tx >> 2, c = (tx & 3) * 8;
            int kg = k0 + r;
            if (kg < TT) {
                short8 a = *(const short8*)(ybase  + (size_t)kg * 256 + c);
                short8 b1 = *(const short8*)(v1base + (size_t)kg * 256 + c);
                short8 c1 = *(const short8*)(v2base + (size_t)kg * 256 + c);
                #pragma unroll
                for (int i = 0; i < 8; ++i) {
                    Ks[r][c + i]  = bf2f_bits(a[i]);
                    V1s[r][c + i] = bf2f_bits(b1[i]);
                    V2s[r][c + i] = bf2f_bits(c1[i]);
                }
            } else {
                #pragma unroll
                for (int i = 0; i < 8; ++i) { Ks[r][c+i]=0.f; V1s[r][c+i]=0.f; V2s[r][c+i]=0.f; }
            }
        }
        __syncthreads();
        float acc[4][4] = {};
        #pragma unroll
        for (int j = 0; j < 32; ++j) {
            float a0 = Qs[tr][j], a1 = Qs[tr+1][j], a2 = Qs[tr+2][j], a3 = Qs[tr+3][j];
            float b0 = Ks[tc][j], b1 = Ks[tc+1][j], b2 = Ks[tc+2][j], b3 = Ks[tc+3][j];
            acc[0][0] += a0*b0; acc[0][1] += a0*b1; acc[0][2] += a0*b2; acc[0][3] += a0*b3;
            acc[1][0] += a1*b0; acc[1][1] += a1*b1; acc[1][2] += a1*b2; acc[1][3] += a1*b3;
            acc[2][0] += a2*b0; acc[2][1] += a2*b1; acc[2][2] += a2*b2; acc[2][3] += a2*b3;
            acc[3][0] += a3*b0; acc[3][1] += a3*b1; acc[3][2] += a3*b2; acc[3][3] += a3*b3;
        }
        #pragma unroll
        for (int i = 0; i < 4; ++i) {
            int qq = q0 + tr + i;
            #pragma unroll
            for (int j = 0; j < 4; ++j) {
                int kk = k0 + tc + j;
                float s;
                if (kk < qq)      s = acc[i][j] * scale;
                else if (kk < TT) s = -1e9f;
                else              s = -INFINITY;
                sc[tr + i][tc + j] = s;
            }
        }
        __syncthreads();
        float pv[16];
        float tm = -INFINITY;
        #pragma unroll
        for (int i = 0; i < 16; ++i) { pv[i] = sc[q_l][part * 16 + i]; tm = fmaxf(tm, pv[i]); }
        tm = fmaxf(tm, __shfl_xor(tm, 1));
        tm = fmaxf(tm, __shfl_xor(tm, 2));
        float mn = fmaxf(m, tm);
        float rescale = expf(m - mn);
        float ts = 0.f;
        #pragma unroll
        for (int i = 0; i < 16; ++i) { float e = expf(pv[i] - mn); pv[i] = e; ts += e; }
        #pragma unroll
        for (int i = 0; i < 16; ++i) sc[q_l][part * 16 + i] = pv[i];
        ts += __shfl_xor(ts, 1);
        ts += __shfl_xor(ts, 2);
        l = l * rescale + ts;
        m = mn;
        #pragma unroll
        for (int i = 0; i < 16; ++i) o[i] *= rescale;
        __syncthreads();
        const float (*Vs)[33] = vsel ? V2s : V1s;
        const int dbase = dsel * 16;
        for (int k = 0; k < 64; ++k) {
            float p = sc[q_l][k];
            #pragma unroll
            for (int i = 0; i < 16; ++i) o[i] += p * Vs[k][dbase + i];
        }
    }

    int qg = q0 + q_l;
    if (qg < TT) {
        float inv = 1.0f / l;
        int col = 256 + vsel * 256 + h * 32 + dsel * 16;
        bf16* dst = ycin + (size_t)(b * TT + qg) * 768 + col;
        #pragma unroll
        for (int i = 0; i < 16; ++i) dst[i] = __float2bfloat16(o[i] * inv);
    }
}

// ---------------------------------------------------------------- gathered logit + sigmoid
__global__ __launch_bounds__(256) void pred_kernel(
    const float* __restrict__ yc,     // (NTOK,256)
    const int* __restrict__ skills,
    const float* __restrict__ outW,   // (500,256)
    const float* __restrict__ outB,   // (500)
    float* __restrict__ out)          // (NTOK)
{
    int n = blockIdx.x * 4 + (threadIdx.x >> 6);
    if (n >= NTOK) return;
    int lane = threadIdx.x & 63;
    int b = n / TT, t = n % TT;
    int c = skills[b * SEQL + t + 1];            // cshft
    const float* wrow = outW + (size_t)c * 256;
    const float* xrow = yc + (size_t)n * 256;
    float s = 0.f;
    for (int j = lane; j < 256; j += 64) s += xrow[j] * wrow[j];
    #pragma unroll
    for (int off = 32; off > 0; off >>= 1) s += __shfl_down(s, off);
    if (lane == 0) out[n] = 1.0f / (1.0f + expf(-(s + outB[c])));
}

// ---------------------------------------------------------------- host
static inline void gemmb(const bf16* A, int lda, const bf16* W, const float* bias,
                         bf16* C, int ldc, int M, int N, int K, int act, hipStream_t s)
{
    dim3 g(N / 128, (M + 127) / 128), b(256);
    switch (act) {
        case 0: gemm_mfma<0, bf16><<<g, b, 0, s>>>(A, lda, W, bias, C, ldc, M, N, K); break;
        case 1: gemm_mfma<1, bf16><<<g, b, 0, s>>>(A, lda, W, bias, C, ldc, M, N, K); break;
        case 3: gemm_mfma<3, bf16><<<g, b, 0, s>>>(A, lda, W, bias, C, ldc, M, N, K); break;
    }
}

extern "C" void kernel_launch(void* const* d_in, const int* in_sizes, int n_in,
                              void* d_out, int out_size, void* d_ws, size_t ws_size,
                              hipStream_t stream)
{
    const int*   skills    = (const int*)d_in[0];
    const int*   responses = (const int*)d_in[2];
    const float* embC  = (const float*)d_in[3];
    const float* embA  = (const float*)d_in[4];
    const float* embT  = (const float*)d_in[5];
    const float* embF  = (const float*)d_in[6];
    const float* mlpW1 = (const float*)d_in[9];
    const float* mlpb1 = (const float*)d_in[10];
    const float* mlpW2 = (const float*)d_in[11];
    const float* mlpb2 = (const float*)d_in[12];
    const float* inW   = (const float*)d_in[13];
    const float* convW = (const float*)d_in[14];
    const float* convb = (const float*)d_in[15];
    const float* xpW   = (const float*)d_in[16];
    const float* dtW   = (const float*)d_in[17];
    const float* dtb   = (const float*)d_in[18];
    const float* Alog  = (const float*)d_in[19];
    const float* Dp    = (const float*)d_in[20];
    const float* opW   = (const float*)d_in[21];
    const float* mnw   = (const float*)d_in[22];
    const float* fW1   = (const float*)d_in[23];
    const float* fb1   = (const float*)d_in[24];
    const float* fW2   = (const float*)d_in[25];
    const float* fb2   = (const float*)d_in[26];
    const float* fnw   = (const float*)d_in[27];
    const float* finW  = (const float*)d_in[28];
    const float* finb  = (const float*)d_in[29];
    const float* outW  = (const float*)d_in[30];
    const float* outb  = (const float*)d_in[31];

    const size_t NT = NTOK;
    // fp32 region
    float* t1   = (float*)d_ws;          // NT*256 (final gemm out)
    float* dt   = t1 + NT * 256;         // NT*512
    float* xdbl = dt + NT * 512;         // NT*48
    // bf16 region
    bf16* y    = (bf16*)(xdbl + NT * 48);
    bf16* st   = y    + NT * 256;
    bf16* sf   = st   + NT * 256;
    bf16* h1   = sf   + NT * 256;
    bf16* thid = h1   + NT * 256;        // temp (mlp hidden / outproj / ffn2 out)
    bf16* bufA = thid + NT * 256;        // NT*1024: xz / ffnmid / ycin(768)
    bf16* xc   = bufA + NT * 1024;       // NT*512
    bf16* ym   = xc   + NT * 512;        // NT*512
    // bf16 weights
    bf16* wMlp1 = ym    + NT * 512;      // 65536
    bf16* wMlp2 = wMlp1 + 65536;         // 65536
    bf16* wIn   = wMlp2 + 65536;         // 2*262144
    bf16* wOp   = wIn   + 2 * 262144;    // 2*131072
    bf16* wF1   = wOp   + 2 * 131072;    // 2*262144
    bf16* wF2   = wF1   + 2 * 262144;    // 2*262144
    bf16* wFin  = wF2   + 2 * 262144;    // 196608

    // 0) weight conversions
    f2bf_kernel<<<(65536 + 255) / 256, 256, 0, stream>>>(mlpW1, wMlp1, 65536);
    f2bf_kernel<<<(65536 + 255) / 256, 256, 0, stream>>>(mlpW2, wMlp2, 65536);
    f2bf_kernel<<<(524288 + 255) / 256, 256, 0, stream>>>(inW, wIn, 524288);
    f2bf_kernel<<<(262144 + 255) / 256, 256, 0, stream>>>(opW, wOp, 262144);
    f2bf_kernel<<<(524288 + 255) / 256, 256, 0, stream>>>(fW1, wF1, 524288);
    f2bf_kernel<<<(524288 + 255) / 256, 256, 0, stream>>>(fW2, wF2, 524288);
    f2bf_kernel<<<(196608 + 255) / 256, 256, 0, stream>>>(finW, wFin, 196608);

    // 1) embeddings
    embed_kernel<<<NTOK, 256, 0, stream>>>(skills, responses, embC, embA, embT, embF, y, st, sf);

    // 2) three MLPs (tanh hidden)
    gemmb(y,  256, wMlp1, mlpb1, thid, 256, NTOK, 256, 256, 1, stream);
    gemmb(thid, 256, wMlp2, mlpb2, y,  256, NTOK, 256, 256, 0, stream);
    gemmb(st, 256, wMlp1, mlpb1, thid, 256, NTOK, 256, 256, 1, stream);
    gemmb(thid, 256, wMlp2, mlpb2, st, 256, NTOK, 256, 256, 0, stream);
    gemmb(sf, 256, wMlp1, mlpb1, thid, 256, NTOK, 256, 256, 1, stream);
    gemmb(thid, 256, wMlp2, mlpb2, sf, 256, NTOK, 256, 256, 0, stream);

    // 3) two mamba layers
    for (int i = 0; i < 2; ++i) {
        gemmb(y, 256, wIn + (size_t)i * 262144, nullptr, bufA, 1024, NTOK, 1024, 256, 0, stream);
        conv_silu_kernel<<<(NTOK * 512) / 256, 256, 0, stream>>>(bufA, convW + i * 2048, convb + i * 512, xc);
        {   // xproj: N=48, VALU path, bf16 A
            dim3 g((48 + 63) / 64, (NTOK + 63) / 64);
            gemm_kernel<0, bf16><<<g, 256, 0, stream>>>(xc, 512, xpW + (size_t)i * 48 * 512, nullptr, xdbl, 48, NTOK, 48, 512);
        }
        {   // dtproj: K=16, VALU path, fp32 A, softplus
            dim3 g((512 + 63) / 64, (NTOK + 63) / 64);
            gemm_kernel<2, float><<<g, 256, 0, stream>>>(xdbl, 48, dtW + (size_t)i * 512 * 16, dtb + i * 512, dt, 512, NTOK, 512, 16);
        }
        scan_kernel<<<(BATCH * 512 * 16) / 256, 256, 0, stream>>>(dt, xc, xdbl, bufA, Alog + i * 8192, Dp + i * 512, ym);
        gemmb(ym, 512, wOp + (size_t)i * 131072, nullptr, thid, 256, NTOK, 256, 512, 0, stream);
        rmsnorm_kernel<<<NTOK, 256, 0, stream>>>(thid, y, mnw + i * 256, h1);
        gemmb(h1, 256, wF1 + (size_t)i * 262144, fb1 + i * 1024, bufA, 1024, NTOK, 1024, 256, 3, stream);
        gemmb(bufA, 1024, wF2 + (size_t)i * 262144, fb2 + i * 256, thid, 256, NTOK, 256, 1024, 0, stream);
        rmsnorm_kernel<<<NTOK, 256, 0, stream>>>(thid, h1, fnw + i * 256, y);
    }

    // 4) dual attention into ycin = bufA (stride 768)
    copy_ycin_kernel<<<NTOK, 256, 0, stream>>>(y, bufA);
    attn_kernel<<<BATCH * 8 * 8, 256, 0, stream>>>(y, st, sf, bufA);

    // 5) final projection + gathered sigmoid
    {
        dim3 g(256 / 128, (NTOK + 127) / 128);
        gemm_mfma<0, float><<<g, 256, 0, stream>>>(bufA, 768, wFin, finb, t1, 256, NTOK, 256, 768);
    }
    pred_kernel<<<NTOK / 4, 256, 0, stream>>>(t1, skills, outW, outb, (float*)d_out);
}

// Round 5
// 1707.423 us; speedup vs baseline: 3.3435x; 1.3635x over previous
//
#include <hip/hip_runtime.h>
#include <hip/hip_bf16.h>
#include <math.h>
#include <string.h>

#define BATCH 32
#define SEQL  512
#define TT    511          // T = L-1
#define DMODEL 256
#define DIN   512          // DI = EXP*D
#define DSN   16           // DS
#define NSK   500
#define NTOK  (BATCH*TT)   // 16352

typedef __hip_bfloat16 bf16;
typedef __attribute__((ext_vector_type(8))) short short8;
typedef __attribute__((ext_vector_type(4))) float f32x4;

__device__ inline unsigned pack_bf2(float a, float b) {
    bf16 ba = __float2bfloat16(a), bb = __float2bfloat16(b);
    unsigned short ua, ub; memcpy(&ua, &ba, 2); memcpy(&ub, &bb, 2);
    return (unsigned)ua | ((unsigned)ub << 16);
}

// ---------------------------------------------------------------- fp32 -> bf16 weight conversion
__global__ __launch_bounds__(256) void f2bf_kernel(const float* __restrict__ in, bf16* __restrict__ out, int n)
{
    int i = blockIdx.x * 256 + threadIdx.x;
    if (i < n) out[i] = __float2bfloat16(in[i]);
}

// ---------------------------------------------------------------- embeddings (bf16 out)
__global__ __launch_bounds__(256) void embed_kernel(
    const int* __restrict__ skills, const int* __restrict__ responses,
    const float* __restrict__ embC, const float* __restrict__ embA,
    const float* __restrict__ embT, const float* __restrict__ embF,
    bf16* __restrict__ o_state, bf16* __restrict__ o_st, bf16* __restrict__ o_sf)
{
    int idx = blockIdx.x * 256 + threadIdx.x;      // < NTOK*256
    int n = idx >> 8, j = idx & 255;
    int b = n / TT, t = n % TT;
    int c = skills[b * SEQL + t];
    int r = responses[b * SEQL + t];
    r = (r > -1) ? r : 0;                          // masked_r
    o_state[idx] = __float2bfloat16(embA[r * DMODEL + j] + embC[c * DMODEL + j]);
    o_st[idx]    = __float2bfloat16(embT[(r * (c + NSK)) * DMODEL + j]);
    o_sf[idx]    = __float2bfloat16(embF[(c * (1 - r)) * DMODEL + j]);
}

// ---------------------------------------------------------------- MFMA bf16 GEMM
// C[M,N] = act(A[M,K](lda,bf16) @ W[N,K]^T(bf16) + bias[N]); K%32==0, N%128==0
template<int ACT, typename OUTT>   // ACT: 0 none, 1 tanh, 3 gelu-exact
__global__ __launch_bounds__(256) void gemm_mfma(
    const bf16* __restrict__ A, int lda,
    const bf16* __restrict__ W,
    const float* __restrict__ bias,
    OUTT* __restrict__ C, int ldc,
    int M, int N, int K)
{
    __shared__ short As[128 * 40];
    __shared__ short Ws[128 * 40];
    const int tx = threadIdx.x;
    const int lane = tx & 63;
    const int wv = tx >> 6;
    const int rowBase = blockIdx.y * 128;
    const int colBase = blockIdx.x * 128;
    const int wrb = (wv >> 1) * 64;
    const int wcb = (wv & 1) * 64;

    f32x4 acc[4][4];
    #pragma unroll
    for (int m = 0; m < 4; ++m)
        #pragma unroll
        for (int n = 0; n < 4; ++n)
            acc[m][n] = (f32x4){0.f, 0.f, 0.f, 0.f};

    const int srow = tx >> 1;
    const int scol = (tx & 1) * 16;
    const bool arow_ok = (rowBase + srow) < M;
    const bf16* Ag = A + (size_t)(rowBase + srow) * lda + scol;
    const bf16* Wg = W + (size_t)(colBase + srow) * K + scol;

    const int kq = (lane >> 4) * 8;      // k-offset of this lane's 8 elems
    const int rl = lane & 15;            // row (A) / col (W) within fragment

    for (int k0 = 0; k0 < K; k0 += 32) {
        short8 av0 = {}, av1 = {};
        if (arow_ok) {
            av0 = *(const short8*)(Ag + k0);
            av1 = *(const short8*)(Ag + k0 + 8);
        }
        short8 wv0 = *(const short8*)(Wg + k0);
        short8 wv1 = *(const short8*)(Wg + k0 + 8);
        __syncthreads();                       // previous iter's LDS reads done
        *(short8*)&As[srow * 40 + scol]     = av0;
        *(short8*)&As[srow * 40 + scol + 8] = av1;
        *(short8*)&Ws[srow * 40 + scol]     = wv0;
        *(short8*)&Ws[srow * 40 + scol + 8] = wv1;
        __syncthreads();
        short8 af[4], bfr[4];
        #pragma unroll
        for (int m = 0; m < 4; ++m) af[m]  = *(const short8*)&As[(wrb + m * 16 + rl) * 40 + kq];
        #pragma unroll
        for (int n = 0; n < 4; ++n) bfr[n] = *(const short8*)&Ws[(wcb + n * 16 + rl) * 40 + kq];
        #pragma unroll
        for (int m = 0; m < 4; ++m)
            #pragma unroll
            for (int n = 0; n < 4; ++n)
                acc[m][n] = __builtin_amdgcn_mfma_f32_16x16x32_bf16(af[m], bfr[n], acc[m][n], 0, 0, 0);
    }

    // epilogue: C/D layout col=lane&15, row=(lane>>4)*4+reg  [m89/m91]
    const int rq = (lane >> 4) * 4;
    const int cl = lane & 15;
    #pragma unroll
    for (int m = 0; m < 4; ++m) {
        #pragma unroll
        for (int i = 0; i < 4; ++i) {
            int row = rowBase + wrb + m * 16 + rq + i;
            if (row >= M) continue;
            #pragma unroll
            for (int n = 0; n < 4; ++n) {
                int col = colBase + wcb + n * 16 + cl;
                float x = acc[m][n][i];
                if (bias) x += bias[col];
                if (ACT == 1) x = tanhf(x);
                else if (ACT == 3) x = 0.5f * x * (1.f + erff(x * 0.70710678118654752440f));
                C[(size_t)row * ldc + col] = OUTT(x);
            }
        }
    }
}

// ---------------------------------------------------------------- small VALU GEMM (xproj N=48, dtproj K=16)
__device__ inline float4 loadA4(const float* p) { return *reinterpret_cast<const float4*>(p); }
__device__ inline float4 loadA4(const bf16* p) {
    return make_float4(__bfloat162float(p[0]), __bfloat162float(p[1]),
                       __bfloat162float(p[2]), __bfloat162float(p[3]));
}

template<int ACT, typename TA>   // 0 none, 2 softplus
__global__ __launch_bounds__(256) void gemm_kernel(
    const TA* __restrict__ A, int lda,
    const float* __restrict__ W,
    const float* __restrict__ bias,
    float* __restrict__ C, int ldc,
    int M, int N, int K)
{
    __shared__ float As[64][17];
    __shared__ float Ws[64][17];
    const int tx = threadIdx.x;
    const int rowBase = blockIdx.y * 64;
    const int colBase = blockIdx.x * 64;
    const int lr = tx >> 2;
    const int lk = (tx & 3) << 2;
    const int tr = (tx >> 4) << 2;
    const int tc = (tx & 15) << 2;
    float acc[4][4] = {};

    for (int k0 = 0; k0 < K; k0 += 16) {
        float4 av = make_float4(0.f, 0.f, 0.f, 0.f);
        int ar = rowBase + lr;
        if (ar < M) av = loadA4(A + (size_t)ar * lda + k0 + lk);
        As[lr][lk] = av.x; As[lr][lk + 1] = av.y; As[lr][lk + 2] = av.z; As[lr][lk + 3] = av.w;
        float4 wvv = make_float4(0.f, 0.f, 0.f, 0.f);
        int wr = colBase + lr;
        if (wr < N) wvv = *reinterpret_cast<const float4*>(W + (size_t)wr * K + k0 + lk);
        Ws[lr][lk] = wvv.x; Ws[lr][lk + 1] = wvv.y; Ws[lr][lk + 2] = wvv.z; Ws[lr][lk + 3] = wvv.w;
        __syncthreads();
        #pragma unroll
        for (int k = 0; k < 16; ++k) {
            float a0 = As[tr][k], a1 = As[tr + 1][k], a2 = As[tr + 2][k], a3 = As[tr + 3][k];
            float b0 = Ws[tc][k], b1 = Ws[tc + 1][k], b2 = Ws[tc + 2][k], b3 = Ws[tc + 3][k];
            acc[0][0] += a0 * b0; acc[0][1] += a0 * b1; acc[0][2] += a0 * b2; acc[0][3] += a0 * b3;
            acc[1][0] += a1 * b0; acc[1][1] += a1 * b1; acc[1][2] += a1 * b2; acc[1][3] += a1 * b3;
            acc[2][0] += a2 * b0; acc[2][1] += a2 * b1; acc[2][2] += a2 * b2; acc[2][3] += a2 * b3;
            acc[3][0] += a3 * b0; acc[3][1] += a3 * b1; acc[3][2] += a3 * b2; acc[3][3] += a3 * b3;
        }
        __syncthreads();
    }

    #pragma unroll
    for (int i = 0; i < 4; ++i) {
        int r = rowBase + tr + i;
        if (r >= M) break;
        int cb = colBase + tc;
        if (cb >= N) continue;
        float4 v;
        float* vp = &v.x;
        #pragma unroll
        for (int j = 0; j < 4; ++j) {
            float x = acc[i][j];
            if (bias) x += bias[cb + j];
            if (ACT == 2) x = fmaxf(x, 0.f) + log1pf(expf(-fabsf(x)));   // softplus
            vp[j] = x;
        }
        *reinterpret_cast<float4*>(C + (size_t)r * ldc + cb) = v;
    }
}

// ---------------------------------------------------------------- conv1d(4, causal, depthwise) + silu (bf16 io)
__global__ __launch_bounds__(256) void conv_silu_kernel(
    const bf16* __restrict__ xz,    // (NTOK,1024), xc part = cols 0..511
    const float* __restrict__ cW,   // (512,4)
    const float* __restrict__ cb,   // (512)
    bf16* __restrict__ xc)          // (NTOK,512)
{
    int idx = blockIdx.x * 256 + threadIdx.x;     // < NTOK*512
    int d = idx & 511;
    int n = idx >> 9;
    int b = n / TT, t = n % TT;
    float w0 = cW[d * 4], w1 = cW[d * 4 + 1], w2 = cW[d * 4 + 2], w3 = cW[d * 4 + 3];
    const bf16* base = xz + (size_t)(b * TT) * 1024 + d;
    float acc = cb[d];
    if (t >= 3) acc += w0 * __bfloat162float(base[(size_t)(t - 3) * 1024]);
    if (t >= 2) acc += w1 * __bfloat162float(base[(size_t)(t - 2) * 1024]);
    if (t >= 1) acc += w2 * __bfloat162float(base[(size_t)(t - 1) * 1024]);
    acc += w3 * __bfloat162float(base[(size_t)t * 1024]);
    xc[idx] = __float2bfloat16(acc / (1.f + expf(-acc)));   // silu
}

// ---------------------------------------------------------------- selective scan, state-parallel
__global__ __launch_bounds__(256) void scan_kernel(
    const float* __restrict__ dt,     // (NTOK,512)
    const bf16* __restrict__ xc,      // (NTOK,512)
    const float* __restrict__ xdbl,   // (NTOK,48): [dtr(16) | B(16) | C(16)]
    const bf16* __restrict__ xz,      // (NTOK,1024): z = cols 512..1023
    const float* __restrict__ Alog,   // (512,16)
    const float* __restrict__ Dpv,    // (512)
    bf16* __restrict__ ym)            // (NTOK,512)
{
    const int gid = (blockIdx.x * 256 + threadIdx.x) >> 4;   // b*512 + d
    const int s = threadIdx.x & 15;
    const int d = gid & 511;
    const int b = gid >> 9;
    const float A = -expf(Alog[d * DSN + s]);
    const float Dv = Dpv[d];
    float h = 0.f;

    const float* dtp  = dt + (size_t)(b * TT) * 512 + d;
    const bf16*  xcp  = xc + (size_t)(b * TT) * 512 + d;
    const bf16*  zzp  = xz + (size_t)(b * TT) * 1024 + 512 + d;
    const float* bcp  = xdbl + (size_t)(b * TT) * 48 + 16 + s;
    bf16* ymp = ym + (size_t)(b * TT) * 512 + d;

    for (int t = 0; t < TT; ++t) {
        float dtt = dtp[(size_t)t * 512];                 // broadcast in group
        float xt  = __bfloat162float(xcp[(size_t)t * 512]);
        float Bs  = bcp[(size_t)t * 48];
        float Cs  = bcp[(size_t)t * 48 + 16];
        h = expf(dtt * A) * h + (dtt * xt) * Bs;
        float yp = h * Cs;
        yp += __shfl_xor(yp, 1);
        yp += __shfl_xor(yp, 2);
        yp += __shfl_xor(yp, 4);
        yp += __shfl_xor(yp, 8);
        if (s == 0) {
            float zz = __bfloat162float(zzp[(size_t)t * 1024]);
            float v = (yp + xt * Dv) * (zz / (1.f + expf(-zz)));
            ymp[(size_t)t * 512] = __float2bfloat16(v);
        }
    }
}

// ---------------------------------------------------------------- rmsnorm(a+b)*w  (bf16 io, fp32 math)
__global__ __launch_bounds__(256) void rmsnorm_kernel(
    const bf16* __restrict__ a, const bf16* __restrict__ b,
    const float* __restrict__ w, bf16* __restrict__ out)
{
    __shared__ float red[256];
    int n = blockIdx.x, j = threadIdx.x;
    float v = __bfloat162float(a[(size_t)n * 256 + j]) + __bfloat162float(b[(size_t)n * 256 + j]);
    red[j] = v * v;
    __syncthreads();
    for (int s = 128; s > 0; s >>= 1) { if (j < s) red[j] += red[j + s]; __syncthreads(); }
    float scale = rsqrtf(red[0] / 256.0f + 1e-12f);
    out[(size_t)n * 256 + j] = __float2bfloat16(v * scale * w[j]);
}

// ---------------------------------------------------------------- copy y into ycin[:, 0:256] (stride 768)
__global__ __launch_bounds__(256) void copy_ycin_kernel(
    const bf16* __restrict__ y, bf16* __restrict__ ycin)
{
    int idx = blockIdx.x * 256 + threadIdx.x;
    int n = idx >> 8, j = idx & 255;
    ycin[(size_t)n * 768 + j] = y[idx];
}

// ---------------------------------------------------------------- MFMA dual flash attention
// Block = 256 thr = 4 waves, one block per (b,h,qt64). Wave w owns q rows
// q0+w*16..+15. Swapped QK^T: S^T = mfma(A=K, B=Q) -> lane's 16 scores all
// belong to q = lane&15 (keys 16*jm+4*g+reg). Softmax: in-lane reduce + 2
// shfl_xor. P -> bf16 -> LDS (stride 88 shorts, 16B-aligned rows, ~2-way
// banks). V staged transposed Vt[d][key] so PV B-frags are contiguous-in-k.
// Exactness: -1e9 mask for k in [q,TT), -INF for phantom k=511; qt==0 runs
// all 8 k-tiles (rows>=1 get exp(-1e9-m)==0 exactly); q==511 lane is
// zero-Q, write-guarded.
__global__ __launch_bounds__(256) void attn_kernel(
    const bf16* __restrict__ y,    // (B,TT,256) q = k
    const bf16* __restrict__ st,   // v1
    const bf16* __restrict__ sf,   // v2
    bf16* __restrict__ ycin)       // (B,TT,768), writes cols 256..767
{
    __shared__ short Ks[64 * 40];      // K[key][d], row stride 40 shorts (80B)
    __shared__ short Vt[2][32 * 88];   // V^T[d][key], row stride 88 shorts (176B)
    __shared__ short Pl[64 * 88];      // P[q][key] bf16, row stride 88 shorts

    const int bid = blockIdx.x;        // ((b*8)+h)*8 + qt
    const int qt = bid & 7;
    const int h  = (bid >> 3) & 7;
    const int b  = bid >> 6;
    const int tx = threadIdx.x;
    const int w  = tx >> 6;            // wave 0..3
    const int lane = tx & 63;
    const int g  = lane >> 4;          // 0..3
    const int l15 = lane & 15;
    const int q0 = qt * 64;
    const int qg = q0 + w * 16 + l15;  // this lane's q row (S^T col)
    const float scale = 0.17677669529663687f;   // 1/sqrt(32)

    const bf16* ybase  = y  + (size_t)(b * TT) * 256 + h * 32;
    const bf16* v1base = st + (size_t)(b * TT) * 256 + h * 32;
    const bf16* v2base = sf + (size_t)(b * TT) * 256 + h * 32;

    // Q fragment (B operand): col=q=lane&15, k-slice d=(lane>>4)*8..+7
    short8 qf = {};
    if (qg < TT) qf = *(const short8*)(ybase + (size_t)qg * 256 + g * 8);

    float m = -INFINITY, l = 0.f;
    f32x4 o[2][2];                     // [v][dsub]
    #pragma unroll
    for (int v = 0; v < 2; ++v) { o[v][0] = (f32x4){0,0,0,0}; o[v][1] = (f32x4){0,0,0,0}; }

    const int sr = tx >> 2;            // staging key row 0..63
    const int sc = (tx & 3) * 8;       // staging d base

    const int nkt = (qt == 0) ? 8 : (qt + 1);
    for (int kt = 0; kt < nkt; ++kt) {
        const int k0 = kt * 64;
        __syncthreads();               // previous tile's LDS reads done
        {
            int kgr = k0 + sr;
            short8 kv = {}, v1v = {}, v2v = {};
            if (kgr < TT) {
                kv  = *(const short8*)(ybase  + (size_t)kgr * 256 + sc);
                v1v = *(const short8*)(v1base + (size_t)kgr * 256 + sc);
                v2v = *(const short8*)(v2base + (size_t)kgr * 256 + sc);
            }
            *(short8*)&Ks[sr * 40 + sc] = kv;
            #pragma unroll
            for (int i = 0; i < 8; ++i) {
                Vt[0][(sc + i) * 88 + sr] = v1v[i];
                Vt[1][(sc + i) * 88 + sr] = v2v[i];
            }
        }
        __syncthreads();

        // S^T[key][q]: 4 mfmas, each 16 keys x 16 q, K=32 (full head dim)
        f32x4 s[4];
        #pragma unroll
        for (int jm = 0; jm < 4; ++jm) {
            short8 kf = *(const short8*)&Ks[(jm * 16 + l15) * 40 + g * 8];
            s[jm] = __builtin_amdgcn_mfma_f32_16x16x32_bf16(kf, qf, (f32x4){0,0,0,0}, 0, 0, 0);
        }
        // mask + tile max (per lane: all 16 values are q=qg)
        float tm = -INFINITY;
        #pragma unroll
        for (int jm = 0; jm < 4; ++jm)
            #pragma unroll
            for (int r = 0; r < 4; ++r) {
                int kk = k0 + jm * 16 + g * 4 + r;
                float sv = s[jm][r];
                sv = (kk < qg) ? sv * scale : ((kk < TT) ? -1e9f : -INFINITY);
                s[jm][r] = sv;
                tm = fmaxf(tm, sv);
            }
        tm = fmaxf(tm, __shfl_xor(tm, 16));
        tm = fmaxf(tm, __shfl_xor(tm, 32));
        float mn = fmaxf(m, tm);
        float rs = expf(m - mn);       // m==-inf -> 0
        m = mn;
        float ts = 0.f;
        #pragma unroll
        for (int jm = 0; jm < 4; ++jm)
            #pragma unroll
            for (int r = 0; r < 4; ++r) {
                float e = expf(s[jm][r] - mn);
                s[jm][r] = e;
                ts += e;
            }
        ts += __shfl_xor(ts, 16);
        ts += __shfl_xor(ts, 32);
        l = l * rs + ts;
        // P -> LDS as bf16 (u32 pair writes; row q, key 16*jm+4*g+{0..3})
        #pragma unroll
        for (int jm = 0; jm < 4; ++jm) {
            *(unsigned*)&Pl[(w * 16 + l15) * 88 + jm * 16 + g * 4]     = pack_bf2(s[jm][0], s[jm][1]);
            *(unsigned*)&Pl[(w * 16 + l15) * 88 + jm * 16 + g * 4 + 2] = pack_bf2(s[jm][2], s[jm][3]);
        }
        // rescale O accs: O row = 4*g+reg -> factor lives in lane (q row)
        float rq[4];
        #pragma unroll
        for (int r = 0; r < 4; ++r) rq[r] = __shfl(rs, 4 * g + r);
        #pragma unroll
        for (int v = 0; v < 2; ++v)
            #pragma unroll
            for (int d = 0; d < 2; ++d)
                #pragma unroll
                for (int r = 0; r < 4; ++r)
                    o[v][d][r] *= rq[r];
        // PV: A = P (row=q=lane&15, k=keys), B = Vt (col=d=lane&15, k=keys)
        #pragma unroll
        for (int ks = 0; ks < 2; ++ks) {
            short8 pf = *(const short8*)&Pl[(w * 16 + l15) * 88 + ks * 32 + g * 8];
            #pragma unroll
            for (int v = 0; v < 2; ++v)
                #pragma unroll
                for (int d = 0; d < 2; ++d) {
                    short8 vf = *(const short8*)&Vt[v][(d * 16 + l15) * 88 + ks * 32 + g * 8];
                    o[v][d] = __builtin_amdgcn_mfma_f32_16x16x32_bf16(pf, vf, o[v][d], 0, 0, 0);
                }
        }
    }

    // epilogue: O row = q0+w*16+4*g+r, col d = lane&15
    float invl = 1.0f / l;             // per q = lane&15
    float iq[4];
    #pragma unroll
    for (int r = 0; r < 4; ++r) iq[r] = __shfl(invl, 4 * g + r);
    #pragma unroll
    for (int r = 0; r < 4; ++r) {
        int rowq = q0 + w * 16 + 4 * g + r;
        if (rowq >= TT) continue;
        bf16* dst = ycin + (size_t)(b * TT + rowq) * 768 + 256;
        #pragma unroll
        for (int v = 0; v < 2; ++v)
            #pragma unroll
            for (int d = 0; d < 2; ++d)
                dst[v * 256 + h * 32 + d * 16 + l15] = __float2bfloat16(o[v][d][r] * iq[r]);
    }
}

// ---------------------------------------------------------------- gathered logit + sigmoid
__global__ __launch_bounds__(256) void pred_kernel(
    const float* __restrict__ yc,     // (NTOK,256)
    const int* __restrict__ skills,
    const float* __restrict__ outW,   // (500,256)
    const float* __restrict__ outB,   // (500)
    float* __restrict__ out)          // (NTOK)
{
    int n = blockIdx.x * 4 + (threadIdx.x >> 6);
    if (n >= NTOK) return;
    int lane = threadIdx.x & 63;
    int b = n / TT, t = n % TT;
    int c = skills[b * SEQL + t + 1];            // cshft
    const float* wrow = outW + (size_t)c * 256;
    const float* xrow = yc + (size_t)n * 256;
    float s = 0.f;
    for (int j = lane; j < 256; j += 64) s += xrow[j] * wrow[j];
    #pragma unroll
    for (int off = 32; off > 0; off >>= 1) s += __shfl_down(s, off);
    if (lane == 0) out[n] = 1.0f / (1.0f + expf(-(s + outB[c])));
}

// ---------------------------------------------------------------- host
static inline void gemmb(const bf16* A, int lda, const bf16* W, const float* bias,
                         bf16* C, int ldc, int M, int N, int K, int act, hipStream_t s)
{
    dim3 g(N / 128, (M + 127) / 128), b(256);
    switch (act) {
        case 0: gemm_mfma<0, bf16><<<g, b, 0, s>>>(A, lda, W, bias, C, ldc, M, N, K); break;
        case 1: gemm_mfma<1, bf16><<<g, b, 0, s>>>(A, lda, W, bias, C, ldc, M, N, K); break;
        case 3: gemm_mfma<3, bf16><<<g, b, 0, s>>>(A, lda, W, bias, C, ldc, M, N, K); break;
    }
}

extern "C" void kernel_launch(void* const* d_in, const int* in_sizes, int n_in,
                              void* d_out, int out_size, void* d_ws, size_t ws_size,
                              hipStream_t stream)
{
    const int*   skills    = (const int*)d_in[0];
    const int*   responses = (const int*)d_in[2];
    const float* embC  = (const float*)d_in[3];
    const float* embA  = (const float*)d_in[4];
    const float* embT  = (const float*)d_in[5];
    const float* embF  = (const float*)d_in[6];
    const float* mlpW1 = (const float*)d_in[9];
    const float* mlpb1 = (const float*)d_in[10];
    const float* mlpW2 = (const float*)d_in[11];
    const float* mlpb2 = (const float*)d_in[12];
    const float* inW   = (const float*)d_in[13];
    const float* convW = (const float*)d_in[14];
    const float* convb = (const float*)d_in[15];
    const float* xpW   = (const float*)d_in[16];
    const float* dtW   = (const float*)d_in[17];
    const float* dtb   = (const float*)d_in[18];
    const float* Alog  = (const float*)d_in[19];
    const float* Dp    = (const float*)d_in[20];
    const float* opW   = (const float*)d_in[21];
    const float* mnw   = (const float*)d_in[22];
    const float* fW1   = (const float*)d_in[23];
    const float* fb1   = (const float*)d_in[24];
    const float* fW2   = (const float*)d_in[25];
    const float* fb2   = (const float*)d_in[26];
    const float* fnw   = (const float*)d_in[27];
    const float* finW  = (const float*)d_in[28];
    const float* finb  = (const float*)d_in[29];
    const float* outW  = (const float*)d_in[30];
    const float* outb  = (const float*)d_in[31];

    const size_t NT = NTOK;
    // fp32 region
    float* t1   = (float*)d_ws;          // NT*256 (final gemm out)
    float* dt   = t1 + NT * 256;         // NT*512
    float* xdbl = dt + NT * 512;         // NT*48
    // bf16 region
    bf16* y    = (bf16*)(xdbl + NT * 48);
    bf16* st   = y    + NT * 256;
    bf16* sf   = st   + NT * 256;
    bf16* h1   = sf   + NT * 256;
    bf16* thid = h1   + NT * 256;        // temp (mlp hidden / outproj / ffn2 out)
    bf16* bufA = thid + NT * 256;        // NT*1024: xz / ffnmid / ycin(768)
    bf16* xc   = bufA + NT * 1024;       // NT*512
    bf16* ym   = xc   + NT * 512;        // NT*512
    // bf16 weights
    bf16* wMlp1 = ym    + NT * 512;      // 65536
    bf16* wMlp2 = wMlp1 + 65536;         // 65536
    bf16* wIn   = wMlp2 + 65536;         // 2*262144
    bf16* wOp   = wIn   + 2 * 262144;    // 2*131072
    bf16* wF1   = wOp   + 2 * 131072;    // 2*262144
    bf16* wF2   = wF1   + 2 * 262144;    // 2*262144
    bf16* wFin  = wF2   + 2 * 262144;    // 196608

    // 0) weight conversions
    f2bf_kernel<<<(65536 + 255) / 256, 256, 0, stream>>>(mlpW1, wMlp1, 65536);
    f2bf_kernel<<<(65536 + 255) / 256, 256, 0, stream>>>(mlpW2, wMlp2, 65536);
    f2bf_kernel<<<(524288 + 255) / 256, 256, 0, stream>>>(inW, wIn, 524288);
    f2bf_kernel<<<(262144 + 255) / 256, 256, 0, stream>>>(opW, wOp, 262144);
    f2bf_kernel<<<(524288 + 255) / 256, 256, 0, stream>>>(fW1, wF1, 524288);
    f2bf_kernel<<<(524288 + 255) / 256, 256, 0, stream>>>(fW2, wF2, 524288);
    f2bf_kernel<<<(196608 + 255) / 256, 256, 0, stream>>>(finW, wFin, 196608);

    // 1) embeddings
    embed_kernel<<<NTOK, 256, 0, stream>>>(skills, responses, embC, embA, embT, embF, y, st, sf);

    // 2) three MLPs (tanh hidden)
    gemmb(y,  256, wMlp1, mlpb1, thid, 256, NTOK, 256, 256, 1, stream);
    gemmb(thid, 256, wMlp2, mlpb2, y,  256, NTOK, 256, 256, 0, stream);
    gemmb(st, 256, wMlp1, mlpb1, thid, 256, NTOK, 256, 256, 1, stream);
    gemmb(thid, 256, wMlp2, mlpb2, st, 256, NTOK, 256, 256, 0, stream);
    gemmb(sf, 256, wMlp1, mlpb1, thid, 256, NTOK, 256, 256, 1, stream);
    gemmb(thid, 256, wMlp2, mlpb2, sf, 256, NTOK, 256, 256, 0, stream);

    // 3) two mamba layers
    for (int i = 0; i < 2; ++i) {
        gemmb(y, 256, wIn + (size_t)i * 262144, nullptr, bufA, 1024, NTOK, 1024, 256, 0, stream);
        conv_silu_kernel<<<(NTOK * 512) / 256, 256, 0, stream>>>(bufA, convW + i * 2048, convb + i * 512, xc);
        {   // xproj: N=48, VALU path, bf16 A
            dim3 g((48 + 63) / 64, (NTOK + 63) / 64);
            gemm_kernel<0, bf16><<<g, 256, 0, stream>>>(xc, 512, xpW + (size_t)i * 48 * 512, nullptr, xdbl, 48, NTOK, 48, 512);
        }
        {   // dtproj: K=16, VALU path, fp32 A, softplus
            dim3 g((512 + 63) / 64, (NTOK + 63) / 64);
            gemm_kernel<2, float><<<g, 256, 0, stream>>>(xdbl, 48, dtW + (size_t)i * 512 * 16, dtb + i * 512, dt, 512, NTOK, 512, 16);
        }
        scan_kernel<<<(BATCH * 512 * 16) / 256, 256, 0, stream>>>(dt, xc, xdbl, bufA, Alog + i * 8192, Dp + i * 512, ym);
        gemmb(ym, 512, wOp + (size_t)i * 131072, nullptr, thid, 256, NTOK, 256, 512, 0, stream);
        rmsnorm_kernel<<<NTOK, 256, 0, stream>>>(thid, y, mnw + i * 256, h1);
        gemmb(h1, 256, wF1 + (size_t)i * 262144, fb1 + i * 1024, bufA, 1024, NTOK, 1024, 256, 3, stream);
        gemmb(bufA, 1024, wF2 + (size_t)i * 262144, fb2 + i * 256, thid, 256, NTOK, 256, 1024, 0, stream);
        rmsnorm_kernel<<<NTOK, 256, 0, stream>>>(thid, h1, fnw + i * 256, y);
    }

    // 4) dual attention into ycin = bufA (stride 768)
    copy_ycin_kernel<<<NTOK, 256, 0, stream>>>(y, bufA);
    attn_kernel<<<BATCH * 8 * 8, 256, 0, stream>>>(y, st, sf, bufA);

    // 5) final projection + gathered sigmoid
    {
        dim3 g(256 / 128, (NTOK + 127) / 128);
        gemm_mfma<0, float><<<g, 256, 0, stream>>>(bufA, 768, wFin, finb, t1, 256, NTOK, 256, 768);
    }
    pred_kernel<<<NTOK / 4, 256, 0, stream>>>(t1, skills, outW, outb, (float*)d_out);
}

// Round 6
// 1153.062 us; speedup vs baseline: 4.9510x; 1.4808x over previous
//
#include <hip/hip_runtime.h>
#include <hip/hip_bf16.h>
#include <math.h>
#include <string.h>

#define BATCH 32
#define SEQL  512
#define TT    511          // T = L-1
#define DMODEL 256
#define DIN   512          // DI = EXP*D
#define DSN   16           // DS
#define NSK   500
#define NTOK  (BATCH*TT)   // 16352

typedef __hip_bfloat16 bf16;
typedef __attribute__((ext_vector_type(8))) short short8;
typedef __attribute__((ext_vector_type(4))) float f32x4;

__device__ inline unsigned pack_bf2(float a, float b) {
    bf16 ba = __float2bfloat16(a), bb = __float2bfloat16(b);
    unsigned short ua, ub; memcpy(&ua, &ba, 2); memcpy(&ub, &bb, 2);
    return (unsigned)ua | ((unsigned)ub << 16);
}

// ---------------------------------------------------------------- fp32 -> bf16 weight conversion
__global__ __launch_bounds__(256) void f2bf_kernel(const float* __restrict__ in, bf16* __restrict__ out, int n)
{
    int i = blockIdx.x * 256 + threadIdx.x;
    if (i < n) out[i] = __float2bfloat16(in[i]);
}

// ---------------------------------------------------------------- embeddings (bf16 out)
__global__ __launch_bounds__(256) void embed_kernel(
    const int* __restrict__ skills, const int* __restrict__ responses,
    const float* __restrict__ embC, const float* __restrict__ embA,
    const float* __restrict__ embT, const float* __restrict__ embF,
    bf16* __restrict__ o_state, bf16* __restrict__ o_st, bf16* __restrict__ o_sf)
{
    int idx = blockIdx.x * 256 + threadIdx.x;      // < NTOK*256
    int n = idx >> 8, j = idx & 255;
    int b = n / TT, t = n % TT;
    int c = skills[b * SEQL + t];
    int r = responses[b * SEQL + t];
    r = (r > -1) ? r : 0;                          // masked_r
    o_state[idx] = __float2bfloat16(embA[r * DMODEL + j] + embC[c * DMODEL + j]);
    o_st[idx]    = __float2bfloat16(embT[(r * (c + NSK)) * DMODEL + j]);
    o_sf[idx]    = __float2bfloat16(embF[(c * (1 - r)) * DMODEL + j]);
}

// ---------------------------------------------------------------- MFMA bf16 GEMM
// C[M,N] = act(A[M,K](lda,bf16) @ W[N,K]^T(bf16) + bias[N]); K%32==0, N%128==0
template<int ACT, typename OUTT>   // ACT: 0 none, 1 tanh, 3 gelu-exact
__global__ __launch_bounds__(256) void gemm_mfma(
    const bf16* __restrict__ A, int lda,
    const bf16* __restrict__ W,
    const float* __restrict__ bias,
    OUTT* __restrict__ C, int ldc,
    int M, int N, int K)
{
    __shared__ short As[128 * 40];
    __shared__ short Ws[128 * 40];
    const int tx = threadIdx.x;
    const int lane = tx & 63;
    const int wv = tx >> 6;
    const int rowBase = blockIdx.y * 128;
    const int colBase = blockIdx.x * 128;
    const int wrb = (wv >> 1) * 64;
    const int wcb = (wv & 1) * 64;

    f32x4 acc[4][4];
    #pragma unroll
    for (int m = 0; m < 4; ++m)
        #pragma unroll
        for (int n = 0; n < 4; ++n)
            acc[m][n] = (f32x4){0.f, 0.f, 0.f, 0.f};

    const int srow = tx >> 1;
    const int scol = (tx & 1) * 16;
    const bool arow_ok = (rowBase + srow) < M;
    const bf16* Ag = A + (size_t)(rowBase + srow) * lda + scol;
    const bf16* Wg = W + (size_t)(colBase + srow) * K + scol;

    const int kq = (lane >> 4) * 8;      // k-offset of this lane's 8 elems
    const int rl = lane & 15;            // row (A) / col (W) within fragment

    for (int k0 = 0; k0 < K; k0 += 32) {
        short8 av0 = {}, av1 = {};
        if (arow_ok) {
            av0 = *(const short8*)(Ag + k0);
            av1 = *(const short8*)(Ag + k0 + 8);
        }
        short8 wv0 = *(const short8*)(Wg + k0);
        short8 wv1 = *(const short8*)(Wg + k0 + 8);
        __syncthreads();                       // previous iter's LDS reads done
        *(short8*)&As[srow * 40 + scol]     = av0;
        *(short8*)&As[srow * 40 + scol + 8] = av1;
        *(short8*)&Ws[srow * 40 + scol]     = wv0;
        *(short8*)&Ws[srow * 40 + scol + 8] = wv1;
        __syncthreads();
        short8 af[4], bfr[4];
        #pragma unroll
        for (int m = 0; m < 4; ++m) af[m]  = *(const short8*)&As[(wrb + m * 16 + rl) * 40 + kq];
        #pragma unroll
        for (int n = 0; n < 4; ++n) bfr[n] = *(const short8*)&Ws[(wcb + n * 16 + rl) * 40 + kq];
        #pragma unroll
        for (int m = 0; m < 4; ++m)
            #pragma unroll
            for (int n = 0; n < 4; ++n)
                acc[m][n] = __builtin_amdgcn_mfma_f32_16x16x32_bf16(af[m], bfr[n], acc[m][n], 0, 0, 0);
    }

    // epilogue: C/D layout col=lane&15, row=(lane>>4)*4+reg  [m89/m91]
    const int rq = (lane >> 4) * 4;
    const int cl = lane & 15;
    #pragma unroll
    for (int m = 0; m < 4; ++m) {
        #pragma unroll
        for (int i = 0; i < 4; ++i) {
            int row = rowBase + wrb + m * 16 + rq + i;
            if (row >= M) continue;
            #pragma unroll
            for (int n = 0; n < 4; ++n) {
                int col = colBase + wcb + n * 16 + cl;
                float x = acc[m][n][i];
                if (bias) x += bias[col];
                if (ACT == 1) x = tanhf(x);
                else if (ACT == 3) x = 0.5f * x * (1.f + erff(x * 0.70710678118654752440f));
                C[(size_t)row * ldc + col] = OUTT(x);
            }
        }
    }
}

// ---------------------------------------------------------------- small VALU GEMM (xproj N=48, dtproj K=16)
__device__ inline float4 loadA4(const float* p) { return *reinterpret_cast<const float4*>(p); }
__device__ inline float4 loadA4(const bf16* p) {
    return make_float4(__bfloat162float(p[0]), __bfloat162float(p[1]),
                       __bfloat162float(p[2]), __bfloat162float(p[3]));
}

template<int ACT, typename TA>   // 0 none, 2 softplus
__global__ __launch_bounds__(256) void gemm_kernel(
    const TA* __restrict__ A, int lda,
    const float* __restrict__ W,
    const float* __restrict__ bias,
    float* __restrict__ C, int ldc,
    int M, int N, int K)
{
    __shared__ float As[64][17];
    __shared__ float Ws[64][17];
    const int tx = threadIdx.x;
    const int rowBase = blockIdx.y * 64;
    const int colBase = blockIdx.x * 64;
    const int lr = tx >> 2;
    const int lk = (tx & 3) << 2;
    const int tr = (tx >> 4) << 2;
    const int tc = (tx & 15) << 2;
    float acc[4][4] = {};

    for (int k0 = 0; k0 < K; k0 += 16) {
        float4 av = make_float4(0.f, 0.f, 0.f, 0.f);
        int ar = rowBase + lr;
        if (ar < M) av = loadA4(A + (size_t)ar * lda + k0 + lk);
        As[lr][lk] = av.x; As[lr][lk + 1] = av.y; As[lr][lk + 2] = av.z; As[lr][lk + 3] = av.w;
        float4 wvv = make_float4(0.f, 0.f, 0.f, 0.f);
        int wr = colBase + lr;
        if (wr < N) wvv = *reinterpret_cast<const float4*>(W + (size_t)wr * K + k0 + lk);
        Ws[lr][lk] = wvv.x; Ws[lr][lk + 1] = wvv.y; Ws[lr][lk + 2] = wvv.z; Ws[lr][lk + 3] = wvv.w;
        __syncthreads();
        #pragma unroll
        for (int k = 0; k < 16; ++k) {
            float a0 = As[tr][k], a1 = As[tr + 1][k], a2 = As[tr + 2][k], a3 = As[tr + 3][k];
            float b0 = Ws[tc][k], b1 = Ws[tc + 1][k], b2 = Ws[tc + 2][k], b3 = Ws[tc + 3][k];
            acc[0][0] += a0 * b0; acc[0][1] += a0 * b1; acc[0][2] += a0 * b2; acc[0][3] += a0 * b3;
            acc[1][0] += a1 * b0; acc[1][1] += a1 * b1; acc[1][2] += a1 * b2; acc[1][3] += a1 * b3;
            acc[2][0] += a2 * b0; acc[2][1] += a2 * b1; acc[2][2] += a2 * b2; acc[2][3] += a2 * b3;
            acc[3][0] += a3 * b0; acc[3][1] += a3 * b1; acc[3][2] += a3 * b2; acc[3][3] += a3 * b3;
        }
        __syncthreads();
    }

    #pragma unroll
    for (int i = 0; i < 4; ++i) {
        int r = rowBase + tr + i;
        if (r >= M) break;
        int cb = colBase + tc;
        if (cb >= N) continue;
        float4 v;
        float* vp = &v.x;
        #pragma unroll
        for (int j = 0; j < 4; ++j) {
            float x = acc[i][j];
            if (bias) x += bias[cb + j];
            if (ACT == 2) x = fmaxf(x, 0.f) + log1pf(expf(-fabsf(x)));   // softplus
            vp[j] = x;
        }
        *reinterpret_cast<float4*>(C + (size_t)r * ldc + cb) = v;
    }
}

// ---------------------------------------------------------------- conv1d(4, causal, depthwise) + silu (bf16 io)
__global__ __launch_bounds__(256) void conv_silu_kernel(
    const bf16* __restrict__ xz,    // (NTOK,1024), xc part = cols 0..511
    const float* __restrict__ cW,   // (512,4)
    const float* __restrict__ cb,   // (512)
    bf16* __restrict__ xc)          // (NTOK,512)
{
    int idx = blockIdx.x * 256 + threadIdx.x;     // < NTOK*512
    int d = idx & 511;
    int n = idx >> 9;
    int b = n / TT, t = n % TT;
    float w0 = cW[d * 4], w1 = cW[d * 4 + 1], w2 = cW[d * 4 + 2], w3 = cW[d * 4 + 3];
    const bf16* base = xz + (size_t)(b * TT) * 1024 + d;
    float acc = cb[d];
    if (t >= 3) acc += w0 * __bfloat162float(base[(size_t)(t - 3) * 1024]);
    if (t >= 2) acc += w1 * __bfloat162float(base[(size_t)(t - 2) * 1024]);
    if (t >= 1) acc += w2 * __bfloat162float(base[(size_t)(t - 1) * 1024]);
    acc += w3 * __bfloat162float(base[(size_t)t * 1024]);
    xc[idx] = __float2bfloat16(acc / (1.f + expf(-acc)));   // silu
}

// ---------------------------------------------------------------- chunk-parallel selective scan (no shuffles)
// Linear recurrence h_t = a_t*h_t-1 + b_t split into 16 chunks of 32 steps.
// One thread per (b, d, chunk), all 16 states in registers.
// Block = 256 thr = 16 d x 16 chunks for one b; LDS prefix-combine gives
// each chunk its h_init; pass 2 rescans emitting ym (D-term + silu(z) fused).
// a_t in (0,1] (dt>=0, A<0) so the decay product P never overflows.
__global__ __launch_bounds__(256) void scan_kernel(
    const float* __restrict__ dt,     // (NTOK,512)
    const bf16* __restrict__ xc,      // (NTOK,512)
    const float* __restrict__ xdbl,   // (NTOK,48): [dtr(16) | B(16) | C(16)]
    const bf16* __restrict__ xz,      // (NTOK,1024): z = cols 512..1023
    const float* __restrict__ Alog,   // (512,16)
    const float* __restrict__ Dpv,    // (512)
    bf16* __restrict__ ym)            // (NTOK,512)
{
    __shared__ float smry[256][33];   // [chunk*16+dl][P(16) | h(16)], pad 33

    const int tx = threadIdx.x;
    const int dl = tx & 15;
    const int c  = tx >> 4;           // chunk 0..15
    const int b  = blockIdx.x >> 5;
    const int d  = ((blockIdx.x & 31) << 4) + dl;

    float A[16];
    {
        const float* Ap = Alog + d * 16;
        #pragma unroll
        for (int s = 0; s < 16; ++s) A[s] = -expf(Ap[s]);
    }
    const float Dv = Dpv[d];
    const size_t nb = (size_t)b * TT;
    const int t0 = c * 32;
    const int t1 = (t0 + 32 < TT) ? (t0 + 32) : TT;

    float P[16], h[16];
    #pragma unroll
    for (int s = 0; s < 16; ++s) { P[s] = 1.f; h[s] = 0.f; }

    // pass 1: local scan (h from 0) + decay product
    for (int t = t0; t < t1; ++t) {
        const size_t n = nb + t;
        const float dtt = dt[n * 512 + d];
        const float xt  = __bfloat162float(xc[n * 512 + d]);
        const float dx  = dtt * xt;
        const float* Bp = xdbl + n * 48 + 16;
        const float4 b0 = *(const float4*)(Bp);
        const float4 b1 = *(const float4*)(Bp + 4);
        const float4 b2 = *(const float4*)(Bp + 8);
        const float4 b3 = *(const float4*)(Bp + 12);
        const float Bv[16] = {b0.x,b0.y,b0.z,b0.w, b1.x,b1.y,b1.z,b1.w,
                              b2.x,b2.y,b2.z,b2.w, b3.x,b3.y,b3.z,b3.w};
        #pragma unroll
        for (int s = 0; s < 16; ++s) {
            const float e = expf(dtt * A[s]);
            P[s] *= e;
            h[s] = e * h[s] + dx * Bv[s];
        }
    }
    #pragma unroll
    for (int s = 0; s < 16; ++s) { smry[tx][s] = P[s]; smry[tx][16 + s] = h[s]; }
    __syncthreads();

    // prefix combine (oldest chunk first): h_init for this chunk
    #pragma unroll
    for (int s = 0; s < 16; ++s) h[s] = 0.f;
    for (int cc = 0; cc < c; ++cc) {
        const float* S = smry[(cc << 4) + dl];
        #pragma unroll
        for (int s = 0; s < 16; ++s) h[s] = S[s] * h[s] + S[16 + s];
    }

    // pass 2: rescan from h_init, emit ym
    for (int t = t0; t < t1; ++t) {
        const size_t n = nb + t;
        const float dtt = dt[n * 512 + d];
        const float xt  = __bfloat162float(xc[n * 512 + d]);
        const float dx  = dtt * xt;
        const float* Bp = xdbl + n * 48 + 16;
        const float4 b0 = *(const float4*)(Bp);
        const float4 b1 = *(const float4*)(Bp + 4);
        const float4 b2 = *(const float4*)(Bp + 8);
        const float4 b3 = *(const float4*)(Bp + 12);
        const float4 c0 = *(const float4*)(Bp + 16);
        const float4 c1 = *(const float4*)(Bp + 20);
        const float4 c2 = *(const float4*)(Bp + 24);
        const float4 c3 = *(const float4*)(Bp + 28);
        const float Bv[16] = {b0.x,b0.y,b0.z,b0.w, b1.x,b1.y,b1.z,b1.w,
                              b2.x,b2.y,b2.z,b2.w, b3.x,b3.y,b3.z,b3.w};
        const float Cv[16] = {c0.x,c0.y,c0.z,c0.w, c1.x,c1.y,c1.z,c1.w,
                              c2.x,c2.y,c2.z,c2.w, c3.x,c3.y,c3.z,c3.w};
        float y = 0.f;
        #pragma unroll
        for (int s = 0; s < 16; ++s) {
            const float e = expf(dtt * A[s]);
            h[s] = e * h[s] + dx * Bv[s];
            y += h[s] * Cv[s];
        }
        const float zz = __bfloat162float(xz[n * 1024 + 512 + d]);
        const float v = (y + xt * Dv) * (zz / (1.f + expf(-zz)));
        ym[n * 512 + d] = __float2bfloat16(v);
    }
}

// ---------------------------------------------------------------- rmsnorm(a+b)*w  (bf16 io, fp32 math)
__global__ __launch_bounds__(256) void rmsnorm_kernel(
    const bf16* __restrict__ a, const bf16* __restrict__ b,
    const float* __restrict__ w, bf16* __restrict__ out)
{
    __shared__ float red[256];
    int n = blockIdx.x, j = threadIdx.x;
    float v = __bfloat162float(a[(size_t)n * 256 + j]) + __bfloat162float(b[(size_t)n * 256 + j]);
    red[j] = v * v;
    __syncthreads();
    for (int s = 128; s > 0; s >>= 1) { if (j < s) red[j] += red[j + s]; __syncthreads(); }
    float scale = rsqrtf(red[0] / 256.0f + 1e-12f);
    out[(size_t)n * 256 + j] = __float2bfloat16(v * scale * w[j]);
}

// ---------------------------------------------------------------- copy y into ycin[:, 0:256] (stride 768)
__global__ __launch_bounds__(256) void copy_ycin_kernel(
    const bf16* __restrict__ y, bf16* __restrict__ ycin)
{
    int idx = blockIdx.x * 256 + threadIdx.x;
    int n = idx >> 8, j = idx & 255;
    ycin[(size_t)n * 768 + j] = y[idx];
}

// ---------------------------------------------------------------- MFMA dual flash attention
__global__ __launch_bounds__(256) void attn_kernel(
    const bf16* __restrict__ y,    // (B,TT,256) q = k
    const bf16* __restrict__ st,   // v1
    const bf16* __restrict__ sf,   // v2
    bf16* __restrict__ ycin)       // (B,TT,768), writes cols 256..767
{
    __shared__ short Ks[64 * 40];      // K[key][d], row stride 40 shorts (80B)
    __shared__ short Vt[2][32 * 88];   // V^T[d][key], row stride 88 shorts (176B)
    __shared__ short Pl[64 * 88];      // P[q][key] bf16, row stride 88 shorts

    const int bid = blockIdx.x;        // ((b*8)+h)*8 + qt
    const int qt = bid & 7;
    const int h  = (bid >> 3) & 7;
    const int b  = bid >> 6;
    const int tx = threadIdx.x;
    const int w  = tx >> 6;            // wave 0..3
    const int lane = tx & 63;
    const int g  = lane >> 4;          // 0..3
    const int l15 = lane & 15;
    const int q0 = qt * 64;
    const int qg = q0 + w * 16 + l15;  // this lane's q row (S^T col)
    const float scale = 0.17677669529663687f;   // 1/sqrt(32)

    const bf16* ybase  = y  + (size_t)(b * TT) * 256 + h * 32;
    const bf16* v1base = st + (size_t)(b * TT) * 256 + h * 32;
    const bf16* v2base = sf + (size_t)(b * TT) * 256 + h * 32;

    // Q fragment (B operand): col=q=lane&15, k-slice d=(lane>>4)*8..+7
    short8 qf = {};
    if (qg < TT) qf = *(const short8*)(ybase + (size_t)qg * 256 + g * 8);

    float m = -INFINITY, l = 0.f;
    f32x4 o[2][2];                     // [v][dsub]
    #pragma unroll
    for (int v = 0; v < 2; ++v) { o[v][0] = (f32x4){0,0,0,0}; o[v][1] = (f32x4){0,0,0,0}; }

    const int sr = tx >> 2;            // staging key row 0..63
    const int sc = (tx & 3) * 8;       // staging d base

    const int nkt = (qt == 0) ? 8 : (qt + 1);
    for (int kt = 0; kt < nkt; ++kt) {
        const int k0 = kt * 64;
        __syncthreads();               // previous tile's LDS reads done
        {
            int kgr = k0 + sr;
            short8 kv = {}, v1v = {}, v2v = {};
            if (kgr < TT) {
                kv  = *(const short8*)(ybase  + (size_t)kgr * 256 + sc);
                v1v = *(const short8*)(v1base + (size_t)kgr * 256 + sc);
                v2v = *(const short8*)(v2base + (size_t)kgr * 256 + sc);
            }
            *(short8*)&Ks[sr * 40 + sc] = kv;
            #pragma unroll
            for (int i = 0; i < 8; ++i) {
                Vt[0][(sc + i) * 88 + sr] = v1v[i];
                Vt[1][(sc + i) * 88 + sr] = v2v[i];
            }
        }
        __syncthreads();

        // S^T[key][q]: 4 mfmas, each 16 keys x 16 q, K=32 (full head dim)
        f32x4 s[4];
        #pragma unroll
        for (int jm = 0; jm < 4; ++jm) {
            short8 kf = *(const short8*)&Ks[(jm * 16 + l15) * 40 + g * 8];
            s[jm] = __builtin_amdgcn_mfma_f32_16x16x32_bf16(kf, qf, (f32x4){0,0,0,0}, 0, 0, 0);
        }
        // mask + tile max (per lane: all 16 values are q=qg)
        float tm = -INFINITY;
        #pragma unroll
        for (int jm = 0; jm < 4; ++jm)
            #pragma unroll
            for (int r = 0; r < 4; ++r) {
                int kk = k0 + jm * 16 + g * 4 + r;
                float sv = s[jm][r];
                sv = (kk < qg) ? sv * scale : ((kk < TT) ? -1e9f : -INFINITY);
                s[jm][r] = sv;
                tm = fmaxf(tm, sv);
            }
        tm = fmaxf(tm, __shfl_xor(tm, 16));
        tm = fmaxf(tm, __shfl_xor(tm, 32));
        float mn = fmaxf(m, tm);
        float rs = expf(m - mn);       // m==-inf -> 0
        m = mn;
        float ts = 0.f;
        #pragma unroll
        for (int jm = 0; jm < 4; ++jm)
            #pragma unroll
            for (int r = 0; r < 4; ++r) {
                float e = expf(s[jm][r] - mn);
                s[jm][r] = e;
                ts += e;
            }
        ts += __shfl_xor(ts, 16);
        ts += __shfl_xor(ts, 32);
        l = l * rs + ts;
        // P -> LDS as bf16 (u32 pair writes; row q, key 16*jm+4*g+{0..3})
        #pragma unroll
        for (int jm = 0; jm < 4; ++jm) {
            *(unsigned*)&Pl[(w * 16 + l15) * 88 + jm * 16 + g * 4]     = pack_bf2(s[jm][0], s[jm][1]);
            *(unsigned*)&Pl[(w * 16 + l15) * 88 + jm * 16 + g * 4 + 2] = pack_bf2(s[jm][2], s[jm][3]);
        }
        // rescale O accs: O row = 4*g+reg -> factor lives in lane (q row)
        float rq[4];
        #pragma unroll
        for (int r = 0; r < 4; ++r) rq[r] = __shfl(rs, 4 * g + r);
        #pragma unroll
        for (int v = 0; v < 2; ++v)
            #pragma unroll
            for (int d = 0; d < 2; ++d)
                #pragma unroll
                for (int r = 0; r < 4; ++r)
                    o[v][d][r] *= rq[r];
        // PV: A = P (row=q=lane&15, k=keys), B = Vt (col=d=lane&15, k=keys)
        #pragma unroll
        for (int ks = 0; ks < 2; ++ks) {
            short8 pf = *(const short8*)&Pl[(w * 16 + l15) * 88 + ks * 32 + g * 8];
            #pragma unroll
            for (int v = 0; v < 2; ++v)
                #pragma unroll
                for (int d = 0; d < 2; ++d) {
                    short8 vf = *(const short8*)&Vt[v][(d * 16 + l15) * 88 + ks * 32 + g * 8];
                    o[v][d] = __builtin_amdgcn_mfma_f32_16x16x32_bf16(pf, vf, o[v][d], 0, 0, 0);
                }
        }
    }

    // epilogue: O row = q0+w*16+4*g+r, col d = lane&15
    float invl = 1.0f / l;             // per q = lane&15
    float iq[4];
    #pragma unroll
    for (int r = 0; r < 4; ++r) iq[r] = __shfl(invl, 4 * g + r);
    #pragma unroll
    for (int r = 0; r < 4; ++r) {
        int rowq = q0 + w * 16 + 4 * g + r;
        if (rowq >= TT) continue;
        bf16* dst = ycin + (size_t)(b * TT + rowq) * 768 + 256;
        #pragma unroll
        for (int v = 0; v < 2; ++v)
            #pragma unroll
            for (int d = 0; d < 2; ++d)
                dst[v * 256 + h * 32 + d * 16 + l15] = __float2bfloat16(o[v][d][r] * iq[r]);
    }
}

// ---------------------------------------------------------------- gathered logit + sigmoid
__global__ __launch_bounds__(256) void pred_kernel(
    const float* __restrict__ yc,     // (NTOK,256)
    const int* __restrict__ skills,
    const float* __restrict__ outW,   // (500,256)
    const float* __restrict__ outB,   // (500)
    float* __restrict__ out)          // (NTOK)
{
    int n = blockIdx.x * 4 + (threadIdx.x >> 6);
    if (n >= NTOK) return;
    int lane = threadIdx.x & 63;
    int b = n / TT, t = n % TT;
    int c = skills[b * SEQL + t + 1];            // cshft
    const float* wrow = outW + (size_t)c * 256;
    const float* xrow = yc + (size_t)n * 256;
    float s = 0.f;
    for (int j = lane; j < 256; j += 64) s += xrow[j] * wrow[j];
    #pragma unroll
    for (int off = 32; off > 0; off >>= 1) s += __shfl_down(s, off);
    if (lane == 0) out[n] = 1.0f / (1.0f + expf(-(s + outB[c])));
}

// ---------------------------------------------------------------- host
static inline void gemmb(const bf16* A, int lda, const bf16* W, const float* bias,
                         bf16* C, int ldc, int M, int N, int K, int act, hipStream_t s)
{
    dim3 g(N / 128, (M + 127) / 128), b(256);
    switch (act) {
        case 0: gemm_mfma<0, bf16><<<g, b, 0, s>>>(A, lda, W, bias, C, ldc, M, N, K); break;
        case 1: gemm_mfma<1, bf16><<<g, b, 0, s>>>(A, lda, W, bias, C, ldc, M, N, K); break;
        case 3: gemm_mfma<3, bf16><<<g, b, 0, s>>>(A, lda, W, bias, C, ldc, M, N, K); break;
    }
}

extern "C" void kernel_launch(void* const* d_in, const int* in_sizes, int n_in,
                              void* d_out, int out_size, void* d_ws, size_t ws_size,
                              hipStream_t stream)
{
    const int*   skills    = (const int*)d_in[0];
    const int*   responses = (const int*)d_in[2];
    const float* embC  = (const float*)d_in[3];
    const float* embA  = (const float*)d_in[4];
    const float* embT  = (const float*)d_in[5];
    const float* embF  = (const float*)d_in[6];
    const float* mlpW1 = (const float*)d_in[9];
    const float* mlpb1 = (const float*)d_in[10];
    const float* mlpW2 = (const float*)d_in[11];
    const float* mlpb2 = (const float*)d_in[12];
    const float* inW   = (const float*)d_in[13];
    const float* convW = (const float*)d_in[14];
    const float* convb = (const float*)d_in[15];
    const float* xpW   = (const float*)d_in[16];
    const float* dtW   = (const float*)d_in[17];
    const float* dtb   = (const float*)d_in[18];
    const float* Alog  = (const float*)d_in[19];
    const float* Dp    = (const float*)d_in[20];
    const float* opW   = (const float*)d_in[21];
    const float* mnw   = (const float*)d_in[22];
    const float* fW1   = (const float*)d_in[23];
    const float* fb1   = (const float*)d_in[24];
    const float* fW2   = (const float*)d_in[25];
    const float* fb2   = (const float*)d_in[26];
    const float* fnw   = (const float*)d_in[27];
    const float* finW  = (const float*)d_in[28];
    const float* finb  = (const float*)d_in[29];
    const float* outW  = (const float*)d_in[30];
    const float* outb  = (const float*)d_in[31];

    const size_t NT = NTOK;
    // fp32 region
    float* t1   = (float*)d_ws;          // NT*256 (final gemm out)
    float* dt   = t1 + NT * 256;         // NT*512
    float* xdbl = dt + NT * 512;         // NT*48
    // bf16 region
    bf16* y    = (bf16*)(xdbl + NT * 48);
    bf16* st   = y    + NT * 256;
    bf16* sf   = st   + NT * 256;
    bf16* h1   = sf   + NT * 256;
    bf16* thid = h1   + NT * 256;        // temp (mlp hidden / outproj / ffn2 out)
    bf16* bufA = thid + NT * 256;        // NT*1024: xz / ffnmid / ycin(768)
    bf16* xc   = bufA + NT * 1024;       // NT*512
    bf16* ym   = xc   + NT * 512;        // NT*512
    // bf16 weights
    bf16* wMlp1 = ym    + NT * 512;      // 65536
    bf16* wMlp2 = wMlp1 + 65536;         // 65536
    bf16* wIn   = wMlp2 + 65536;         // 2*262144
    bf16* wOp   = wIn   + 2 * 262144;    // 2*131072
    bf16* wF1   = wOp   + 2 * 131072;    // 2*262144
    bf16* wF2   = wF1   + 2 * 262144;    // 2*262144
    bf16* wFin  = wF2   + 2 * 262144;    // 196608

    // 0) weight conversions
    f2bf_kernel<<<(65536 + 255) / 256, 256, 0, stream>>>(mlpW1, wMlp1, 65536);
    f2bf_kernel<<<(65536 + 255) / 256, 256, 0, stream>>>(mlpW2, wMlp2, 65536);
    f2bf_kernel<<<(524288 + 255) / 256, 256, 0, stream>>>(inW, wIn, 524288);
    f2bf_kernel<<<(262144 + 255) / 256, 256, 0, stream>>>(opW, wOp, 262144);
    f2bf_kernel<<<(524288 + 255) / 256, 256, 0, stream>>>(fW1, wF1, 524288);
    f2bf_kernel<<<(524288 + 255) / 256, 256, 0, stream>>>(fW2, wF2, 524288);
    f2bf_kernel<<<(196608 + 255) / 256, 256, 0, stream>>>(finW, wFin, 196608);

    // 1) embeddings
    embed_kernel<<<NTOK, 256, 0, stream>>>(skills, responses, embC, embA, embT, embF, y, st, sf);

    // 2) three MLPs (tanh hidden)
    gemmb(y,  256, wMlp1, mlpb1, thid, 256, NTOK, 256, 256, 1, stream);
    gemmb(thid, 256, wMlp2, mlpb2, y,  256, NTOK, 256, 256, 0, stream);
    gemmb(st, 256, wMlp1, mlpb1, thid, 256, NTOK, 256, 256, 1, stream);
    gemmb(thid, 256, wMlp2, mlpb2, st, 256, NTOK, 256, 256, 0, stream);
    gemmb(sf, 256, wMlp1, mlpb1, thid, 256, NTOK, 256, 256, 1, stream);
    gemmb(thid, 256, wMlp2, mlpb2, sf, 256, NTOK, 256, 256, 0, stream);

    // 3) two mamba layers
    for (int i = 0; i < 2; ++i) {
        gemmb(y, 256, wIn + (size_t)i * 262144, nullptr, bufA, 1024, NTOK, 1024, 256, 0, stream);
        conv_silu_kernel<<<(NTOK * 512) / 256, 256, 0, stream>>>(bufA, convW + i * 2048, convb + i * 512, xc);
        {   // xproj: N=48, VALU path, bf16 A
            dim3 g((48 + 63) / 64, (NTOK + 63) / 64);
            gemm_kernel<0, bf16><<<g, 256, 0, stream>>>(xc, 512, xpW + (size_t)i * 48 * 512, nullptr, xdbl, 48, NTOK, 48, 512);
        }
        {   // dtproj: K=16, VALU path, fp32 A, softplus
            dim3 g((512 + 63) / 64, (NTOK + 63) / 64);
            gemm_kernel<2, float><<<g, 256, 0, stream>>>(xdbl, 48, dtW + (size_t)i * 512 * 16, dtb + i * 512, dt, 512, NTOK, 512, 16);
        }
        scan_kernel<<<BATCH * 32, 256, 0, stream>>>(dt, xc, xdbl, bufA, Alog + i * 8192, Dp + i * 512, ym);
        gemmb(ym, 512, wOp + (size_t)i * 131072, nullptr, thid, 256, NTOK, 256, 512, 0, stream);
        rmsnorm_kernel<<<NTOK, 256, 0, stream>>>(thid, y, mnw + i * 256, h1);
        gemmb(h1, 256, wF1 + (size_t)i * 262144, fb1 + i * 1024, bufA, 1024, NTOK, 1024, 256, 3, stream);
        gemmb(bufA, 1024, wF2 + (size_t)i * 262144, fb2 + i * 256, thid, 256, NTOK, 256, 1024, 0, stream);
        rmsnorm_kernel<<<NTOK, 256, 0, stream>>>(thid, h1, fnw + i * 256, y);
    }

    // 4) dual attention into ycin = bufA (stride 768)
    copy_ycin_kernel<<<NTOK, 256, 0, stream>>>(y, bufA);
    attn_kernel<<<BATCH * 8 * 8, 256, 0, stream>>>(y, st, sf, bufA);

    // 5) final projection + gathered sigmoid
    {
        dim3 g(256 / 128, (NTOK + 127) / 128);
        gemm_mfma<0, float><<<g, 256, 0, stream>>>(bufA, 768, wFin, finb, t1, 256, NTOK, 256, 768);
    }
    pred_kernel<<<NTOK / 4, 256, 0, stream>>>(t1, skills, outW, outb, (float*)d_out);
}

// Round 7
// 777.582 us; speedup vs baseline: 7.3418x; 1.4829x over previous
//
#include <hip/hip_runtime.h>
#include <hip/hip_bf16.h>
#include <math.h>
#include <string.h>

#define BATCH 32
#define SEQL  512
#define TT    511          // T = L-1
#define DMODEL 256
#define DIN   512          // DI = EXP*D
#define DSN   16           // DS
#define NSK   500
#define NTOK  (BATCH*TT)   // 16352

typedef __hip_bfloat16 bf16;
typedef __attribute__((ext_vector_type(8))) short short8;
typedef __attribute__((ext_vector_type(4))) float f32x4;

#define L2E 1.4426950408889634f
#define LN2 0.6931471805599453f

__device__ inline float fexp(float x) { return __builtin_amdgcn_exp2f(x * L2E); }

__device__ inline unsigned pack_bf2(float a, float b) {
    bf16 ba = __float2bfloat16(a), bb = __float2bfloat16(b);
    unsigned short ua, ub; memcpy(&ua, &ba, 2); memcpy(&ub, &bb, 2);
    return (unsigned)ua | ((unsigned)ub << 16);
}

// ---------------------------------------------------------------- fp32 -> bf16 weight conversion
__global__ __launch_bounds__(256) void f2bf_kernel(const float* __restrict__ in, bf16* __restrict__ out, int n)
{
    int i = blockIdx.x * 256 + threadIdx.x;
    if (i < n) out[i] = __float2bfloat16(in[i]);
}

// pad rows: out[r*K+k] = r<rows_in ? in[r*K+k] : 0   (rows_out x K)
__global__ __launch_bounds__(256) void f2bf_pad_kernel(const float* __restrict__ in, bf16* __restrict__ out,
                                                        int rows_in, int rows_out, int K)
{
    int i = blockIdx.x * 256 + threadIdx.x;
    if (i >= rows_out * K) return;
    int r = i / K;
    out[i] = (r < rows_in) ? __float2bfloat16(in[i]) : __float2bfloat16(0.f);
}

// ---------------------------------------------------------------- embeddings (bf16 out)
__global__ __launch_bounds__(256) void embed_kernel(
    const int* __restrict__ skills, const int* __restrict__ responses,
    const float* __restrict__ embC, const float* __restrict__ embA,
    const float* __restrict__ embT, const float* __restrict__ embF,
    bf16* __restrict__ o_state, bf16* __restrict__ o_st, bf16* __restrict__ o_sf)
{
    int idx = blockIdx.x * 256 + threadIdx.x;      // < NTOK*256
    int n = idx >> 8, j = idx & 255;
    int b = n / TT, t = n % TT;
    int c = skills[b * SEQL + t];
    int r = responses[b * SEQL + t];
    r = (r > -1) ? r : 0;                          // masked_r
    o_state[idx] = __float2bfloat16(embA[r * DMODEL + j] + embC[c * DMODEL + j]);
    o_st[idx]    = __float2bfloat16(embT[(r * (c + NSK)) * DMODEL + j]);
    o_sf[idx]    = __float2bfloat16(embF[(c * (1 - r)) * DMODEL + j]);
}

// ---------------------------------------------------------------- MFMA bf16 GEMM
// C[M,N] = act(A[M,K](lda,bf16) @ W[N,K]^T(bf16) + bias[N]); K%32==0, N%128==0
template<int ACT, typename OUTT>   // ACT: 0 none, 1 tanh, 3 gelu-exact
__global__ __launch_bounds__(256) void gemm_mfma(
    const bf16* __restrict__ A, int lda,
    const bf16* __restrict__ W,
    const float* __restrict__ bias,
    OUTT* __restrict__ C, int ldc,
    int M, int N, int K)
{
    __shared__ short As[128 * 40];
    __shared__ short Ws[128 * 40];
    const int tx = threadIdx.x;
    const int lane = tx & 63;
    const int wv = tx >> 6;
    const int rowBase = blockIdx.y * 128;
    const int colBase = blockIdx.x * 128;
    const int wrb = (wv >> 1) * 64;
    const int wcb = (wv & 1) * 64;

    f32x4 acc[4][4];
    #pragma unroll
    for (int m = 0; m < 4; ++m)
        #pragma unroll
        for (int n = 0; n < 4; ++n)
            acc[m][n] = (f32x4){0.f, 0.f, 0.f, 0.f};

    const int srow = tx >> 1;
    const int scol = (tx & 1) * 16;
    const bool arow_ok = (rowBase + srow) < M;
    const bf16* Ag = A + (size_t)(rowBase + srow) * lda + scol;
    const bf16* Wg = W + (size_t)(colBase + srow) * K + scol;

    const int kq = (lane >> 4) * 8;      // k-offset of this lane's 8 elems
    const int rl = lane & 15;            // row (A) / col (W) within fragment

    for (int k0 = 0; k0 < K; k0 += 32) {
        short8 av0 = {}, av1 = {};
        if (arow_ok) {
            av0 = *(const short8*)(Ag + k0);
            av1 = *(const short8*)(Ag + k0 + 8);
        }
        short8 wv0 = *(const short8*)(Wg + k0);
        short8 wv1 = *(const short8*)(Wg + k0 + 8);
        __syncthreads();                       // previous iter's LDS reads done
        *(short8*)&As[srow * 40 + scol]     = av0;
        *(short8*)&As[srow * 40 + scol + 8] = av1;
        *(short8*)&Ws[srow * 40 + scol]     = wv0;
        *(short8*)&Ws[srow * 40 + scol + 8] = wv1;
        __syncthreads();
        short8 af[4], bfr[4];
        #pragma unroll
        for (int m = 0; m < 4; ++m) af[m]  = *(const short8*)&As[(wrb + m * 16 + rl) * 40 + kq];
        #pragma unroll
        for (int n = 0; n < 4; ++n) bfr[n] = *(const short8*)&Ws[(wcb + n * 16 + rl) * 40 + kq];
        #pragma unroll
        for (int m = 0; m < 4; ++m)
            #pragma unroll
            for (int n = 0; n < 4; ++n)
                acc[m][n] = __builtin_amdgcn_mfma_f32_16x16x32_bf16(af[m], bfr[n], acc[m][n], 0, 0, 0);
    }

    // epilogue: C/D layout col=lane&15, row=(lane>>4)*4+reg  [m89/m91]
    const int rq = (lane >> 4) * 4;
    const int cl = lane & 15;
    #pragma unroll
    for (int m = 0; m < 4; ++m) {
        #pragma unroll
        for (int i = 0; i < 4; ++i) {
            int row = rowBase + wrb + m * 16 + rq + i;
            if (row >= M) continue;
            #pragma unroll
            for (int n = 0; n < 4; ++n) {
                int col = colBase + wcb + n * 16 + cl;
                float x = acc[m][n][i];
                if (bias) x += bias[col];
                if (ACT == 1) x = tanhf(x);
                else if (ACT == 3) x = 0.5f * x * (1.f + erff(x * 0.70710678118654752440f));
                C[(size_t)row * ldc + col] = OUTT(x);
            }
        }
    }
}

// ---------------------------------------------------------------- small VALU GEMM (dtproj K=16)
template<int ACT>   // 0 none, 2 softplus
__global__ __launch_bounds__(256) void gemm_kernel(
    const float* __restrict__ A, int lda,
    const float* __restrict__ W,
    const float* __restrict__ bias,
    float* __restrict__ C, int ldc,
    int M, int N, int K)
{
    __shared__ float As[64][17];
    __shared__ float Ws[64][17];
    const int tx = threadIdx.x;
    const int rowBase = blockIdx.y * 64;
    const int colBase = blockIdx.x * 64;
    const int lr = tx >> 2;
    const int lk = (tx & 3) << 2;
    const int tr = (tx >> 4) << 2;
    const int tc = (tx & 15) << 2;
    float acc[4][4] = {};

    for (int k0 = 0; k0 < K; k0 += 16) {
        float4 av = make_float4(0.f, 0.f, 0.f, 0.f);
        int ar = rowBase + lr;
        if (ar < M) av = *reinterpret_cast<const float4*>(A + (size_t)ar * lda + k0 + lk);
        As[lr][lk] = av.x; As[lr][lk + 1] = av.y; As[lr][lk + 2] = av.z; As[lr][lk + 3] = av.w;
        float4 wvv = make_float4(0.f, 0.f, 0.f, 0.f);
        int wr = colBase + lr;
        if (wr < N) wvv = *reinterpret_cast<const float4*>(W + (size_t)wr * K + k0 + lk);
        Ws[lr][lk] = wvv.x; Ws[lr][lk + 1] = wvv.y; Ws[lr][lk + 2] = wvv.z; Ws[lr][lk + 3] = wvv.w;
        __syncthreads();
        #pragma unroll
        for (int k = 0; k < 16; ++k) {
            float a0 = As[tr][k], a1 = As[tr + 1][k], a2 = As[tr + 2][k], a3 = As[tr + 3][k];
            float b0 = Ws[tc][k], b1 = Ws[tc + 1][k], b2 = Ws[tc + 2][k], b3 = Ws[tc + 3][k];
            acc[0][0] += a0 * b0; acc[0][1] += a0 * b1; acc[0][2] += a0 * b2; acc[0][3] += a0 * b3;
            acc[1][0] += a1 * b0; acc[1][1] += a1 * b1; acc[1][2] += a1 * b2; acc[1][3] += a1 * b3;
            acc[2][0] += a2 * b0; acc[2][1] += a2 * b1; acc[2][2] += a2 * b2; acc[2][3] += a2 * b3;
            acc[3][0] += a3 * b0; acc[3][1] += a3 * b1; acc[3][2] += a3 * b2; acc[3][3] += a3 * b3;
        }
        __syncthreads();
    }

    #pragma unroll
    for (int i = 0; i < 4; ++i) {
        int r = rowBase + tr + i;
        if (r >= M) break;
        int cb = colBase + tc;
        if (cb >= N) continue;
        float4 v;
        float* vp = &v.x;
        #pragma unroll
        for (int j = 0; j < 4; ++j) {
            float x = acc[i][j];
            if (bias) x += bias[cb + j];
            if (ACT == 2) {   // softplus via native exp2/log2
                float e = __builtin_amdgcn_exp2f(-fabsf(x) * L2E);
                x = fmaxf(x, 0.f) + __builtin_amdgcn_logf(1.f + e) * LN2;
            }
            vp[j] = x;
        }
        *reinterpret_cast<float4*>(C + (size_t)r * ldc + cb) = v;
    }
}

// ---------------------------------------------------------------- conv1d(4, causal, depthwise) + silu (bf16 io)
__global__ __launch_bounds__(256) void conv_silu_kernel(
    const bf16* __restrict__ xz,    // (NTOK,1024), xc part = cols 0..511
    const float* __restrict__ cW,   // (512,4)
    const float* __restrict__ cb,   // (512)
    bf16* __restrict__ xc)          // (NTOK,512)
{
    int idx = blockIdx.x * 256 + threadIdx.x;     // < NTOK*512
    int d = idx & 511;
    int n = idx >> 9;
    int b = n / TT, t = n % TT;
    float w0 = cW[d * 4], w1 = cW[d * 4 + 1], w2 = cW[d * 4 + 2], w3 = cW[d * 4 + 3];
    const bf16* base = xz + (size_t)(b * TT) * 1024 + d;
    float acc = cb[d];
    if (t >= 3) acc += w0 * __bfloat162float(base[(size_t)(t - 3) * 1024]);
    if (t >= 2) acc += w1 * __bfloat162float(base[(size_t)(t - 2) * 1024]);
    if (t >= 1) acc += w2 * __bfloat162float(base[(size_t)(t - 1) * 1024]);
    acc += w3 * __bfloat162float(base[(size_t)t * 1024]);
    xc[idx] = __float2bfloat16(acc / (1.f + fexp(-acc)));   // silu
}

// ---------------------------------------------------------------- chunk-parallel selective scan (no shuffles)
// h_t = a_t*h_{t-1} + b_t split into 16 chunks of 32 steps; thread = (b,d,chunk),
// 16 states in registers; LDS prefix-combine for h_init; pass 2 emits ym.
// All exps via native v_exp_f32 (A pre-scaled by log2e). Chunk decay product
// P[s] = exp2(A2[s] * sum(dt)) -- exact same value, no per-step multiplies.
__global__ __launch_bounds__(256) void scan_kernel(
    const float* __restrict__ dt,     // (NTOK,512)
    const bf16* __restrict__ xc,      // (NTOK,512)
    const float* __restrict__ xdbl,   // (NTOK,128): [dtr(16) | B(16) | C(16) | pad]
    const bf16* __restrict__ xz,      // (NTOK,1024): z = cols 512..1023
    const float* __restrict__ Alog,   // (512,16)
    const float* __restrict__ Dpv,    // (512)
    bf16* __restrict__ ym)            // (NTOK,512)
{
    __shared__ float smry[256][33];   // [chunk*16+dl][P(16) | h(16)], pad 33

    const int tx = threadIdx.x;
    const int dl = tx & 15;
    const int c  = tx >> 4;           // chunk 0..15
    const int b  = blockIdx.x >> 5;
    const int d  = ((blockIdx.x & 31) << 4) + dl;

    float A2[16];
    {
        const float* Ap = Alog + d * 16;
        #pragma unroll
        for (int s = 0; s < 16; ++s) A2[s] = -expf(Ap[s]) * L2E;   // pre-scaled by log2e
    }
    const float Dv = Dpv[d];
    const size_t nb = (size_t)b * TT;
    const int t0 = c * 32;
    const int t1 = (t0 + 32 < TT) ? (t0 + 32) : TT;

    float h[16];
    float sdt = 0.f;
    #pragma unroll
    for (int s = 0; s < 16; ++s) h[s] = 0.f;

    // pass 1: local scan (h from 0) + dt sum
    for (int t = t0; t < t1; ++t) {
        const size_t n = nb + t;
        const float dtt = dt[n * 512 + d];
        const float xt  = __bfloat162float(xc[n * 512 + d]);
        const float dx  = dtt * xt;
        sdt += dtt;
        const float* Bp = xdbl + n * 128 + 16;
        const float4 b0 = *(const float4*)(Bp);
        const float4 b1 = *(const float4*)(Bp + 4);
        const float4 b2 = *(const float4*)(Bp + 8);
        const float4 b3 = *(const float4*)(Bp + 12);
        const float Bv[16] = {b0.x,b0.y,b0.z,b0.w, b1.x,b1.y,b1.z,b1.w,
                              b2.x,b2.y,b2.z,b2.w, b3.x,b3.y,b3.z,b3.w};
        #pragma unroll
        for (int s = 0; s < 16; ++s) {
            const float e = __builtin_amdgcn_exp2f(dtt * A2[s]);
            h[s] = e * h[s] + dx * Bv[s];
        }
    }
    #pragma unroll
    for (int s = 0; s < 16; ++s) {
        smry[tx][s]      = __builtin_amdgcn_exp2f(A2[s] * sdt);   // chunk decay product
        smry[tx][16 + s] = h[s];
    }
    __syncthreads();

    // prefix combine (oldest chunk first): h_init for this chunk
    #pragma unroll
    for (int s = 0; s < 16; ++s) h[s] = 0.f;
    for (int cc = 0; cc < c; ++cc) {
        const float* S = smry[(cc << 4) + dl];
        #pragma unroll
        for (int s = 0; s < 16; ++s) h[s] = S[s] * h[s] + S[16 + s];
    }

    // pass 2: rescan from h_init, emit ym
    for (int t = t0; t < t1; ++t) {
        const size_t n = nb + t;
        const float dtt = dt[n * 512 + d];
        const float xt  = __bfloat162float(xc[n * 512 + d]);
        const float dx  = dtt * xt;
        const float* Bp = xdbl + n * 128 + 16;
        const float4 b0 = *(const float4*)(Bp);
        const float4 b1 = *(const float4*)(Bp + 4);
        const float4 b2 = *(const float4*)(Bp + 8);
        const float4 b3 = *(const float4*)(Bp + 12);
        const float4 c0 = *(const float4*)(Bp + 16);
        const float4 c1 = *(const float4*)(Bp + 20);
        const float4 c2 = *(const float4*)(Bp + 24);
        const float4 c3 = *(const float4*)(Bp + 28);
        const float Bv[16] = {b0.x,b0.y,b0.z,b0.w, b1.x,b1.y,b1.z,b1.w,
                              b2.x,b2.y,b2.z,b2.w, b3.x,b3.y,b3.z,b3.w};
        const float Cv[16] = {c0.x,c0.y,c0.z,c0.w, c1.x,c1.y,c1.z,c1.w,
                              c2.x,c2.y,c2.z,c2.w, c3.x,c3.y,c3.z,c3.w};
        float y = 0.f;
        #pragma unroll
        for (int s = 0; s < 16; ++s) {
            const float e = __builtin_amdgcn_exp2f(dtt * A2[s]);
            h[s] = e * h[s] + dx * Bv[s];
            y += h[s] * Cv[s];
        }
        const float zz = __bfloat162float(xz[n * 1024 + 512 + d]);
        const float v = (y + xt * Dv) * (zz / (1.f + fexp(-zz)));
        ym[n * 512 + d] = __float2bfloat16(v);
    }
}

// ---------------------------------------------------------------- rmsnorm(a+b)*w  (bf16 io, fp32 math)
// optional second output at stride 768 (ycin cols 0..255) to kill copy kernel
__global__ __launch_bounds__(256) void rmsnorm_kernel(
    const bf16* __restrict__ a, const bf16* __restrict__ b,
    const float* __restrict__ w, bf16* __restrict__ out,
    bf16* __restrict__ out768)
{
    __shared__ float red[256];
    int n = blockIdx.x, j = threadIdx.x;
    float v = __bfloat162float(a[(size_t)n * 256 + j]) + __bfloat162float(b[(size_t)n * 256 + j]);
    red[j] = v * v;
    __syncthreads();
    for (int s = 128; s > 0; s >>= 1) { if (j < s) red[j] += red[j + s]; __syncthreads(); }
    float scale = rsqrtf(red[0] / 256.0f + 1e-12f);
    bf16 r = __float2bfloat16(v * scale * w[j]);
    out[(size_t)n * 256 + j] = r;
    if (out768) out768[(size_t)n * 768 + j] = r;
}

// ---------------------------------------------------------------- MFMA dual flash attention
__global__ __launch_bounds__(256) void attn_kernel(
    const bf16* __restrict__ y,    // (B,TT,256) q = k
    const bf16* __restrict__ st,   // v1
    const bf16* __restrict__ sf,   // v2
    bf16* __restrict__ ycin)       // (B,TT,768), writes cols 256..767
{
    __shared__ short Ks[64 * 40];      // K[key][d], row stride 40 shorts (80B)
    __shared__ short Vt[2][32 * 88];   // V^T[d][key], row stride 88 shorts (176B)
    __shared__ short Pl[64 * 88];      // P[q][key] bf16, row stride 88 shorts

    const int bid = blockIdx.x;        // ((b*8)+h)*8 + qt
    const int qt = bid & 7;
    const int h  = (bid >> 3) & 7;
    const int b  = bid >> 6;
    const int tx = threadIdx.x;
    const int w  = tx >> 6;            // wave 0..3
    const int lane = tx & 63;
    const int g  = lane >> 4;          // 0..3
    const int l15 = lane & 15;
    const int q0 = qt * 64;
    const int qg = q0 + w * 16 + l15;  // this lane's q row (S^T col)
    const float scale = 0.17677669529663687f;   // 1/sqrt(32)

    const bf16* ybase  = y  + (size_t)(b * TT) * 256 + h * 32;
    const bf16* v1base = st + (size_t)(b * TT) * 256 + h * 32;
    const bf16* v2base = sf + (size_t)(b * TT) * 256 + h * 32;

    // Q fragment (B operand): col=q=lane&15, k-slice d=(lane>>4)*8..+7
    short8 qf = {};
    if (qg < TT) qf = *(const short8*)(ybase + (size_t)qg * 256 + g * 8);

    float m = -INFINITY, l = 0.f;
    f32x4 o[2][2];                     // [v][dsub]
    #pragma unroll
    for (int v = 0; v < 2; ++v) { o[v][0] = (f32x4){0,0,0,0}; o[v][1] = (f32x4){0,0,0,0}; }

    const int sr = tx >> 2;            // staging key row 0..63
    const int sc = (tx & 3) * 8;       // staging d base

    const int nkt = (qt == 0) ? 8 : (qt + 1);
    for (int kt = 0; kt < nkt; ++kt) {
        const int k0 = kt * 64;
        __syncthreads();               // previous tile's LDS reads done
        {
            int kgr = k0 + sr;
            short8 kv = {}, v1v = {}, v2v = {};
            if (kgr < TT) {
                kv  = *(const short8*)(ybase  + (size_t)kgr * 256 + sc);
                v1v = *(const short8*)(v1base + (size_t)kgr * 256 + sc);
                v2v = *(const short8*)(v2base + (size_t)kgr * 256 + sc);
            }
            *(short8*)&Ks[sr * 40 + sc] = kv;
            #pragma unroll
            for (int i = 0; i < 8; ++i) {
                Vt[0][(sc + i) * 88 + sr] = v1v[i];
                Vt[1][(sc + i) * 88 + sr] = v2v[i];
            }
        }
        __syncthreads();

        // S^T[key][q]: 4 mfmas, each 16 keys x 16 q, K=32 (full head dim)
        f32x4 s[4];
        #pragma unroll
        for (int jm = 0; jm < 4; ++jm) {
            short8 kf = *(const short8*)&Ks[(jm * 16 + l15) * 40 + g * 8];
            s[jm] = __builtin_amdgcn_mfma_f32_16x16x32_bf16(kf, qf, (f32x4){0,0,0,0}, 0, 0, 0);
        }
        // mask + tile max (per lane: all 16 values are q=qg)
        float tm = -INFINITY;
        #pragma unroll
        for (int jm = 0; jm < 4; ++jm)
            #pragma unroll
            for (int r = 0; r < 4; ++r) {
                int kk = k0 + jm * 16 + g * 4 + r;
                float sv = s[jm][r];
                sv = (kk < qg) ? sv * scale : ((kk < TT) ? -1e9f : -INFINITY);
                s[jm][r] = sv;
                tm = fmaxf(tm, sv);
            }
        tm = fmaxf(tm, __shfl_xor(tm, 16));
        tm = fmaxf(tm, __shfl_xor(tm, 32));
        float mn = fmaxf(m, tm);
        float rs = fexp(m - mn);       // m==-inf -> 0
        m = mn;
        float ts = 0.f;
        #pragma unroll
        for (int jm = 0; jm < 4; ++jm)
            #pragma unroll
            for (int r = 0; r < 4; ++r) {
                float e = fexp(s[jm][r] - mn);
                s[jm][r] = e;
                ts += e;
            }
        ts += __shfl_xor(ts, 16);
        ts += __shfl_xor(ts, 32);
        l = l * rs + ts;
        // P -> LDS as bf16 (u32 pair writes; row q, key 16*jm+4*g+{0..3})
        #pragma unroll
        for (int jm = 0; jm < 4; ++jm) {
            *(unsigned*)&Pl[(w * 16 + l15) * 88 + jm * 16 + g * 4]     = pack_bf2(s[jm][0], s[jm][1]);
            *(unsigned*)&Pl[(w * 16 + l15) * 88 + jm * 16 + g * 4 + 2] = pack_bf2(s[jm][2], s[jm][3]);
        }
        // rescale O accs: O row = 4*g+reg -> factor lives in lane (q row)
        float rq[4];
        #pragma unroll
        for (int r = 0; r < 4; ++r) rq[r] = __shfl(rs, 4 * g + r);
        #pragma unroll
        for (int v = 0; v < 2; ++v)
            #pragma unroll
            for (int d = 0; d < 2; ++d)
                #pragma unroll
                for (int r = 0; r < 4; ++r)
                    o[v][d][r] *= rq[r];
        // PV: A = P (row=q=lane&15, k=keys), B = Vt (col=d=lane&15, k=keys)
        #pragma unroll
        for (int ks = 0; ks < 2; ++ks) {
            short8 pf = *(const short8*)&Pl[(w * 16 + l15) * 88 + ks * 32 + g * 8];
            #pragma unroll
            for (int v = 0; v < 2; ++v)
                #pragma unroll
                for (int d = 0; d < 2; ++d) {
                    short8 vf = *(const short8*)&Vt[v][(d * 16 + l15) * 88 + ks * 32 + g * 8];
                    o[v][d] = __builtin_amdgcn_mfma_f32_16x16x32_bf16(pf, vf, o[v][d], 0, 0, 0);
                }
        }
    }

    // epilogue: O row = q0+w*16+4*g+r, col d = lane&15
    float invl = 1.0f / l;             // per q = lane&15
    float iq[4];
    #pragma unroll
    for (int r = 0; r < 4; ++r) iq[r] = __shfl(invl, 4 * g + r);
    #pragma unroll
    for (int r = 0; r < 4; ++r) {
        int rowq = q0 + w * 16 + 4 * g + r;
        if (rowq >= TT) continue;
        bf16* dst = ycin + (size_t)(b * TT + rowq) * 768 + 256;
        #pragma unroll
        for (int v = 0; v < 2; ++v)
            #pragma unroll
            for (int d = 0; d < 2; ++d)
                dst[v * 256 + h * 32 + d * 16 + l15] = __float2bfloat16(o[v][d][r] * iq[r]);
    }
}

// ---------------------------------------------------------------- gathered logit + sigmoid
__global__ __launch_bounds__(256) void pred_kernel(
    const float* __restrict__ yc,     // (NTOK,256)
    const int* __restrict__ skills,
    const float* __restrict__ outW,   // (500,256)
    const float* __restrict__ outB,   // (500)
    float* __restrict__ out)          // (NTOK)
{
    int n = blockIdx.x * 4 + (threadIdx.x >> 6);
    if (n >= NTOK) return;
    int lane = threadIdx.x & 63;
    int b = n / TT, t = n % TT;
    int c = skills[b * SEQL + t + 1];            // cshft
    const float* wrow = outW + (size_t)c * 256;
    const float* xrow = yc + (size_t)n * 256;
    float s = 0.f;
    for (int j = lane; j < 256; j += 64) s += xrow[j] * wrow[j];
    #pragma unroll
    for (int off = 32; off > 0; off >>= 1) s += __shfl_down(s, off);
    if (lane == 0) out[n] = 1.0f / (1.0f + fexp(-(s + outB[c])));
}

// ---------------------------------------------------------------- host
static inline void gemmb(const bf16* A, int lda, const bf16* W, const float* bias,
                         bf16* C, int ldc, int M, int N, int K, int act, hipStream_t s)
{
    dim3 g(N / 128, (M + 127) / 128), b(256);
    switch (act) {
        case 0: gemm_mfma<0, bf16><<<g, b, 0, s>>>(A, lda, W, bias, C, ldc, M, N, K); break;
        case 1: gemm_mfma<1, bf16><<<g, b, 0, s>>>(A, lda, W, bias, C, ldc, M, N, K); break;
        case 3: gemm_mfma<3, bf16><<<g, b, 0, s>>>(A, lda, W, bias, C, ldc, M, N, K); break;
    }
}

extern "C" void kernel_launch(void* const* d_in, const int* in_sizes, int n_in,
                              void* d_out, int out_size, void* d_ws, size_t ws_size,
                              hipStream_t stream)
{
    const int*   skills    = (const int*)d_in[0];
    const int*   responses = (const int*)d_in[2];
    const float* embC  = (const float*)d_in[3];
    const float* embA  = (const float*)d_in[4];
    const float* embT  = (const float*)d_in[5];
    const float* embF  = (const float*)d_in[6];
    const float* mlpW1 = (const float*)d_in[9];
    const float* mlpb1 = (const float*)d_in[10];
    const float* mlpW2 = (const float*)d_in[11];
    const float* mlpb2 = (const float*)d_in[12];
    const float* inW   = (const float*)d_in[13];
    const float* convW = (const float*)d_in[14];
    const float* convb = (const float*)d_in[15];
    const float* xpW   = (const float*)d_in[16];
    const float* dtW   = (const float*)d_in[17];
    const float* dtb   = (const float*)d_in[18];
    const float* Alog  = (const float*)d_in[19];
    const float* Dp    = (const float*)d_in[20];
    const float* opW   = (const float*)d_in[21];
    const float* mnw   = (const float*)d_in[22];
    const float* fW1   = (const float*)d_in[23];
    const float* fb1   = (const float*)d_in[24];
    const float* fW2   = (const float*)d_in[25];
    const float* fb2   = (const float*)d_in[26];
    const float* fnw   = (const float*)d_in[27];
    const float* finW  = (const float*)d_in[28];
    const float* finb  = (const float*)d_in[29];
    const float* outW  = (const float*)d_in[30];
    const float* outb  = (const float*)d_in[31];

    const size_t NT = NTOK;
    // fp32 region
    float* t1   = (float*)d_ws;          // NT*256 (final gemm out)
    float* dt   = t1 + NT * 256;         // NT*512
    float* xdbl = dt + NT * 512;         // NT*128 (xproj out, padded N=128)
    // bf16 region
    bf16* y    = (bf16*)(xdbl + NT * 128);
    bf16* st   = y    + NT * 256;        // y,st,sf contiguous -> batched MLP
    bf16* sf   = st   + NT * 256;
    bf16* h1   = sf   + NT * 256;
    bf16* thid3 = h1  + NT * 256;        // 3*NT*256: mlp hidden (batched) / per-layer temp
    bf16* bufA = thid3 + 3 * NT * 256;   // NT*1024: xz / ffnmid / ycin(768)
    bf16* xc   = bufA + NT * 1024;       // NT*512
    bf16* ym   = xc   + NT * 512;        // NT*512
    // bf16 weights
    bf16* wMlp1 = ym    + NT * 512;      // 65536
    bf16* wMlp2 = wMlp1 + 65536;         // 65536
    bf16* wIn   = wMlp2 + 65536;         // 2*262144
    bf16* wOp   = wIn   + 2 * 262144;    // 2*131072
    bf16* wF1   = wOp   + 2 * 131072;    // 2*262144
    bf16* wF2   = wF1   + 2 * 262144;    // 2*262144
    bf16* wFin  = wF2   + 2 * 262144;    // 196608
    bf16* wXp   = wFin  + 196608;        // 2*65536 (xproj padded 48->128 rows)

    // 0) weight conversions
    f2bf_kernel<<<(65536 + 255) / 256, 256, 0, stream>>>(mlpW1, wMlp1, 65536);
    f2bf_kernel<<<(65536 + 255) / 256, 256, 0, stream>>>(mlpW2, wMlp2, 65536);
    f2bf_kernel<<<(524288 + 255) / 256, 256, 0, stream>>>(inW, wIn, 524288);
    f2bf_kernel<<<(262144 + 255) / 256, 256, 0, stream>>>(opW, wOp, 262144);
    f2bf_kernel<<<(524288 + 255) / 256, 256, 0, stream>>>(fW1, wF1, 524288);
    f2bf_kernel<<<(524288 + 255) / 256, 256, 0, stream>>>(fW2, wF2, 524288);
    f2bf_kernel<<<(196608 + 255) / 256, 256, 0, stream>>>(finW, wFin, 196608);
    f2bf_pad_kernel<<<(65536 + 255) / 256, 256, 0, stream>>>(xpW, wXp, 48, 128, 512);
    f2bf_pad_kernel<<<(65536 + 255) / 256, 256, 0, stream>>>(xpW + 48 * 512, wXp + 65536, 48, 128, 512);

    // 1) embeddings
    embed_kernel<<<NTOK, 256, 0, stream>>>(skills, responses, embC, embA, embT, embF, y, st, sf);

    // 2) three MLPs batched: y,st,sf contiguous -> M = 3*NTOK
    gemmb(y, 256, wMlp1, mlpb1, thid3, 256, 3 * NTOK, 256, 256, 1, stream);
    gemmb(thid3, 256, wMlp2, mlpb2, y, 256, 3 * NTOK, 256, 256, 0, stream);

    // 3) two mamba layers
    for (int i = 0; i < 2; ++i) {
        gemmb(y, 256, wIn + (size_t)i * 262144, nullptr, bufA, 1024, NTOK, 1024, 256, 0, stream);
        conv_silu_kernel<<<(NTOK * 512) / 256, 256, 0, stream>>>(bufA, convW + i * 2048, convb + i * 512, xc);
        {   // xproj: MFMA, N padded to 128 (rows 48..127 zero), out fp32 stride 128
            dim3 g(1, (NTOK + 127) / 128);
            gemm_mfma<0, float><<<g, 256, 0, stream>>>(xc, 512, wXp + (size_t)i * 65536, nullptr, xdbl, 128, NTOK, 128, 512);
        }
        {   // dtproj: K=16, VALU path, fp32 A (lda=128), softplus
            dim3 g((512 + 63) / 64, (NTOK + 63) / 64);
            gemm_kernel<2><<<g, 256, 0, stream>>>(xdbl, 128, dtW + (size_t)i * 512 * 16, dtb + i * 512, dt, 512, NTOK, 512, 16);
        }
        scan_kernel<<<BATCH * 32, 256, 0, stream>>>(dt, xc, xdbl, bufA, Alog + i * 8192, Dp + i * 512, ym);
        gemmb(ym, 512, wOp + (size_t)i * 131072, nullptr, thid3, 256, NTOK, 256, 512, 0, stream);
        rmsnorm_kernel<<<NTOK, 256, 0, stream>>>(thid3, y, mnw + i * 256, h1, nullptr);
        gemmb(h1, 256, wF1 + (size_t)i * 262144, fb1 + i * 1024, bufA, 1024, NTOK, 1024, 256, 3, stream);
        gemmb(bufA, 1024, wF2 + (size_t)i * 262144, fb2 + i * 256, thid3, 256, NTOK, 256, 1024, 0, stream);
        // final layer's rmsnorm also writes ycin cols 0..255 (replaces copy kernel)
        rmsnorm_kernel<<<NTOK, 256, 0, stream>>>(thid3, h1, fnw + i * 256, y, (i == 1) ? bufA : nullptr);
    }

    // 4) dual attention into ycin = bufA (stride 768)
    attn_kernel<<<BATCH * 8 * 8, 256, 0, stream>>>(y, st, sf, bufA);

    // 5) final projection + gathered sigmoid
    {
        dim3 g(256 / 128, (NTOK + 127) / 128);
        gemm_mfma<0, float><<<g, 256, 0, stream>>>(bufA, 768, wFin, finb, t1, 256, NTOK, 256, 768);
    }
    pred_kernel<<<NTOK / 4, 256, 0, stream>>>(t1, skills, outW, outb, (float*)d_out);
}

// Round 8
// 746.619 us; speedup vs baseline: 7.6463x; 1.0415x over previous
//
#include <hip/hip_runtime.h>
#include <hip/hip_bf16.h>
#include <math.h>
#include <string.h>

#define BATCH 32
#define SEQL  512
#define TT    511          // T = L-1
#define DMODEL 256
#define DIN   512          // DI = EXP*D
#define DSN   16           // DS
#define NSK   500
#define NTOK  (BATCH*TT)   // 16352

typedef __hip_bfloat16 bf16;
typedef __attribute__((ext_vector_type(8))) short short8;
typedef __attribute__((ext_vector_type(4))) float f32x4;

#define L2E 1.4426950408889634f
#define LN2 0.6931471805599453f

__device__ inline float fexp(float x) { return __builtin_amdgcn_exp2f(x * L2E); }

__device__ inline unsigned pack_bf2(float a, float b) {
    bf16 ba = __float2bfloat16(a), bb = __float2bfloat16(b);
    unsigned short ua, ub; memcpy(&ua, &ba, 2); memcpy(&ub, &bb, 2);
    return (unsigned)ua | ((unsigned)ub << 16);
}

// async global->LDS, 16B per lane; LDS dest is wave-uniform base + lane*16
__device__ inline void glds16(const bf16* g, short* l) {
    __builtin_amdgcn_global_load_lds(
        (const __attribute__((address_space(1))) unsigned int*)g,
        (__attribute__((address_space(3))) unsigned int*)l,
        16, 0, 0);
}

// ---------------------------------------------------------------- fp32 -> bf16 weight conversion
__global__ __launch_bounds__(256) void f2bf_kernel(const float* __restrict__ in, bf16* __restrict__ out, int n)
{
    int i = blockIdx.x * 256 + threadIdx.x;
    if (i < n) out[i] = __float2bfloat16(in[i]);
}

// pad rows: out[r*K+k] = r<rows_in ? in[r*K+k] : 0   (rows_out x K)
__global__ __launch_bounds__(256) void f2bf_pad_kernel(const float* __restrict__ in, bf16* __restrict__ out,
                                                        int rows_in, int rows_out, int K)
{
    int i = blockIdx.x * 256 + threadIdx.x;
    if (i >= rows_out * K) return;
    int r = i / K;
    out[i] = (r < rows_in) ? __float2bfloat16(in[i]) : __float2bfloat16(0.f);
}

// ---------------------------------------------------------------- embeddings (bf16 out)
__global__ __launch_bounds__(256) void embed_kernel(
    const int* __restrict__ skills, const int* __restrict__ responses,
    const float* __restrict__ embC, const float* __restrict__ embA,
    const float* __restrict__ embT, const float* __restrict__ embF,
    bf16* __restrict__ o_state, bf16* __restrict__ o_st, bf16* __restrict__ o_sf)
{
    int idx = blockIdx.x * 256 + threadIdx.x;      // < NTOK*256
    int n = idx >> 8, j = idx & 255;
    int b = n / TT, t = n % TT;
    int c = skills[b * SEQL + t];
    int r = responses[b * SEQL + t];
    r = (r > -1) ? r : 0;                          // masked_r
    o_state[idx] = __float2bfloat16(embA[r * DMODEL + j] + embC[c * DMODEL + j]);
    o_st[idx]    = __float2bfloat16(embT[(r * (c + NSK)) * DMODEL + j]);
    o_sf[idx]    = __float2bfloat16(embF[(c * (1 - r)) * DMODEL + j]);
}

// ---------------------------------------------------------------- MFMA bf16 GEMM (glds + LDS double-buffer)
// C[M,N] = act(A[M,K](lda) @ W[N,K]^T + bias[N]); K%32==0, N%128==0.
// grid = (rowPanels, colPanels): bid%8 = rowPanel%8 -> one A-panel per XCD L2.
// Staging: global_load_lds 16B/lane into linear [128][32] tiles; stage(k+1)
// issued before compute(k); ONE barrier per K-step (dbuf).
template<int ACT, typename OUTT>   // ACT: 0 none, 1 tanh, 3 gelu-exact
__global__ __launch_bounds__(256) void gemm_mfma(
    const bf16* __restrict__ A, int lda,
    const bf16* __restrict__ W,
    const float* __restrict__ bias,
    OUTT* __restrict__ C, int ldc,
    int M, int N, int K)
{
    __shared__ short As[2][128 * 32];
    __shared__ short Ws[2][128 * 32];
    const int tx = threadIdx.x;
    const int lane = tx & 63;
    const int wv = tx >> 6;
    const int rowBase = blockIdx.x * 128;
    const int colBase = blockIdx.y * 128;
    const int wrb = (wv >> 1) * 64;
    const int wcb = (wv & 1) * 64;

    f32x4 acc[4][4];
    #pragma unroll
    for (int m = 0; m < 4; ++m)
        #pragma unroll
        for (int n = 0; n < 4; ++n)
            acc[m][n] = (f32x4){0.f, 0.f, 0.f, 0.f};

    // staging: wave wv owns 1KB chunks 2wv, 2wv+1 of each tile (16 rows/chunk);
    // lane i covers 16B: row = i>>2, k-offset = (i&3)*8 shorts (linear = base+i*16)
    const int srow16 = lane >> 2;
    const int sko    = (lane & 3) * 8;
    const int ca     = wv * 2;

    const int nst = K >> 5;
    const int kq = (lane >> 4) * 8;
    const int rl = lane & 15;

    // prologue: stage tile 0
    #pragma unroll
    for (int cc = 0; cc < 2; ++cc) {
        int c = ca + cc;
        int gr = rowBase + c * 16 + srow16;
        if (gr < M) glds16(A + (size_t)gr * lda + sko, &As[0][c * 512]);
        int gc = colBase + c * 16 + srow16;
        glds16(W + (size_t)gc * K + sko, &Ws[0][c * 512]);
    }
    __syncthreads();

    int buf = 0;
    for (int s = 0; s < nst; ++s) {
        if (s + 1 < nst) {
            const int k0 = (s + 1) << 5;
            #pragma unroll
            for (int cc = 0; cc < 2; ++cc) {
                int c = ca + cc;
                int gr = rowBase + c * 16 + srow16;
                if (gr < M) glds16(A + (size_t)gr * lda + k0 + sko, &As[buf ^ 1][c * 512]);
                int gc = colBase + c * 16 + srow16;
                glds16(W + (size_t)gc * K + k0 + sko, &Ws[buf ^ 1][c * 512]);
            }
        }
        short8 af[4], bfr[4];
        #pragma unroll
        for (int m = 0; m < 4; ++m) af[m]  = *(const short8*)&As[buf][(wrb + m * 16 + rl) * 32 + kq];
        #pragma unroll
        for (int n = 0; n < 4; ++n) bfr[n] = *(const short8*)&Ws[buf][(wcb + n * 16 + rl) * 32 + kq];
        #pragma unroll
        for (int m = 0; m < 4; ++m)
            #pragma unroll
            for (int n = 0; n < 4; ++n)
                acc[m][n] = __builtin_amdgcn_mfma_f32_16x16x32_bf16(af[m], bfr[n], acc[m][n], 0, 0, 0);
        __syncthreads();   // drains glds (vmcnt) + ds_reads (lgkm) for buffer swap
        buf ^= 1;
    }

    // epilogue: C/D layout col=lane&15, row=(lane>>4)*4+reg  [m89/m91]
    const int rq = (lane >> 4) * 4;
    const int cl = lane & 15;
    #pragma unroll
    for (int m = 0; m < 4; ++m) {
        #pragma unroll
        for (int i = 0; i < 4; ++i) {
            int row = rowBase + wrb + m * 16 + rq + i;
            if (row >= M) continue;
            #pragma unroll
            for (int n = 0; n < 4; ++n) {
                int col = colBase + wcb + n * 16 + cl;
                float x = acc[m][n][i];
                if (bias) x += bias[col];
                if (ACT == 1) x = tanhf(x);
                else if (ACT == 3) x = 0.5f * x * (1.f + erff(x * 0.70710678118654752440f));
                C[(size_t)row * ldc + col] = OUTT(x);
            }
        }
    }
}

// ---------------------------------------------------------------- small VALU GEMM (dtproj K=16)
template<int ACT>   // 0 none, 2 softplus
__global__ __launch_bounds__(256) void gemm_kernel(
    const float* __restrict__ A, int lda,
    const float* __restrict__ W,
    const float* __restrict__ bias,
    float* __restrict__ C, int ldc,
    int M, int N, int K)
{
    __shared__ float As[64][17];
    __shared__ float Ws[64][17];
    const int tx = threadIdx.x;
    const int rowBase = blockIdx.y * 64;
    const int colBase = blockIdx.x * 64;
    const int lr = tx >> 2;
    const int lk = (tx & 3) << 2;
    const int tr = (tx >> 4) << 2;
    const int tc = (tx & 15) << 2;
    float acc[4][4] = {};

    for (int k0 = 0; k0 < K; k0 += 16) {
        float4 av = make_float4(0.f, 0.f, 0.f, 0.f);
        int ar = rowBase + lr;
        if (ar < M) av = *reinterpret_cast<const float4*>(A + (size_t)ar * lda + k0 + lk);
        As[lr][lk] = av.x; As[lr][lk + 1] = av.y; As[lr][lk + 2] = av.z; As[lr][lk + 3] = av.w;
        float4 wvv = make_float4(0.f, 0.f, 0.f, 0.f);
        int wr = colBase + lr;
        if (wr < N) wvv = *reinterpret_cast<const float4*>(W + (size_t)wr * K + k0 + lk);
        Ws[lr][lk] = wvv.x; Ws[lr][lk + 1] = wvv.y; Ws[lr][lk + 2] = wvv.z; Ws[lr][lk + 3] = wvv.w;
        __syncthreads();
        #pragma unroll
        for (int k = 0; k < 16; ++k) {
            float a0 = As[tr][k], a1 = As[tr + 1][k], a2 = As[tr + 2][k], a3 = As[tr + 3][k];
            float b0 = Ws[tc][k], b1 = Ws[tc + 1][k], b2 = Ws[tc + 2][k], b3 = Ws[tc + 3][k];
            acc[0][0] += a0 * b0; acc[0][1] += a0 * b1; acc[0][2] += a0 * b2; acc[0][3] += a0 * b3;
            acc[1][0] += a1 * b0; acc[1][1] += a1 * b1; acc[1][2] += a1 * b2; acc[1][3] += a1 * b3;
            acc[2][0] += a2 * b0; acc[2][1] += a2 * b1; acc[2][2] += a2 * b2; acc[2][3] += a2 * b3;
            acc[3][0] += a3 * b0; acc[3][1] += a3 * b1; acc[3][2] += a3 * b2; acc[3][3] += a3 * b3;
        }
        __syncthreads();
    }

    #pragma unroll
    for (int i = 0; i < 4; ++i) {
        int r = rowBase + tr + i;
        if (r >= M) break;
        int cb = colBase + tc;
        if (cb >= N) continue;
        float4 v;
        float* vp = &v.x;
        #pragma unroll
        for (int j = 0; j < 4; ++j) {
            float x = acc[i][j];
            if (bias) x += bias[cb + j];
            if (ACT == 2) {   // softplus via native exp2/log2
                float e = __builtin_amdgcn_exp2f(-fabsf(x) * L2E);
                x = fmaxf(x, 0.f) + __builtin_amdgcn_logf(1.f + e) * LN2;
            }
            vp[j] = x;
        }
        *reinterpret_cast<float4*>(C + (size_t)r * ldc + cb) = v;
    }
}

// ---------------------------------------------------------------- conv1d(4, causal, depthwise) + silu (bf16 io)
__global__ __launch_bounds__(256) void conv_silu_kernel(
    const bf16* __restrict__ xz,    // (NTOK,1024), xc part = cols 0..511
    const float* __restrict__ cW,   // (512,4)
    const float* __restrict__ cb,   // (512)
    bf16* __restrict__ xc)          // (NTOK,512)
{
    int idx = blockIdx.x * 256 + threadIdx.x;     // < NTOK*512
    int d = idx & 511;
    int n = idx >> 9;
    int b = n / TT, t = n % TT;
    float w0 = cW[d * 4], w1 = cW[d * 4 + 1], w2 = cW[d * 4 + 2], w3 = cW[d * 4 + 3];
    const bf16* base = xz + (size_t)(b * TT) * 1024 + d;
    float acc = cb[d];
    if (t >= 3) acc += w0 * __bfloat162float(base[(size_t)(t - 3) * 1024]);
    if (t >= 2) acc += w1 * __bfloat162float(base[(size_t)(t - 2) * 1024]);
    if (t >= 1) acc += w2 * __bfloat162float(base[(size_t)(t - 1) * 1024]);
    acc += w3 * __bfloat162float(base[(size_t)t * 1024]);
    xc[idx] = __float2bfloat16(acc / (1.f + fexp(-acc)));   // silu
}

// ---------------------------------------------------------------- chunk-parallel selective scan (no shuffles)
__global__ __launch_bounds__(256) void scan_kernel(
    const float* __restrict__ dt,     // (NTOK,512)
    const bf16* __restrict__ xc,      // (NTOK,512)
    const float* __restrict__ xdbl,   // (NTOK,128): [dtr(16) | B(16) | C(16) | pad]
    const bf16* __restrict__ xz,      // (NTOK,1024): z = cols 512..1023
    const float* __restrict__ Alog,   // (512,16)
    const float* __restrict__ Dpv,    // (512)
    bf16* __restrict__ ym)            // (NTOK,512)
{
    __shared__ float smry[256][33];   // [chunk*16+dl][P(16) | h(16)], pad 33

    const int tx = threadIdx.x;
    const int dl = tx & 15;
    const int c  = tx >> 4;           // chunk 0..15
    const int b  = blockIdx.x >> 5;
    const int d  = ((blockIdx.x & 31) << 4) + dl;

    float A2[16];
    {
        const float* Ap = Alog + d * 16;
        #pragma unroll
        for (int s = 0; s < 16; ++s) A2[s] = -expf(Ap[s]) * L2E;   // pre-scaled by log2e
    }
    const float Dv = Dpv[d];
    const size_t nb = (size_t)b * TT;
    const int t0 = c * 32;
    const int t1 = (t0 + 32 < TT) ? (t0 + 32) : TT;

    float h[16];
    float sdt = 0.f;
    #pragma unroll
    for (int s = 0; s < 16; ++s) h[s] = 0.f;

    // pass 1: local scan (h from 0) + dt sum
    for (int t = t0; t < t1; ++t) {
        const size_t n = nb + t;
        const float dtt = dt[n * 512 + d];
        const float xt  = __bfloat162float(xc[n * 512 + d]);
        const float dx  = dtt * xt;
        sdt += dtt;
        const float* Bp = xdbl + n * 128 + 16;
        const float4 b0 = *(const float4*)(Bp);
        const float4 b1 = *(const float4*)(Bp + 4);
        const float4 b2 = *(const float4*)(Bp + 8);
        const float4 b3 = *(const float4*)(Bp + 12);
        const float Bv[16] = {b0.x,b0.y,b0.z,b0.w, b1.x,b1.y,b1.z,b1.w,
                              b2.x,b2.y,b2.z,b2.w, b3.x,b3.y,b3.z,b3.w};
        #pragma unroll
        for (int s = 0; s < 16; ++s) {
            const float e = __builtin_amdgcn_exp2f(dtt * A2[s]);
            h[s] = e * h[s] + dx * Bv[s];
        }
    }
    #pragma unroll
    for (int s = 0; s < 16; ++s) {
        smry[tx][s]      = __builtin_amdgcn_exp2f(A2[s] * sdt);   // chunk decay product
        smry[tx][16 + s] = h[s];
    }
    __syncthreads();

    // prefix combine (oldest chunk first): h_init for this chunk
    #pragma unroll
    for (int s = 0; s < 16; ++s) h[s] = 0.f;
    for (int cc = 0; cc < c; ++cc) {
        const float* S = smry[(cc << 4) + dl];
        #pragma unroll
        for (int s = 0; s < 16; ++s) h[s] = S[s] * h[s] + S[16 + s];
    }

    // pass 2: rescan from h_init, emit ym
    for (int t = t0; t < t1; ++t) {
        const size_t n = nb + t;
        const float dtt = dt[n * 512 + d];
        const float xt  = __bfloat162float(xc[n * 512 + d]);
        const float dx  = dtt * xt;
        const float* Bp = xdbl + n * 128 + 16;
        const float4 b0 = *(const float4*)(Bp);
        const float4 b1 = *(const float4*)(Bp + 4);
        const float4 b2 = *(const float4*)(Bp + 8);
        const float4 b3 = *(const float4*)(Bp + 12);
        const float4 c0 = *(const float4*)(Bp + 16);
        const float4 c1 = *(const float4*)(Bp + 20);
        const float4 c2 = *(const float4*)(Bp + 24);
        const float4 c3 = *(const float4*)(Bp + 28);
        const float Bv[16] = {b0.x,b0.y,b0.z,b0.w, b1.x,b1.y,b1.z,b1.w,
                              b2.x,b2.y,b2.z,b2.w, b3.x,b3.y,b3.z,b3.w};
        const float Cv[16] = {c0.x,c0.y,c0.z,c0.w, c1.x,c1.y,c1.z,c1.w,
                              c2.x,c2.y,c2.z,c2.w, c3.x,c3.y,c3.z,c3.w};
        float y = 0.f;
        #pragma unroll
        for (int s = 0; s < 16; ++s) {
            const float e = __builtin_amdgcn_exp2f(dtt * A2[s]);
            h[s] = e * h[s] + dx * Bv[s];
            y += h[s] * Cv[s];
        }
        const float zz = __bfloat162float(xz[n * 1024 + 512 + d]);
        const float v = (y + xt * Dv) * (zz / (1.f + fexp(-zz)));
        ym[n * 512 + d] = __float2bfloat16(v);
    }
}

// ---------------------------------------------------------------- rmsnorm(a+b)*w  (bf16 io, fp32 math)
__global__ __launch_bounds__(256) void rmsnorm_kernel(
    const bf16* __restrict__ a, const bf16* __restrict__ b,
    const float* __restrict__ w, bf16* __restrict__ out,
    bf16* __restrict__ out768)
{
    __shared__ float red[256];
    int n = blockIdx.x, j = threadIdx.x;
    float v = __bfloat162float(a[(size_t)n * 256 + j]) + __bfloat162float(b[(size_t)n * 256 + j]);
    red[j] = v * v;
    __syncthreads();
    for (int s = 128; s > 0; s >>= 1) { if (j < s) red[j] += red[j + s]; __syncthreads(); }
    float scale = rsqrtf(red[0] / 256.0f + 1e-12f);
    bf16 r = __float2bfloat16(v * scale * w[j]);
    out[(size_t)n * 256 + j] = r;
    if (out768) out768[(size_t)n * 768 + j] = r;
}

// ---------------------------------------------------------------- MFMA dual flash attention
__global__ __launch_bounds__(256) void attn_kernel(
    const bf16* __restrict__ y,    // (B,TT,256) q = k
    const bf16* __restrict__ st,   // v1
    const bf16* __restrict__ sf,   // v2
    bf16* __restrict__ ycin)       // (B,TT,768), writes cols 256..767
{
    __shared__ short Ks[64 * 40];      // K[key][d], row stride 40 shorts (80B)
    __shared__ short Vt[2][32 * 88];   // V^T[d][key], row stride 88 shorts (176B)
    __shared__ short Pl[64 * 88];      // P[q][key] bf16, row stride 88 shorts

    const int bid = blockIdx.x;        // ((b*8)+h)*8 + qt
    const int qt = bid & 7;
    const int h  = (bid >> 3) & 7;
    const int b  = bid >> 6;
    const int tx = threadIdx.x;
    const int w  = tx >> 6;            // wave 0..3
    const int lane = tx & 63;
    const int g  = lane >> 4;          // 0..3
    const int l15 = lane & 15;
    const int q0 = qt * 64;
    const int qg = q0 + w * 16 + l15;  // this lane's q row (S^T col)
    const float scale = 0.17677669529663687f;   // 1/sqrt(32)

    const bf16* ybase  = y  + (size_t)(b * TT) * 256 + h * 32;
    const bf16* v1base = st + (size_t)(b * TT) * 256 + h * 32;
    const bf16* v2base = sf + (size_t)(b * TT) * 256 + h * 32;

    // Q fragment (B operand): col=q=lane&15, k-slice d=(lane>>4)*8..+7
    short8 qf = {};
    if (qg < TT) qf = *(const short8*)(ybase + (size_t)qg * 256 + g * 8);

    float m = -INFINITY, l = 0.f;
    f32x4 o[2][2];                     // [v][dsub]
    #pragma unroll
    for (int v = 0; v < 2; ++v) { o[v][0] = (f32x4){0,0,0,0}; o[v][1] = (f32x4){0,0,0,0}; }

    const int sr = tx >> 2;            // staging key row 0..63
    const int sc = (tx & 3) * 8;       // staging d base

    const int nkt = (qt == 0) ? 8 : (qt + 1);
    for (int kt = 0; kt < nkt; ++kt) {
        const int k0 = kt * 64;
        __syncthreads();               // previous tile's LDS reads done
        {
            int kgr = k0 + sr;
            short8 kv = {}, v1v = {}, v2v = {};
            if (kgr < TT) {
                kv  = *(const short8*)(ybase  + (size_t)kgr * 256 + sc);
                v1v = *(const short8*)(v1base + (size_t)kgr * 256 + sc);
                v2v = *(const short8*)(v2base + (size_t)kgr * 256 + sc);
            }
            *(short8*)&Ks[sr * 40 + sc] = kv;
            #pragma unroll
            for (int i = 0; i < 8; ++i) {
                Vt[0][(sc + i) * 88 + sr] = v1v[i];
                Vt[1][(sc + i) * 88 + sr] = v2v[i];
            }
        }
        __syncthreads();

        // S^T[key][q]: 4 mfmas, each 16 keys x 16 q, K=32 (full head dim)
        f32x4 s[4];
        #pragma unroll
        for (int jm = 0; jm < 4; ++jm) {
            short8 kf = *(const short8*)&Ks[(jm * 16 + l15) * 40 + g * 8];
            s[jm] = __builtin_amdgcn_mfma_f32_16x16x32_bf16(kf, qf, (f32x4){0,0,0,0}, 0, 0, 0);
        }
        // mask + tile max (per lane: all 16 values are q=qg)
        float tm = -INFINITY;
        #pragma unroll
        for (int jm = 0; jm < 4; ++jm)
            #pragma unroll
            for (int r = 0; r < 4; ++r) {
                int kk = k0 + jm * 16 + g * 4 + r;
                float sv = s[jm][r];
                sv = (kk < qg) ? sv * scale : ((kk < TT) ? -1e9f : -INFINITY);
                s[jm][r] = sv;
                tm = fmaxf(tm, sv);
            }
        tm = fmaxf(tm, __shfl_xor(tm, 16));
        tm = fmaxf(tm, __shfl_xor(tm, 32));
        float mn = fmaxf(m, tm);
        float rs = fexp(m - mn);       // m==-inf -> 0
        m = mn;
        float ts = 0.f;
        #pragma unroll
        for (int jm = 0; jm < 4; ++jm)
            #pragma unroll
            for (int r = 0; r < 4; ++r) {
                float e = fexp(s[jm][r] - mn);
                s[jm][r] = e;
                ts += e;
            }
        ts += __shfl_xor(ts, 16);
        ts += __shfl_xor(ts, 32);
        l = l * rs + ts;
        // P -> LDS as bf16 (u32 pair writes; row q, key 16*jm+4*g+{0..3})
        #pragma unroll
        for (int jm = 0; jm < 4; ++jm) {
            *(unsigned*)&Pl[(w * 16 + l15) * 88 + jm * 16 + g * 4]     = pack_bf2(s[jm][0], s[jm][1]);
            *(unsigned*)&Pl[(w * 16 + l15) * 88 + jm * 16 + g * 4 + 2] = pack_bf2(s[jm][2], s[jm][3]);
        }
        // rescale O accs: O row = 4*g+reg -> factor lives in lane (q row)
        float rq[4];
        #pragma unroll
        for (int r = 0; r < 4; ++r) rq[r] = __shfl(rs, 4 * g + r);
        #pragma unroll
        for (int v = 0; v < 2; ++v)
            #pragma unroll
            for (int d = 0; d < 2; ++d)
                #pragma unroll
                for (int r = 0; r < 4; ++r)
                    o[v][d][r] *= rq[r];
        // PV: A = P (row=q=lane&15, k=keys), B = Vt (col=d=lane&15, k=keys)
        #pragma unroll
        for (int ks = 0; ks < 2; ++ks) {
            short8 pf = *(const short8*)&Pl[(w * 16 + l15) * 88 + ks * 32 + g * 8];
            #pragma unroll
            for (int v = 0; v < 2; ++v)
                #pragma unroll
                for (int d = 0; d < 2; ++d) {
                    short8 vf = *(const short8*)&Vt[v][(d * 16 + l15) * 88 + ks * 32 + g * 8];
                    o[v][d] = __builtin_amdgcn_mfma_f32_16x16x32_bf16(pf, vf, o[v][d], 0, 0, 0);
                }
        }
    }

    // epilogue: O row = q0+w*16+4*g+r, col d = lane&15
    float invl = 1.0f / l;             // per q = lane&15
    float iq[4];
    #pragma unroll
    for (int r = 0; r < 4; ++r) iq[r] = __shfl(invl, 4 * g + r);
    #pragma unroll
    for (int r = 0; r < 4; ++r) {
        int rowq = q0 + w * 16 + 4 * g + r;
        if (rowq >= TT) continue;
        bf16* dst = ycin + (size_t)(b * TT + rowq) * 768 + 256;
        #pragma unroll
        for (int v = 0; v < 2; ++v)
            #pragma unroll
            for (int d = 0; d < 2; ++d)
                dst[v * 256 + h * 32 + d * 16 + l15] = __float2bfloat16(o[v][d][r] * iq[r]);
    }
}

// ---------------------------------------------------------------- gathered logit + sigmoid
__global__ __launch_bounds__(256) void pred_kernel(
    const float* __restrict__ yc,     // (NTOK,256)
    const int* __restrict__ skills,
    const float* __restrict__ outW,   // (500,256)
    const float* __restrict__ outB,   // (500)
    float* __restrict__ out)          // (NTOK)
{
    int n = blockIdx.x * 4 + (threadIdx.x >> 6);
    if (n >= NTOK) return;
    int lane = threadIdx.x & 63;
    int b = n / TT, t = n % TT;
    int c = skills[b * SEQL + t + 1];            // cshft
    const float* wrow = outW + (size_t)c * 256;
    const float* xrow = yc + (size_t)n * 256;
    float s = 0.f;
    for (int j = lane; j < 256; j += 64) s += xrow[j] * wrow[j];
    #pragma unroll
    for (int off = 32; off > 0; off >>= 1) s += __shfl_down(s, off);
    if (lane == 0) out[n] = 1.0f / (1.0f + fexp(-(s + outB[c])));
}

// ---------------------------------------------------------------- host
static inline void gemmb(const bf16* A, int lda, const bf16* W, const float* bias,
                         bf16* C, int ldc, int M, int N, int K, int act, hipStream_t s)
{
    dim3 g((M + 127) / 128, N / 128), b(256);   // grid: (rowPanels, colPanels) for XCD L2 locality
    switch (act) {
        case 0: gemm_mfma<0, bf16><<<g, b, 0, s>>>(A, lda, W, bias, C, ldc, M, N, K); break;
        case 1: gemm_mfma<1, bf16><<<g, b, 0, s>>>(A, lda, W, bias, C, ldc, M, N, K); break;
        case 3: gemm_mfma<3, bf16><<<g, b, 0, s>>>(A, lda, W, bias, C, ldc, M, N, K); break;
    }
}

extern "C" void kernel_launch(void* const* d_in, const int* in_sizes, int n_in,
                              void* d_out, int out_size, void* d_ws, size_t ws_size,
                              hipStream_t stream)
{
    const int*   skills    = (const int*)d_in[0];
    const int*   responses = (const int*)d_in[2];
    const float* embC  = (const float*)d_in[3];
    const float* embA  = (const float*)d_in[4];
    const float* embT  = (const float*)d_in[5];
    const float* embF  = (const float*)d_in[6];
    const float* mlpW1 = (const float*)d_in[9];
    const float* mlpb1 = (const float*)d_in[10];
    const float* mlpW2 = (const float*)d_in[11];
    const float* mlpb2 = (const float*)d_in[12];
    const float* inW   = (const float*)d_in[13];
    const float* convW = (const float*)d_in[14];
    const float* convb = (const float*)d_in[15];
    const float* xpW   = (const float*)d_in[16];
    const float* dtW   = (const float*)d_in[17];
    const float* dtb   = (const float*)d_in[18];
    const float* Alog  = (const float*)d_in[19];
    const float* Dp    = (const float*)d_in[20];
    const float* opW   = (const float*)d_in[21];
    const float* mnw   = (const float*)d_in[22];
    const float* fW1   = (const float*)d_in[23];
    const float* fb1   = (const float*)d_in[24];
    const float* fW2   = (const float*)d_in[25];
    const float* fb2   = (const float*)d_in[26];
    const float* fnw   = (const float*)d_in[27];
    const float* finW  = (const float*)d_in[28];
    const float* finb  = (const float*)d_in[29];
    const float* outW  = (const float*)d_in[30];
    const float* outb  = (const float*)d_in[31];

    const size_t NT = NTOK;
    // fp32 region
    float* t1   = (float*)d_ws;          // NT*256 (final gemm out)
    float* dt   = t1 + NT * 256;         // NT*512
    float* xdbl = dt + NT * 512;         // NT*128 (xproj out, padded N=128)
    // bf16 region
    bf16* y    = (bf16*)(xdbl + NT * 128);
    bf16* st   = y    + NT * 256;        // y,st,sf contiguous -> batched MLP
    bf16* sf   = st   + NT * 256;
    bf16* h1   = sf   + NT * 256;
    bf16* thid3 = h1  + NT * 256;        // 3*NT*256: mlp hidden (batched) / per-layer temp
    bf16* bufA = thid3 + 3 * NT * 256;   // NT*1024: xz / ffnmid / ycin(768)
    bf16* xc   = bufA + NT * 1024;       // NT*512
    bf16* ym   = xc   + NT * 512;        // NT*512
    // bf16 weights
    bf16* wMlp1 = ym    + NT * 512;      // 65536
    bf16* wMlp2 = wMlp1 + 65536;         // 65536
    bf16* wIn   = wMlp2 + 65536;         // 2*262144
    bf16* wOp   = wIn   + 2 * 262144;    // 2*131072
    bf16* wF1   = wOp   + 2 * 131072;    // 2*262144
    bf16* wF2   = wF1   + 2 * 262144;    // 2*262144
    bf16* wFin  = wF2   + 2 * 262144;    // 196608
    bf16* wXp   = wFin  + 196608;        // 2*65536 (xproj padded 48->128 rows)

    // 0) weight conversions
    f2bf_kernel<<<(65536 + 255) / 256, 256, 0, stream>>>(mlpW1, wMlp1, 65536);
    f2bf_kernel<<<(65536 + 255) / 256, 256, 0, stream>>>(mlpW2, wMlp2, 65536);
    f2bf_kernel<<<(524288 + 255) / 256, 256, 0, stream>>>(inW, wIn, 524288);
    f2bf_kernel<<<(262144 + 255) / 256, 256, 0, stream>>>(opW, wOp, 262144);
    f2bf_kernel<<<(524288 + 255) / 256, 256, 0, stream>>>(fW1, wF1, 524288);
    f2bf_kernel<<<(524288 + 255) / 256, 256, 0, stream>>>(fW2, wF2, 524288);
    f2bf_kernel<<<(196608 + 255) / 256, 256, 0, stream>>>(finW, wFin, 196608);
    f2bf_pad_kernel<<<(65536 + 255) / 256, 256, 0, stream>>>(xpW, wXp, 48, 128, 512);
    f2bf_pad_kernel<<<(65536 + 255) / 256, 256, 0, stream>>>(xpW + 48 * 512, wXp + 65536, 48, 128, 512);

    // 1) embeddings
    embed_kernel<<<NTOK, 256, 0, stream>>>(skills, responses, embC, embA, embT, embF, y, st, sf);

    // 2) three MLPs batched: y,st,sf contiguous -> M = 3*NTOK
    gemmb(y, 256, wMlp1, mlpb1, thid3, 256, 3 * NTOK, 256, 256, 1, stream);
    gemmb(thid3, 256, wMlp2, mlpb2, y, 256, 3 * NTOK, 256, 256, 0, stream);

    // 3) two mamba layers
    for (int i = 0; i < 2; ++i) {
        gemmb(y, 256, wIn + (size_t)i * 262144, nullptr, bufA, 1024, NTOK, 1024, 256, 0, stream);
        conv_silu_kernel<<<(NTOK * 512) / 256, 256, 0, stream>>>(bufA, convW + i * 2048, convb + i * 512, xc);
        {   // xproj: MFMA, N padded to 128 (rows 48..127 zero), out fp32 stride 128
            dim3 g((NTOK + 127) / 128, 1);
            gemm_mfma<0, float><<<g, 256, 0, stream>>>(xc, 512, wXp + (size_t)i * 65536, nullptr, xdbl, 128, NTOK, 128, 512);
        }
        {   // dtproj: K=16, VALU path, fp32 A (lda=128), softplus
            dim3 g((512 + 63) / 64, (NTOK + 63) / 64);
            gemm_kernel<2><<<g, 256, 0, stream>>>(xdbl, 128, dtW + (size_t)i * 512 * 16, dtb + i * 512, dt, 512, NTOK, 512, 16);
        }
        scan_kernel<<<BATCH * 32, 256, 0, stream>>>(dt, xc, xdbl, bufA, Alog + i * 8192, Dp + i * 512, ym);
        gemmb(ym, 512, wOp + (size_t)i * 131072, nullptr, thid3, 256, NTOK, 256, 512, 0, stream);
        rmsnorm_kernel<<<NTOK, 256, 0, stream>>>(thid3, y, mnw + i * 256, h1, nullptr);
        gemmb(h1, 256, wF1 + (size_t)i * 262144, fb1 + i * 1024, bufA, 1024, NTOK, 1024, 256, 3, stream);
        gemmb(bufA, 1024, wF2 + (size_t)i * 262144, fb2 + i * 256, thid3, 256, NTOK, 256, 1024, 0, stream);
        // final layer's rmsnorm also writes ycin cols 0..255 (replaces copy kernel)
        rmsnorm_kernel<<<NTOK, 256, 0, stream>>>(thid3, h1, fnw + i * 256, y, (i == 1) ? bufA : nullptr);
    }

    // 4) dual attention into ycin = bufA (stride 768)
    attn_kernel<<<BATCH * 8 * 8, 256, 0, stream>>>(y, st, sf, bufA);

    // 5) final projection + gathered sigmoid
    {
        dim3 g((NTOK + 127) / 128, 2);
        gemm_mfma<0, float><<<g, 256, 0, stream>>>(bufA, 768, wFin, finb, t1, 256, NTOK, 256, 768);
    }
    pred_kernel<<<NTOK / 4, 256, 0, stream>>>(t1, skills, outW, outb, (float*)d_out);
}

// Round 9
// 745.882 us; speedup vs baseline: 7.6538x; 1.0010x over previous
//
#include <hip/hip_runtime.h>
#include <hip/hip_bf16.h>
#include <math.h>
#include <string.h>

#define BATCH 32
#define SEQL  512
#define TT    511          // T = L-1
#define DMODEL 256
#define DIN   512          // DI = EXP*D
#define DSN   16           // DS
#define NSK   500
#define NTOK  (BATCH*TT)   // 16352

typedef __hip_bfloat16 bf16;
typedef __attribute__((ext_vector_type(8))) short short8;
typedef __attribute__((ext_vector_type(4))) float f32x4;

#define L2E 1.4426950408889634f
#define LN2 0.6931471805599453f

__device__ inline float fexp(float x) { return __builtin_amdgcn_exp2f(x * L2E); }

__device__ inline unsigned pack_bf2(float a, float b) {
    bf16 ba = __float2bfloat16(a), bb = __float2bfloat16(b);
    unsigned short ua, ub; memcpy(&ua, &ba, 2); memcpy(&ub, &bb, 2);
    return (unsigned)ua | ((unsigned)ub << 16);
}

// async global->LDS, 16B per lane; LDS dest is wave-uniform base + lane*16
__device__ inline void glds16(const bf16* g, short* l) {
    __builtin_amdgcn_global_load_lds(
        (const __attribute__((address_space(1))) unsigned int*)g,
        (__attribute__((address_space(3))) unsigned int*)l,
        16, 0, 0);
}

// ---------------------------------------------------------------- fp32 -> bf16 weight conversion
__global__ __launch_bounds__(256) void f2bf_kernel(const float* __restrict__ in, bf16* __restrict__ out, int n)
{
    int i = blockIdx.x * 256 + threadIdx.x;
    if (i < n) out[i] = __float2bfloat16(in[i]);
}

// pad rows: out[r*K+k] = r<rows_in ? in[r*K+k] : 0   (rows_out x K)
__global__ __launch_bounds__(256) void f2bf_pad_kernel(const float* __restrict__ in, bf16* __restrict__ out,
                                                        int rows_in, int rows_out, int K)
{
    int i = blockIdx.x * 256 + threadIdx.x;
    if (i >= rows_out * K) return;
    int r = i / K;
    out[i] = (r < rows_in) ? __float2bfloat16(in[i]) : __float2bfloat16(0.f);
}

// ---------------------------------------------------------------- embeddings (bf16 out)
__global__ __launch_bounds__(256) void embed_kernel(
    const int* __restrict__ skills, const int* __restrict__ responses,
    const float* __restrict__ embC, const float* __restrict__ embA,
    const float* __restrict__ embT, const float* __restrict__ embF,
    bf16* __restrict__ o_state, bf16* __restrict__ o_st, bf16* __restrict__ o_sf)
{
    int idx = blockIdx.x * 256 + threadIdx.x;      // < NTOK*256
    int n = idx >> 8, j = idx & 255;
    int b = n / TT, t = n % TT;
    int c = skills[b * SEQL + t];
    int r = responses[b * SEQL + t];
    r = (r > -1) ? r : 0;                          // masked_r
    o_state[idx] = __float2bfloat16(embA[r * DMODEL + j] + embC[c * DMODEL + j]);
    o_st[idx]    = __float2bfloat16(embT[(r * (c + NSK)) * DMODEL + j]);
    o_sf[idx]    = __float2bfloat16(embF[(c * (1 - r)) * DMODEL + j]);
}

// ---------------------------------------------------------------- MFMA bf16 GEMM
// C[M,N] = act(A @ W^T + bias); K%32==0, N%128==0. grid = (rowPanels, colPanels).
// T4 pipeline: 3 LDS buffers, depth-2 glds prefetch, counted s_waitcnt vmcnt(4)
// + RAW s_barrier (no vmcnt(0) drain -> newest 4 loads stay in flight across
// the barrier). Loads are unconditional (row clamped) so vmcnt counts are
// wave-uniform. No ds_writes -> no lgkm drain needed at the barrier.
template<int ACT, typename OUTT>   // ACT: 0 none, 1 tanh, 3 gelu-exact
__global__ __launch_bounds__(256) void gemm_mfma(
    const bf16* __restrict__ A, int lda,
    const bf16* __restrict__ W,
    const float* __restrict__ bias,
    OUTT* __restrict__ C, int ldc,
    int M, int N, int K)
{
    __shared__ short As[3][128 * 32];
    __shared__ short Ws[3][128 * 32];
    const int tx = threadIdx.x;
    const int lane = tx & 63;
    const int wv = tx >> 6;
    const int rowBase = blockIdx.x * 128;
    const int colBase = blockIdx.y * 128;
    const int wrb = (wv >> 1) * 64;
    const int wcb = (wv & 1) * 64;

    f32x4 acc[4][4];
    #pragma unroll
    for (int m = 0; m < 4; ++m)
        #pragma unroll
        for (int n = 0; n < 4; ++n)
            acc[m][n] = (f32x4){0.f, 0.f, 0.f, 0.f};

    // staging: wave wv owns 1KB chunks 2wv, 2wv+1; lane i = row i>>2, kslot i&3
    const int srow16 = lane >> 2;
    const int sko    = (lane & 3) * 8;
    const int ca     = wv * 2;
    const int nst = K >> 5;
    const int kq = (lane >> 4) * 8;
    const int rl = lane & 15;

    // per-step stage: 4 glds/lane (2 A-chunks + 2 W-chunks), rows clamped
    #define STAGE(S, BF)                                                        \
        {                                                                       \
            const int k0_ = (S) << 5;                                           \
            _Pragma("unroll")                                                   \
            for (int cc = 0; cc < 2; ++cc) {                                    \
                int c_ = ca + cc;                                               \
                int gr_ = rowBase + c_ * 16 + srow16;                           \
                gr_ = gr_ < M ? gr_ : M - 1;                                    \
                glds16(A + (size_t)gr_ * lda + k0_ + sko, &As[BF][c_ * 512]);   \
                int gc_ = colBase + c_ * 16 + srow16;                           \
                glds16(W + (size_t)gc_ * K + k0_ + sko, &Ws[BF][c_ * 512]);     \
            }                                                                   \
        }

    STAGE(0, 0);
    STAGE(1, 1);                                   // nst >= 8 always here
    asm volatile("s_waitcnt vmcnt(4)" ::: "memory");   // buf0 landed; buf1 in flight
    __builtin_amdgcn_s_barrier();

    int buf = 0;
    for (int s = 0; s < nst; ++s) {
        if (s + 2 < nst) {
            int nb = buf + 2; nb = (nb >= 3) ? nb - 3 : nb;
            STAGE(s + 2, nb);
        }
        short8 af[4], bfr[4];
        #pragma unroll
        for (int m = 0; m < 4; ++m) af[m]  = *(const short8*)&As[buf][(wrb + m * 16 + rl) * 32 + kq];
        #pragma unroll
        for (int n = 0; n < 4; ++n) bfr[n] = *(const short8*)&Ws[buf][(wcb + n * 16 + rl) * 32 + kq];
        #pragma unroll
        for (int m = 0; m < 4; ++m)
            #pragma unroll
            for (int n = 0; n < 4; ++n)
                acc[m][n] = __builtin_amdgcn_mfma_f32_16x16x32_bf16(af[m], bfr[n], acc[m][n], 0, 0, 0);
        // next buffer's loads (issued last step) complete when <=4 remain
        asm volatile("s_waitcnt vmcnt(4)" ::: "memory");
        __builtin_amdgcn_s_barrier();
        buf = (buf + 1 >= 3) ? 0 : buf + 1;
    }
    #undef STAGE

    // epilogue: C/D layout col=lane&15, row=(lane>>4)*4+reg  [m89/m91]
    const int rq = (lane >> 4) * 4;
    const int cl = lane & 15;
    #pragma unroll
    for (int m = 0; m < 4; ++m) {
        #pragma unroll
        for (int i = 0; i < 4; ++i) {
            int row = rowBase + wrb + m * 16 + rq + i;
            if (row >= M) continue;
            #pragma unroll
            for (int n = 0; n < 4; ++n) {
                int col = colBase + wcb + n * 16 + cl;
                float x = acc[m][n][i];
                if (bias) x += bias[col];
                if (ACT == 1) x = tanhf(x);
                else if (ACT == 3) x = 0.5f * x * (1.f + erff(x * 0.70710678118654752440f));
                C[(size_t)row * ldc + col] = OUTT(x);
            }
        }
    }
}

// ---------------------------------------------------------------- small VALU GEMM (dtproj K=16)
template<int ACT>   // 0 none, 2 softplus
__global__ __launch_bounds__(256) void gemm_kernel(
    const float* __restrict__ A, int lda,
    const float* __restrict__ W,
    const float* __restrict__ bias,
    float* __restrict__ C, int ldc,
    int M, int N, int K)
{
    __shared__ float As[64][17];
    __shared__ float Ws[64][17];
    const int tx = threadIdx.x;
    const int rowBase = blockIdx.y * 64;
    const int colBase = blockIdx.x * 64;
    const int lr = tx >> 2;
    const int lk = (tx & 3) << 2;
    const int tr = (tx >> 4) << 2;
    const int tc = (tx & 15) << 2;
    float acc[4][4] = {};

    for (int k0 = 0; k0 < K; k0 += 16) {
        float4 av = make_float4(0.f, 0.f, 0.f, 0.f);
        int ar = rowBase + lr;
        if (ar < M) av = *reinterpret_cast<const float4*>(A + (size_t)ar * lda + k0 + lk);
        As[lr][lk] = av.x; As[lr][lk + 1] = av.y; As[lr][lk + 2] = av.z; As[lr][lk + 3] = av.w;
        float4 wvv = make_float4(0.f, 0.f, 0.f, 0.f);
        int wr = colBase + lr;
        if (wr < N) wvv = *reinterpret_cast<const float4*>(W + (size_t)wr * K + k0 + lk);
        Ws[lr][lk] = wvv.x; Ws[lr][lk + 1] = wvv.y; Ws[lr][lk + 2] = wvv.z; Ws[lr][lk + 3] = wvv.w;
        __syncthreads();
        #pragma unroll
        for (int k = 0; k < 16; ++k) {
            float a0 = As[tr][k], a1 = As[tr + 1][k], a2 = As[tr + 2][k], a3 = As[tr + 3][k];
            float b0 = Ws[tc][k], b1 = Ws[tc + 1][k], b2 = Ws[tc + 2][k], b3 = Ws[tc + 3][k];
            acc[0][0] += a0 * b0; acc[0][1] += a0 * b1; acc[0][2] += a0 * b2; acc[0][3] += a0 * b3;
            acc[1][0] += a1 * b0; acc[1][1] += a1 * b1; acc[1][2] += a1 * b2; acc[1][3] += a1 * b3;
            acc[2][0] += a2 * b0; acc[2][1] += a2 * b1; acc[2][2] += a2 * b2; acc[2][3] += a2 * b3;
            acc[3][0] += a3 * b0; acc[3][1] += a3 * b1; acc[3][2] += a3 * b2; acc[3][3] += a3 * b3;
        }
        __syncthreads();
    }

    #pragma unroll
    for (int i = 0; i < 4; ++i) {
        int r = rowBase + tr + i;
        if (r >= M) break;
        int cb = colBase + tc;
        if (cb >= N) continue;
        float4 v;
        float* vp = &v.x;
        #pragma unroll
        for (int j = 0; j < 4; ++j) {
            float x = acc[i][j];
            if (bias) x += bias[cb + j];
            if (ACT == 2) {   // softplus via native exp2/log2
                float e = __builtin_amdgcn_exp2f(-fabsf(x) * L2E);
                x = fmaxf(x, 0.f) + __builtin_amdgcn_logf(1.f + e) * LN2;
            }
            vp[j] = x;
        }
        *reinterpret_cast<float4*>(C + (size_t)r * ldc + cb) = v;
    }
}

// ---------------------------------------------------------------- conv1d(4, causal, depthwise) + silu (bf16 io)
__global__ __launch_bounds__(256) void conv_silu_kernel(
    const bf16* __restrict__ xz,    // (NTOK,1024), xc part = cols 0..511
    const float* __restrict__ cW,   // (512,4)
    const float* __restrict__ cb,   // (512)
    bf16* __restrict__ xc)          // (NTOK,512)
{
    int idx = blockIdx.x * 256 + threadIdx.x;     // < NTOK*512
    int d = idx & 511;
    int n = idx >> 9;
    int b = n / TT, t = n % TT;
    float w0 = cW[d * 4], w1 = cW[d * 4 + 1], w2 = cW[d * 4 + 2], w3 = cW[d * 4 + 3];
    const bf16* base = xz + (size_t)(b * TT) * 1024 + d;
    float acc = cb[d];
    if (t >= 3) acc += w0 * __bfloat162float(base[(size_t)(t - 3) * 1024]);
    if (t >= 2) acc += w1 * __bfloat162float(base[(size_t)(t - 2) * 1024]);
    if (t >= 1) acc += w2 * __bfloat162float(base[(size_t)(t - 1) * 1024]);
    acc += w3 * __bfloat162float(base[(size_t)t * 1024]);
    xc[idx] = __float2bfloat16(acc / (1.f + fexp(-acc)));   // silu
}

// ---------------------------------------------------------------- chunk-parallel selective scan (no shuffles)
__global__ __launch_bounds__(256) void scan_kernel(
    const float* __restrict__ dt,     // (NTOK,512)
    const bf16* __restrict__ xc,      // (NTOK,512)
    const float* __restrict__ xdbl,   // (NTOK,128): [dtr(16) | B(16) | C(16) | pad]
    const bf16* __restrict__ xz,      // (NTOK,1024): z = cols 512..1023
    const float* __restrict__ Alog,   // (512,16)
    const float* __restrict__ Dpv,    // (512)
    bf16* __restrict__ ym)            // (NTOK,512)
{
    __shared__ float smry[256][33];   // [chunk*16+dl][P(16) | h(16)], pad 33

    const int tx = threadIdx.x;
    const int dl = tx & 15;
    const int c  = tx >> 4;           // chunk 0..15
    const int b  = blockIdx.x >> 5;
    const int d  = ((blockIdx.x & 31) << 4) + dl;

    float A2[16];
    {
        const float* Ap = Alog + d * 16;
        #pragma unroll
        for (int s = 0; s < 16; ++s) A2[s] = -expf(Ap[s]) * L2E;   // pre-scaled by log2e
    }
    const float Dv = Dpv[d];
    const size_t nb = (size_t)b * TT;
    const int t0 = c * 32;
    const int t1 = (t0 + 32 < TT) ? (t0 + 32) : TT;

    float h[16];
    float sdt = 0.f;
    #pragma unroll
    for (int s = 0; s < 16; ++s) h[s] = 0.f;

    // pass 1: local scan (h from 0) + dt sum
    for (int t = t0; t < t1; ++t) {
        const size_t n = nb + t;
        const float dtt = dt[n * 512 + d];
        const float xt  = __bfloat162float(xc[n * 512 + d]);
        const float dx  = dtt * xt;
        sdt += dtt;
        const float* Bp = xdbl + n * 128 + 16;
        const float4 b0 = *(const float4*)(Bp);
        const float4 b1 = *(const float4*)(Bp + 4);
        const float4 b2 = *(const float4*)(Bp + 8);
        const float4 b3 = *(const float4*)(Bp + 12);
        const float Bv[16] = {b0.x,b0.y,b0.z,b0.w, b1.x,b1.y,b1.z,b1.w,
                              b2.x,b2.y,b2.z,b2.w, b3.x,b3.y,b3.z,b3.w};
        #pragma unroll
        for (int s = 0; s < 16; ++s) {
            const float e = __builtin_amdgcn_exp2f(dtt * A2[s]);
            h[s] = e * h[s] + dx * Bv[s];
        }
    }
    #pragma unroll
    for (int s = 0; s < 16; ++s) {
        smry[tx][s]      = __builtin_amdgcn_exp2f(A2[s] * sdt);   // chunk decay product
        smry[tx][16 + s] = h[s];
    }
    __syncthreads();

    // prefix combine (oldest chunk first): h_init for this chunk
    #pragma unroll
    for (int s = 0; s < 16; ++s) h[s] = 0.f;
    for (int cc = 0; cc < c; ++cc) {
        const float* S = smry[(cc << 4) + dl];
        #pragma unroll
        for (int s = 0; s < 16; ++s) h[s] = S[s] * h[s] + S[16 + s];
    }

    // pass 2: rescan from h_init, emit ym
    for (int t = t0; t < t1; ++t) {
        const size_t n = nb + t;
        const float dtt = dt[n * 512 + d];
        const float xt  = __bfloat162float(xc[n * 512 + d]);
        const float dx  = dtt * xt;
        const float* Bp = xdbl + n * 128 + 16;
        const float4 b0 = *(const float4*)(Bp);
        const float4 b1 = *(const float4*)(Bp + 4);
        const float4 b2 = *(const float4*)(Bp + 8);
        const float4 b3 = *(const float4*)(Bp + 12);
        const float4 c0 = *(const float4*)(Bp + 16);
        const float4 c1 = *(const float4*)(Bp + 20);
        const float4 c2 = *(const float4*)(Bp + 24);
        const float4 c3 = *(const float4*)(Bp + 28);
        const float Bv[16] = {b0.x,b0.y,b0.z,b0.w, b1.x,b1.y,b1.z,b1.w,
                              b2.x,b2.y,b2.z,b2.w, b3.x,b3.y,b3.z,b3.w};
        const float Cv[16] = {c0.x,c0.y,c0.z,c0.w, c1.x,c1.y,c1.z,c1.w,
                              c2.x,c2.y,c2.z,c2.w, c3.x,c3.y,c3.z,c3.w};
        float y = 0.f;
        #pragma unroll
        for (int s = 0; s < 16; ++s) {
            const float e = __builtin_amdgcn_exp2f(dtt * A2[s]);
            h[s] = e * h[s] + dx * Bv[s];
            y += h[s] * Cv[s];
        }
        const float zz = __bfloat162float(xz[n * 1024 + 512 + d]);
        const float v = (y + xt * Dv) * (zz / (1.f + fexp(-zz)));
        ym[n * 512 + d] = __float2bfloat16(v);
    }
}

// ---------------------------------------------------------------- rmsnorm(a+b)*w  (bf16 io, fp32 math)
__global__ __launch_bounds__(256) void rmsnorm_kernel(
    const bf16* __restrict__ a, const bf16* __restrict__ b,
    const float* __restrict__ w, bf16* __restrict__ out,
    bf16* __restrict__ out768)
{
    __shared__ float red[256];
    int n = blockIdx.x, j = threadIdx.x;
    float v = __bfloat162float(a[(size_t)n * 256 + j]) + __bfloat162float(b[(size_t)n * 256 + j]);
    red[j] = v * v;
    __syncthreads();
    for (int s = 128; s > 0; s >>= 1) { if (j < s) red[j] += red[j + s]; __syncthreads(); }
    float scale = rsqrtf(red[0] / 256.0f + 1e-12f);
    bf16 r = __float2bfloat16(v * scale * w[j]);
    out[(size_t)n * 256 + j] = r;
    if (out768) out768[(size_t)n * 768 + j] = r;
}

// ---------------------------------------------------------------- MFMA dual flash attention
__global__ __launch_bounds__(256) void attn_kernel(
    const bf16* __restrict__ y,    // (B,TT,256) q = k
    const bf16* __restrict__ st,   // v1
    const bf16* __restrict__ sf,   // v2
    bf16* __restrict__ ycin)       // (B,TT,768), writes cols 256..767
{
    __shared__ short Ks[64 * 40];      // K[key][d], row stride 40 shorts (80B)
    __shared__ short Vt[2][32 * 88];   // V^T[d][key], row stride 88 shorts (176B)
    __shared__ short Pl[64 * 88];      // P[q][key] bf16, row stride 88 shorts

    const int bid = blockIdx.x;        // ((b*8)+h)*8 + qt
    const int qt = bid & 7;
    const int h  = (bid >> 3) & 7;
    const int b  = bid >> 6;
    const int tx = threadIdx.x;
    const int w  = tx >> 6;            // wave 0..3
    const int lane = tx & 63;
    const int g  = lane >> 4;          // 0..3
    const int l15 = lane & 15;
    const int q0 = qt * 64;
    const int qg = q0 + w * 16 + l15;  // this lane's q row (S^T col)
    const float scale = 0.17677669529663687f;   // 1/sqrt(32)

    const bf16* ybase  = y  + (size_t)(b * TT) * 256 + h * 32;
    const bf16* v1base = st + (size_t)(b * TT) * 256 + h * 32;
    const bf16* v2base = sf + (size_t)(b * TT) * 256 + h * 32;

    // Q fragment (B operand): col=q=lane&15, k-slice d=(lane>>4)*8..+7
    short8 qf = {};
    if (qg < TT) qf = *(const short8*)(ybase + (size_t)qg * 256 + g * 8);

    float m = -INFINITY, l = 0.f;
    f32x4 o[2][2];                     // [v][dsub]
    #pragma unroll
    for (int v = 0; v < 2; ++v) { o[v][0] = (f32x4){0,0,0,0}; o[v][1] = (f32x4){0,0,0,0}; }

    const int sr = tx >> 2;            // staging key row 0..63
    const int sc = (tx & 3) * 8;       // staging d base

    const int nkt = (qt == 0) ? 8 : (qt + 1);
    for (int kt = 0; kt < nkt; ++kt) {
        const int k0 = kt * 64;
        __syncthreads();               // previous tile's LDS reads done
        {
            int kgr = k0 + sr;
            short8 kv = {}, v1v = {}, v2v = {};
            if (kgr < TT) {
                kv  = *(const short8*)(ybase  + (size_t)kgr * 256 + sc);
                v1v = *(const short8*)(v1base + (size_t)kgr * 256 + sc);
                v2v = *(const short8*)(v2base + (size_t)kgr * 256 + sc);
            }
            *(short8*)&Ks[sr * 40 + sc] = kv;
            #pragma unroll
            for (int i = 0; i < 8; ++i) {
                Vt[0][(sc + i) * 88 + sr] = v1v[i];
                Vt[1][(sc + i) * 88 + sr] = v2v[i];
            }
        }
        __syncthreads();

        // S^T[key][q]: 4 mfmas, each 16 keys x 16 q, K=32 (full head dim)
        f32x4 s[4];
        #pragma unroll
        for (int jm = 0; jm < 4; ++jm) {
            short8 kf = *(const short8*)&Ks[(jm * 16 + l15) * 40 + g * 8];
            s[jm] = __builtin_amdgcn_mfma_f32_16x16x32_bf16(kf, qf, (f32x4){0,0,0,0}, 0, 0, 0);
        }
        // mask + tile max (per lane: all 16 values are q=qg)
        float tm = -INFINITY;
        #pragma unroll
        for (int jm = 0; jm < 4; ++jm)
            #pragma unroll
            for (int r = 0; r < 4; ++r) {
                int kk = k0 + jm * 16 + g * 4 + r;
                float sv = s[jm][r];
                sv = (kk < qg) ? sv * scale : ((kk < TT) ? -1e9f : -INFINITY);
                s[jm][r] = sv;
                tm = fmaxf(tm, sv);
            }
        tm = fmaxf(tm, __shfl_xor(tm, 16));
        tm = fmaxf(tm, __shfl_xor(tm, 32));
        float mn = fmaxf(m, tm);
        float rs = fexp(m - mn);       // m==-inf -> 0
        m = mn;
        float ts = 0.f;
        #pragma unroll
        for (int jm = 0; jm < 4; ++jm)
            #pragma unroll
            for (int r = 0; r < 4; ++r) {
                float e = fexp(s[jm][r] - mn);
                s[jm][r] = e;
                ts += e;
            }
        ts += __shfl_xor(ts, 16);
        ts += __shfl_xor(ts, 32);
        l = l * rs + ts;
        // P -> LDS as bf16 (u32 pair writes; row q, key 16*jm+4*g+{0..3})
        #pragma unroll
        for (int jm = 0; jm < 4; ++jm) {
            *(unsigned*)&Pl[(w * 16 + l15) * 88 + jm * 16 + g * 4]     = pack_bf2(s[jm][0], s[jm][1]);
            *(unsigned*)&Pl[(w * 16 + l15) * 88 + jm * 16 + g * 4 + 2] = pack_bf2(s[jm][2], s[jm][3]);
        }
        // rescale O accs: O row = 4*g+reg -> factor lives in lane (q row)
        float rq[4];
        #pragma unroll
        for (int r = 0; r < 4; ++r) rq[r] = __shfl(rs, 4 * g + r);
        #pragma unroll
        for (int v = 0; v < 2; ++v)
            #pragma unroll
            for (int d = 0; d < 2; ++d)
                #pragma unroll
                for (int r = 0; r < 4; ++r)
                    o[v][d][r] *= rq[r];
        // PV: A = P (row=q=lane&15, k=keys), B = Vt (col=d=lane&15, k=keys)
        #pragma unroll
        for (int ks = 0; ks < 2; ++ks) {
            short8 pf = *(const short8*)&Pl[(w * 16 + l15) * 88 + ks * 32 + g * 8];
            #pragma unroll
            for (int v = 0; v < 2; ++v)
                #pragma unroll
                for (int d = 0; d < 2; ++d) {
                    short8 vf = *(const short8*)&Vt[v][(d * 16 + l15) * 88 + ks * 32 + g * 8];
                    o[v][d] = __builtin_amdgcn_mfma_f32_16x16x32_bf16(pf, vf, o[v][d], 0, 0, 0);
                }
        }
    }

    // epilogue: O row = q0+w*16+4*g+r, col d = lane&15
    float invl = 1.0f / l;             // per q = lane&15
    float iq[4];
    #pragma unroll
    for (int r = 0; r < 4; ++r) iq[r] = __shfl(invl, 4 * g + r);
    #pragma unroll
    for (int r = 0; r < 4; ++r) {
        int rowq = q0 + w * 16 + 4 * g + r;
        if (rowq >= TT) continue;
        bf16* dst = ycin + (size_t)(b * TT + rowq) * 768 + 256;
        #pragma unroll
        for (int v = 0; v < 2; ++v)
            #pragma unroll
            for (int d = 0; d < 2; ++d)
                dst[v * 256 + h * 32 + d * 16 + l15] = __float2bfloat16(o[v][d][r] * iq[r]);
    }
}

// ---------------------------------------------------------------- gathered logit + sigmoid
__global__ __launch_bounds__(256) void pred_kernel(
    const float* __restrict__ yc,     // (NTOK,256)
    const int* __restrict__ skills,
    const float* __restrict__ outW,   // (500,256)
    const float* __restrict__ outB,   // (500)
    float* __restrict__ out)          // (NTOK)
{
    int n = blockIdx.x * 4 + (threadIdx.x >> 6);
    if (n >= NTOK) return;
    int lane = threadIdx.x & 63;
    int b = n / TT, t = n % TT;
    int c = skills[b * SEQL + t + 1];            // cshft
    const float* wrow = outW + (size_t)c * 256;
    const float* xrow = yc + (size_t)n * 256;
    float s = 0.f;
    for (int j = lane; j < 256; j += 64) s += xrow[j] * wrow[j];
    #pragma unroll
    for (int off = 32; off > 0; off >>= 1) s += __shfl_down(s, off);
    if (lane == 0) out[n] = 1.0f / (1.0f + fexp(-(s + outB[c])));
}

// ---------------------------------------------------------------- host
static inline void gemmb(const bf16* A, int lda, const bf16* W, const float* bias,
                         bf16* C, int ldc, int M, int N, int K, int act, hipStream_t s)
{
    dim3 g((M + 127) / 128, N / 128), b(256);   // grid: (rowPanels, colPanels) for XCD L2 locality
    switch (act) {
        case 0: gemm_mfma<0, bf16><<<g, b, 0, s>>>(A, lda, W, bias, C, ldc, M, N, K); break;
        case 1: gemm_mfma<1, bf16><<<g, b, 0, s>>>(A, lda, W, bias, C, ldc, M, N, K); break;
        case 3: gemm_mfma<3, bf16><<<g, b, 0, s>>>(A, lda, W, bias, C, ldc, M, N, K); break;
    }
}

extern "C" void kernel_launch(void* const* d_in, const int* in_sizes, int n_in,
                              void* d_out, int out_size, void* d_ws, size_t ws_size,
                              hipStream_t stream)
{
    const int*   skills    = (const int*)d_in[0];
    const int*   responses = (const int*)d_in[2];
    const float* embC  = (const float*)d_in[3];
    const float* embA  = (const float*)d_in[4];
    const float* embT  = (const float*)d_in[5];
    const float* embF  = (const float*)d_in[6];
    const float* mlpW1 = (const float*)d_in[9];
    const float* mlpb1 = (const float*)d_in[10];
    const float* mlpW2 = (const float*)d_in[11];
    const float* mlpb2 = (const float*)d_in[12];
    const float* inW   = (const float*)d_in[13];
    const float* convW = (const float*)d_in[14];
    const float* convb = (const float*)d_in[15];
    const float* xpW   = (const float*)d_in[16];
    const float* dtW   = (const float*)d_in[17];
    const float* dtb   = (const float*)d_in[18];
    const float* Alog  = (const float*)d_in[19];
    const float* Dp    = (const float*)d_in[20];
    const float* opW   = (const float*)d_in[21];
    const float* mnw   = (const float*)d_in[22];
    const float* fW1   = (const float*)d_in[23];
    const float* fb1   = (const float*)d_in[24];
    const float* fW2   = (const float*)d_in[25];
    const float* fb2   = (const float*)d_in[26];
    const float* fnw   = (const float*)d_in[27];
    const float* finW  = (const float*)d_in[28];
    const float* finb  = (const float*)d_in[29];
    const float* outW  = (const float*)d_in[30];
    const float* outb  = (const float*)d_in[31];

    const size_t NT = NTOK;
    // fp32 region
    float* t1   = (float*)d_ws;          // NT*256 (final gemm out)
    float* dt   = t1 + NT * 256;         // NT*512
    float* xdbl = dt + NT * 512;         // NT*128 (xproj out, padded N=128)
    // bf16 region
    bf16* y    = (bf16*)(xdbl + NT * 128);
    bf16* st   = y    + NT * 256;        // y,st,sf contiguous -> batched MLP
    bf16* sf   = st   + NT * 256;
    bf16* h1   = sf   + NT * 256;
    bf16* thid3 = h1  + NT * 256;        // 3*NT*256: mlp hidden (batched) / per-layer temp
    bf16* bufA = thid3 + 3 * NT * 256;   // NT*1024: xz / ffnmid / ycin(768)
    bf16* xc   = bufA + NT * 1024;       // NT*512
    bf16* ym   = xc   + NT * 512;        // NT*512
    // bf16 weights
    bf16* wMlp1 = ym    + NT * 512;      // 65536
    bf16* wMlp2 = wMlp1 + 65536;         // 65536
    bf16* wIn   = wMlp2 + 65536;         // 2*262144
    bf16* wOp   = wIn   + 2 * 262144;    // 2*131072
    bf16* wF1   = wOp   + 2 * 131072;    // 2*262144
    bf16* wF2   = wF1   + 2 * 262144;    // 2*262144
    bf16* wFin  = wF2   + 2 * 262144;    // 196608
    bf16* wXp   = wFin  + 196608;        // 2*65536 (xproj padded 48->128 rows)

    // 0) weight conversions
    f2bf_kernel<<<(65536 + 255) / 256, 256, 0, stream>>>(mlpW1, wMlp1, 65536);
    f2bf_kernel<<<(65536 + 255) / 256, 256, 0, stream>>>(mlpW2, wMlp2, 65536);
    f2bf_kernel<<<(524288 + 255) / 256, 256, 0, stream>>>(inW, wIn, 524288);
    f2bf_kernel<<<(262144 + 255) / 256, 256, 0, stream>>>(opW, wOp, 262144);
    f2bf_kernel<<<(524288 + 255) / 256, 256, 0, stream>>>(fW1, wF1, 524288);
    f2bf_kernel<<<(524288 + 255) / 256, 256, 0, stream>>>(fW2, wF2, 524288);
    f2bf_kernel<<<(196608 + 255) / 256, 256, 0, stream>>>(finW, wFin, 196608);
    f2bf_pad_kernel<<<(65536 + 255) / 256, 256, 0, stream>>>(xpW, wXp, 48, 128, 512);
    f2bf_pad_kernel<<<(65536 + 255) / 256, 256, 0, stream>>>(xpW + 48 * 512, wXp + 65536, 48, 128, 512);

    // 1) embeddings
    embed_kernel<<<NTOK, 256, 0, stream>>>(skills, responses, embC, embA, embT, embF, y, st, sf);

    // 2) three MLPs batched: y,st,sf contiguous -> M = 3*NTOK
    gemmb(y, 256, wMlp1, mlpb1, thid3, 256, 3 * NTOK, 256, 256, 1, stream);
    gemmb(thid3, 256, wMlp2, mlpb2, y, 256, 3 * NTOK, 256, 256, 0, stream);

    // 3) two mamba layers
    for (int i = 0; i < 2; ++i) {
        gemmb(y, 256, wIn + (size_t)i * 262144, nullptr, bufA, 1024, NTOK, 1024, 256, 0, stream);
        conv_silu_kernel<<<(NTOK * 512) / 256, 256, 0, stream>>>(bufA, convW + i * 2048, convb + i * 512, xc);
        {   // xproj: MFMA, N padded to 128 (rows 48..127 zero), out fp32 stride 128
            dim3 g((NTOK + 127) / 128, 1);
            gemm_mfma<0, float><<<g, 256, 0, stream>>>(xc, 512, wXp + (size_t)i * 65536, nullptr, xdbl, 128, NTOK, 128, 512);
        }
        {   // dtproj: K=16, VALU path, fp32 A (lda=128), softplus
            dim3 g((512 + 63) / 64, (NTOK + 63) / 64);
            gemm_kernel<2><<<g, 256, 0, stream>>>(xdbl, 128, dtW + (size_t)i * 512 * 16, dtb + i * 512, dt, 512, NTOK, 512, 16);
        }
        scan_kernel<<<BATCH * 32, 256, 0, stream>>>(dt, xc, xdbl, bufA, Alog + i * 8192, Dp + i * 512, ym);
        gemmb(ym, 512, wOp + (size_t)i * 131072, nullptr, thid3, 256, NTOK, 256, 512, 0, stream);
        rmsnorm_kernel<<<NTOK, 256, 0, stream>>>(thid3, y, mnw + i * 256, h1, nullptr);
        gemmb(h1, 256, wF1 + (size_t)i * 262144, fb1 + i * 1024, bufA, 1024, NTOK, 1024, 256, 3, stream);
        gemmb(bufA, 1024, wF2 + (size_t)i * 262144, fb2 + i * 256, thid3, 256, NTOK, 256, 1024, 0, stream);
        // final layer's rmsnorm also writes ycin cols 0..255 (replaces copy kernel)
        rmsnorm_kernel<<<NTOK, 256, 0, stream>>>(thid3, h1, fnw + i * 256, y, (i == 1) ? bufA : nullptr);
    }

    // 4) dual attention into ycin = bufA (stride 768)
    attn_kernel<<<BATCH * 8 * 8, 256, 0, stream>>>(y, st, sf, bufA);

    // 5) final projection + gathered sigmoid
    {
        dim3 g((NTOK + 127) / 128, 2);
        gemm_mfma<0, float><<<g, 256, 0, stream>>>(bufA, 768, wFin, finb, t1, 256, NTOK, 256, 768);
    }
    pred_kernel<<<NTOK / 4, 256, 0, stream>>>(t1, skills, outW, outb, (float*)d_out);
}

// Round 11
// 685.756 us; speedup vs baseline: 8.3249x; 1.0877x over previous
//
#include <hip/hip_runtime.h>
#include <hip/hip_bf16.h>
#include <math.h>
#include <string.h>

#define BATCH 32
#define SEQL  512
#define TT    511          // T = L-1
#define DMODEL 256
#define DIN   512          // DI = EXP*D
#define DSN   16           // DS
#define NSK   500
#define NTOK  (BATCH*TT)   // 16352

typedef __hip_bfloat16 bf16;
typedef __attribute__((ext_vector_type(8))) short short8;
typedef __attribute__((ext_vector_type(4))) float f32x4;

#define L2E 1.4426950408889634f
#define LN2 0.6931471805599453f

__device__ inline float fexp(float x) { return __builtin_amdgcn_exp2f(x * L2E); }

__device__ inline unsigned pack_bf2(float a, float b) {
    bf16 ba = __float2bfloat16(a), bb = __float2bfloat16(b);
    unsigned short ua, ub; memcpy(&ua, &ba, 2); memcpy(&ub, &bb, 2);
    return (unsigned)ua | ((unsigned)ub << 16);
}

__device__ inline short bf16s(float x) {
    bf16 b = __float2bfloat16(x);
    short s; memcpy(&s, &b, 2); return s;
}

// async global->LDS, 16B per lane; LDS dest is wave-uniform base + lane*16
__device__ inline void glds16(const bf16* g, short* l) {
    __builtin_amdgcn_global_load_lds(
        (const __attribute__((address_space(1))) unsigned int*)g,
        (__attribute__((address_space(3))) unsigned int*)l,
        16, 0, 0);
}

// ---------------------------------------------------------------- fp32 -> bf16 weight conversion
__global__ __launch_bounds__(256) void f2bf_kernel(const float* __restrict__ in, bf16* __restrict__ out, int n)
{
    int i = blockIdx.x * 256 + threadIdx.x;
    if (i < n) out[i] = __float2bfloat16(in[i]);
}

// pad rows: out[r*K+k] = r<rows_in ? in[r*K+k] : 0   (rows_out x K)
__global__ __launch_bounds__(256) void f2bf_pad_kernel(const float* __restrict__ in, bf16* __restrict__ out,
                                                        int rows_in, int rows_out, int K)
{
    int i = blockIdx.x * 256 + threadIdx.x;
    if (i >= rows_out * K) return;
    int r = i / K;
    out[i] = (r < rows_in) ? __float2bfloat16(in[i]) : __float2bfloat16(0.f);
}

// ---------------------------------------------------------------- embeddings (bf16 out)
__global__ __launch_bounds__(256) void embed_kernel(
    const int* __restrict__ skills, const int* __restrict__ responses,
    const float* __restrict__ embC, const float* __restrict__ embA,
    const float* __restrict__ embT, const float* __restrict__ embF,
    bf16* __restrict__ o_state, bf16* __restrict__ o_st, bf16* __restrict__ o_sf)
{
    int idx = blockIdx.x * 256 + threadIdx.x;      // < NTOK*256
    int n = idx >> 8, j = idx & 255;
    int b = n / TT, t = n % TT;
    int c = skills[b * SEQL + t];
    int r = responses[b * SEQL + t];
    r = (r > -1) ? r : 0;                          // masked_r
    o_state[idx] = __float2bfloat16(embA[r * DMODEL + j] + embC[c * DMODEL + j]);
    o_st[idx]    = __float2bfloat16(embT[(r * (c + NSK)) * DMODEL + j]);
    o_sf[idx]    = __float2bfloat16(embF[(c * (1 - r)) * DMODEL + j]);
}

// ---------------------------------------------------------------- MFMA bf16 GEMM
// C[M,N] = act(A @ W^T + bias); K%32==0, N%128==0. grid = (rowPanels, colPanels).
// Staging: glds 16B/lane, 3 LDS buffers, depth-2 prefetch, counted vmcnt.
// TAIL FIX (r10 bug): at end of step s, wait vmcnt(4) only if a STAGE was
// issued this step; else vmcnt(0). Guarantees (a) tile s+1's loads landed
// before any wave reads them, (b) ZERO in-flight glds at epilogue time --
// the C-bounce epilogue reuses the staging LDS, and an async load landing
// after the bounce write corrupts outputs (round 10's 2.3e-2 failure).
template<int ACT, typename OUTT>   // ACT: 0 none, 1 tanh, 3 gelu-exact
__global__ __launch_bounds__(256) void gemm_mfma(
    const bf16* __restrict__ A, int lda,
    const bf16* __restrict__ W,
    const float* __restrict__ bias,
    OUTT* __restrict__ C, int ldc,
    int M, int N, int K)
{
    __shared__ short SM[24576];        // 48KB: As bufs @0..12287, Ws @12288..24575; C-bounce aliases all
    const int tx = threadIdx.x;
    const int lane = tx & 63;
    const int wv = tx >> 6;
    const int rowBase = blockIdx.x * 128;
    const int colBase = blockIdx.y * 128;
    const int wrb = (wv >> 1) * 64;
    const int wcb = (wv & 1) * 64;

    f32x4 acc[4][4];
    #pragma unroll
    for (int m = 0; m < 4; ++m)
        #pragma unroll
        for (int n = 0; n < 4; ++n)
            acc[m][n] = (f32x4){0.f, 0.f, 0.f, 0.f};

    // staging: wave wv owns 1KB chunks 2wv, 2wv+1; lane i = row i>>2, kslot i&3
    const int srow16 = lane >> 2;
    const int sko    = (lane & 3) * 8;
    const int ca     = wv * 2;
    const int nst = K >> 5;
    const int kq = (lane >> 4) * 8;
    const int rl = lane & 15;

    #define STAGE(S, BF)                                                             \
        {                                                                            \
            const int k0_ = (S) << 5;                                                \
            _Pragma("unroll")                                                        \
            for (int cc = 0; cc < 2; ++cc) {                                         \
                int c_ = ca + cc;                                                    \
                int gr_ = rowBase + c_ * 16 + srow16;                                \
                gr_ = gr_ < M ? gr_ : M - 1;                                         \
                glds16(A + (size_t)gr_ * lda + k0_ + sko, &SM[(BF) * 4096 + c_ * 512]); \
                int gc_ = colBase + c_ * 16 + srow16;                                \
                glds16(W + (size_t)gc_ * K + k0_ + sko, &SM[12288 + (BF) * 4096 + c_ * 512]); \
            }                                                                        \
        }

    STAGE(0, 0);
    STAGE(1, 1);                                   // nst >= 4 always here
    asm volatile("s_waitcnt vmcnt(4)" ::: "memory");   // buf0 landed; buf1 in flight
    __builtin_amdgcn_s_barrier();

    int buf = 0;
    for (int s = 0; s < nst; ++s) {
        const bool staged = (s + 2 < nst);
        if (staged) {
            int nb = buf + 2; nb = (nb >= 3) ? nb - 3 : nb;
            STAGE(s + 2, nb);
        }
        short8 af[4], bfr[4];
        #pragma unroll
        for (int m = 0; m < 4; ++m) af[m]  = *(const short8*)&SM[buf * 4096 + (wrb + m * 16 + rl) * 32 + kq];
        #pragma unroll
        for (int n = 0; n < 4; ++n) bfr[n] = *(const short8*)&SM[12288 + buf * 4096 + (wcb + n * 16 + rl) * 32 + kq];
        #pragma unroll
        for (int m = 0; m < 4; ++m)
            #pragma unroll
            for (int n = 0; n < 4; ++n)
                acc[m][n] = __builtin_amdgcn_mfma_f32_16x16x32_bf16(af[m], bfr[n], acc[m][n], 0, 0, 0);
        // newer-than-needed loads = 4 if we staged this step, else 0 (tail)
        if (staged) asm volatile("s_waitcnt vmcnt(4)" ::: "memory");
        else        asm volatile("s_waitcnt vmcnt(0)" ::: "memory");
        __builtin_amdgcn_s_barrier();
        buf = (buf + 1 >= 3) ? 0 : buf + 1;
    }
    #undef STAGE

    // epilogue: C/D layout col=lane&15, row=(lane>>4)*4+reg  [m89/m91]
    const int rq = (lane >> 4) * 4;
    const int cl = lane & 15;
    if constexpr (sizeof(OUTT) == 2) {
        // bf16: bounce through LDS, then coalesced short8 stores
        #pragma unroll
        for (int m = 0; m < 4; ++m)
            #pragma unroll
            for (int i = 0; i < 4; ++i) {
                int row = wrb + m * 16 + rq + i;
                #pragma unroll
                for (int n = 0; n < 4; ++n) {
                    int col = wcb + n * 16 + cl;
                    float x = acc[m][n][i];
                    if (bias) x += bias[colBase + col];
                    if (ACT == 1) x = tanhf(x);
                    else if (ACT == 3) x = 0.5f * x * (1.f + erff(x * 0.70710678118654752440f));
                    SM[row * 132 + col] = bf16s(x);
                }
            }
        __syncthreads();
        const int r0 = tx >> 4;
        const int c0 = (tx & 15) * 8;
        #pragma unroll
        for (int it = 0; it < 8; ++it) {
            int row = r0 + it * 16;
            int grow = rowBase + row;
            if (grow < M) {
                short8 v = *(const short8*)&SM[row * 132 + c0];
                *(short8*)((short*)C + (size_t)grow * ldc + colBase + c0) = v;
            }
        }
    } else {
        #pragma unroll
        for (int m = 0; m < 4; ++m) {
            #pragma unroll
            for (int i = 0; i < 4; ++i) {
                int row = rowBase + wrb + m * 16 + rq + i;
                if (row >= M) continue;
                #pragma unroll
                for (int n = 0; n < 4; ++n) {
                    int col = colBase + wcb + n * 16 + cl;
                    float x = acc[m][n][i];
                    if (bias) x += bias[col];
                    if (ACT == 1) x = tanhf(x);
                    else if (ACT == 3) x = 0.5f * x * (1.f + erff(x * 0.70710678118654752440f));
                    C[(size_t)row * ldc + col] = OUTT(x);
                }
            }
        }
    }
}

// ---------------------------------------------------------------- small VALU GEMM (dtproj K=16)
template<int ACT>   // 0 none, 2 softplus
__global__ __launch_bounds__(256) void gemm_kernel(
    const float* __restrict__ A, int lda,
    const float* __restrict__ W,
    const float* __restrict__ bias,
    float* __restrict__ C, int ldc,
    int M, int N, int K)
{
    __shared__ float As[64][17];
    __shared__ float Ws[64][17];
    const int tx = threadIdx.x;
    const int rowBase = blockIdx.y * 64;
    const int colBase = blockIdx.x * 64;
    const int lr = tx >> 2;
    const int lk = (tx & 3) << 2;
    const int tr = (tx >> 4) << 2;
    const int tc = (tx & 15) << 2;
    float acc[4][4] = {};

    for (int k0 = 0; k0 < K; k0 += 16) {
        float4 av = make_float4(0.f, 0.f, 0.f, 0.f);
        int ar = rowBase + lr;
        if (ar < M) av = *reinterpret_cast<const float4*>(A + (size_t)ar * lda + k0 + lk);
        As[lr][lk] = av.x; As[lr][lk + 1] = av.y; As[lr][lk + 2] = av.z; As[lr][lk + 3] = av.w;
        float4 wvv = make_float4(0.f, 0.f, 0.f, 0.f);
        int wr = colBase + lr;
        if (wr < N) wvv = *reinterpret_cast<const float4*>(W + (size_t)wr * K + k0 + lk);
        Ws[lr][lk] = wvv.x; Ws[lr][lk + 1] = wvv.y; Ws[lr][lk + 2] = wvv.z; Ws[lr][lk + 3] = wvv.w;
        __syncthreads();
        #pragma unroll
        for (int k = 0; k < 16; ++k) {
            float a0 = As[tr][k], a1 = As[tr + 1][k], a2 = As[tr + 2][k], a3 = As[tr + 3][k];
            float b0 = Ws[tc][k], b1 = Ws[tc + 1][k], b2 = Ws[tc + 2][k], b3 = Ws[tc + 3][k];
            acc[0][0] += a0 * b0; acc[0][1] += a0 * b1; acc[0][2] += a0 * b2; acc[0][3] += a0 * b3;
            acc[1][0] += a1 * b0; acc[1][1] += a1 * b1; acc[1][2] += a1 * b2; acc[1][3] += a1 * b3;
            acc[2][0] += a2 * b0; acc[2][1] += a2 * b1; acc[2][2] += a2 * b2; acc[2][3] += a2 * b3;
            acc[3][0] += a3 * b0; acc[3][1] += a3 * b1; acc[3][2] += a3 * b2; acc[3][3] += a3 * b3;
        }
        __syncthreads();
    }

    #pragma unroll
    for (int i = 0; i < 4; ++i) {
        int r = rowBase + tr + i;
        if (r >= M) break;
        int cb = colBase + tc;
        if (cb >= N) continue;
        float4 v;
        float* vp = &v.x;
        #pragma unroll
        for (int j = 0; j < 4; ++j) {
            float x = acc[i][j];
            if (bias) x += bias[cb + j];
            if (ACT == 2) {   // softplus via native exp2/log2
                float e = __builtin_amdgcn_exp2f(-fabsf(x) * L2E);
                x = fmaxf(x, 0.f) + __builtin_amdgcn_logf(1.f + e) * LN2;
            }
            vp[j] = x;
        }
        *reinterpret_cast<float4*>(C + (size_t)r * ldc + cb) = v;
    }
}

// ---------------------------------------------------------------- conv1d(4, causal, depthwise) + silu (bf16 io)
__global__ __launch_bounds__(256) void conv_silu_kernel(
    const bf16* __restrict__ xz,    // (NTOK,1024), xc part = cols 0..511
    const float* __restrict__ cW,   // (512,4)
    const float* __restrict__ cb,   // (512)
    bf16* __restrict__ xc)          // (NTOK,512)
{
    int idx = blockIdx.x * 256 + threadIdx.x;     // < NTOK*512
    int d = idx & 511;
    int n = idx >> 9;
    int b = n / TT, t = n % TT;
    float w0 = cW[d * 4], w1 = cW[d * 4 + 1], w2 = cW[d * 4 + 2], w3 = cW[d * 4 + 3];
    const bf16* base = xz + (size_t)(b * TT) * 1024 + d;
    float acc = cb[d];
    if (t >= 3) acc += w0 * __bfloat162float(base[(size_t)(t - 3) * 1024]);
    if (t >= 2) acc += w1 * __bfloat162float(base[(size_t)(t - 2) * 1024]);
    if (t >= 1) acc += w2 * __bfloat162float(base[(size_t)(t - 1) * 1024]);
    acc += w3 * __bfloat162float(base[(size_t)t * 1024]);
    xc[idx] = __float2bfloat16(acc / (1.f + fexp(-acc)));   // silu
}

// ---------------------------------------------------------------- chunk-parallel selective scan (no shuffles)
__global__ __launch_bounds__(256) void scan_kernel(
    const float* __restrict__ dt,     // (NTOK,512)
    const bf16* __restrict__ xc,      // (NTOK,512)
    const float* __restrict__ xdbl,   // (NTOK,128): [dtr(16) | B(16) | C(16) | pad]
    const bf16* __restrict__ xz,      // (NTOK,1024): z = cols 512..1023
    const float* __restrict__ Alog,   // (512,16)
    const float* __restrict__ Dpv,    // (512)
    bf16* __restrict__ ym)            // (NTOK,512)
{
    __shared__ float smry[256][33];   // [chunk*16+dl][P(16) | h(16)], pad 33

    const int tx = threadIdx.x;
    const int dl = tx & 15;
    const int c  = tx >> 4;           // chunk 0..15
    const int b  = blockIdx.x >> 5;
    const int d  = ((blockIdx.x & 31) << 4) + dl;

    float A2[16];
    {
        const float* Ap = Alog + d * 16;
        #pragma unroll
        for (int s = 0; s < 16; ++s) A2[s] = -expf(Ap[s]) * L2E;   // pre-scaled by log2e
    }
    const float Dv = Dpv[d];
    const size_t nb = (size_t)b * TT;
    const int t0 = c * 32;
    const int t1 = (t0 + 32 < TT) ? (t0 + 32) : TT;

    float h[16];
    float sdt = 0.f;
    #pragma unroll
    for (int s = 0; s < 16; ++s) h[s] = 0.f;

    // pass 1: local scan (h from 0) + dt sum
    for (int t = t0; t < t1; ++t) {
        const size_t n = nb + t;
        const float dtt = dt[n * 512 + d];
        const float xt  = __bfloat162float(xc[n * 512 + d]);
        const float dx  = dtt * xt;
        sdt += dtt;
        const float* Bp = xdbl + n * 128 + 16;
        const float4 b0 = *(const float4*)(Bp);
        const float4 b1 = *(const float4*)(Bp + 4);
        const float4 b2 = *(const float4*)(Bp + 8);
        const float4 b3 = *(const float4*)(Bp + 12);
        const float Bv[16] = {b0.x,b0.y,b0.z,b0.w, b1.x,b1.y,b1.z,b1.w,
                              b2.x,b2.y,b2.z,b2.w, b3.x,b3.y,b3.z,b3.w};
        #pragma unroll
        for (int s = 0; s < 16; ++s) {
            const float e = __builtin_amdgcn_exp2f(dtt * A2[s]);
            h[s] = e * h[s] + dx * Bv[s];
        }
    }
    #pragma unroll
    for (int s = 0; s < 16; ++s) {
        smry[tx][s]      = __builtin_amdgcn_exp2f(A2[s] * sdt);   // chunk decay product
        smry[tx][16 + s] = h[s];
    }
    __syncthreads();

    // prefix combine (oldest chunk first): h_init for this chunk
    #pragma unroll
    for (int s = 0; s < 16; ++s) h[s] = 0.f;
    for (int cc = 0; cc < c; ++cc) {
        const float* S = smry[(cc << 4) + dl];
        #pragma unroll
        for (int s = 0; s < 16; ++s) h[s] = S[s] * h[s] + S[16 + s];
    }

    // pass 2: rescan from h_init, emit ym
    for (int t = t0; t < t1; ++t) {
        const size_t n = nb + t;
        const float dtt = dt[n * 512 + d];
        const float xt  = __bfloat162float(xc[n * 512 + d]);
        const float dx  = dtt * xt;
        const float* Bp = xdbl + n * 128 + 16;
        const float4 b0 = *(const float4*)(Bp);
        const float4 b1 = *(const float4*)(Bp + 4);
        const float4 b2 = *(const float4*)(Bp + 8);
        const float4 b3 = *(const float4*)(Bp + 12);
        const float4 c0 = *(const float4*)(Bp + 16);
        const float4 c1 = *(const float4*)(Bp + 20);
        const float4 c2 = *(const float4*)(Bp + 24);
        const float4 c3 = *(const float4*)(Bp + 28);
        const float Bv[16] = {b0.x,b0.y,b0.z,b0.w, b1.x,b1.y,b1.z,b1.w,
                              b2.x,b2.y,b2.z,b2.w, b3.x,b3.y,b3.z,b3.w};
        const float Cv[16] = {c0.x,c0.y,c0.z,c0.w, c1.x,c1.y,c1.z,c1.w,
                              c2.x,c2.y,c2.z,c2.w, c3.x,c3.y,c3.z,c3.w};
        float y = 0.f;
        #pragma unroll
        for (int s = 0; s < 16; ++s) {
            const float e = __builtin_amdgcn_exp2f(dtt * A2[s]);
            h[s] = e * h[s] + dx * Bv[s];
            y += h[s] * Cv[s];
        }
        const float zz = __bfloat162float(xz[n * 1024 + 512 + d]);
        const float v = (y + xt * Dv) * (zz / (1.f + fexp(-zz)));
        ym[n * 512 + d] = __float2bfloat16(v);
    }
}

// ---------------------------------------------------------------- rmsnorm(a+b)*w  (bf16 io, fp32 math)
__global__ __launch_bounds__(256) void rmsnorm_kernel(
    const bf16* __restrict__ a, const bf16* __restrict__ b,
    const float* __restrict__ w, bf16* __restrict__ out,
    bf16* __restrict__ out768)
{
    __shared__ float red[256];
    int n = blockIdx.x, j = threadIdx.x;
    float v = __bfloat162float(a[(size_t)n * 256 + j]) + __bfloat162float(b[(size_t)n * 256 + j]);
    red[j] = v * v;
    __syncthreads();
    for (int s = 128; s > 0; s >>= 1) { if (j < s) red[j] += red[j + s]; __syncthreads(); }
    float scale = rsqrtf(red[0] / 256.0f + 1e-12f);
    bf16 r = __float2bfloat16(v * scale * w[j]);
    out[(size_t)n * 256 + j] = r;
    if (out768) out768[(size_t)n * 768 + j] = r;
}

// ---------------------------------------------------------------- MFMA dual flash attention
__global__ __launch_bounds__(256) void attn_kernel(
    const bf16* __restrict__ y,    // (B,TT,256) q = k
    const bf16* __restrict__ st,   // v1
    const bf16* __restrict__ sf,   // v2
    bf16* __restrict__ ycin)       // (B,TT,768), writes cols 256..767
{
    __shared__ short Ks[64 * 40];      // K[key][d], row stride 40 shorts (80B)
    __shared__ short Vt[2][32 * 88];   // V^T[d][key], row stride 88 shorts (176B)
    __shared__ short Pl[64 * 88];      // P[q][key] bf16, row stride 88 shorts

    const int bid = blockIdx.x;        // ((b*8)+h)*8 + qt
    const int qt = bid & 7;
    const int h  = (bid >> 3) & 7;
    const int b  = bid >> 6;
    const int tx = threadIdx.x;
    const int w  = tx >> 6;            // wave 0..3
    const int lane = tx & 63;
    const int g  = lane >> 4;          // 0..3
    const int l15 = lane & 15;
    const int q0 = qt * 64;
    const int qg = q0 + w * 16 + l15;  // this lane's q row (S^T col)
    const float scale = 0.17677669529663687f;   // 1/sqrt(32)

    const bf16* ybase  = y  + (size_t)(b * TT) * 256 + h * 32;
    const bf16* v1base = st + (size_t)(b * TT) * 256 + h * 32;
    const bf16* v2base = sf + (size_t)(b * TT) * 256 + h * 32;

    // Q fragment (B operand): col=q=lane&15, k-slice d=(lane>>4)*8..+7
    short8 qf = {};
    if (qg < TT) qf = *(const short8*)(ybase + (size_t)qg * 256 + g * 8);

    float m = -INFINITY, l = 0.f;
    f32x4 o[2][2];                     // [v][dsub]
    #pragma unroll
    for (int v = 0; v < 2; ++v) { o[v][0] = (f32x4){0,0,0,0}; o[v][1] = (f32x4){0,0,0,0}; }

    const int sr = tx >> 2;            // staging key row 0..63
    const int sc = (tx & 3) * 8;       // staging d base

    const int nkt = (qt == 0) ? 8 : (qt + 1);
    for (int kt = 0; kt < nkt; ++kt) {
        const int k0 = kt * 64;
        __syncthreads();               // previous tile's LDS reads done
        {
            int kgr = k0 + sr;
            short8 kv = {}, v1v = {}, v2v = {};
            if (kgr < TT) {
                kv  = *(const short8*)(ybase  + (size_t)kgr * 256 + sc);
                v1v = *(const short8*)(v1base + (size_t)kgr * 256 + sc);
                v2v = *(const short8*)(v2base + (size_t)kgr * 256 + sc);
            }
            *(short8*)&Ks[sr * 40 + sc] = kv;
            #pragma unroll
            for (int i = 0; i < 8; ++i) {
                Vt[0][(sc + i) * 88 + sr] = v1v[i];
                Vt[1][(sc + i) * 88 + sr] = v2v[i];
            }
        }
        __syncthreads();

        // S^T[key][q]: 4 mfmas, each 16 keys x 16 q, K=32 (full head dim)
        f32x4 s[4];
        #pragma unroll
        for (int jm = 0; jm < 4; ++jm) {
            short8 kf = *(const short8*)&Ks[(jm * 16 + l15) * 40 + g * 8];
            s[jm] = __builtin_amdgcn_mfma_f32_16x16x32_bf16(kf, qf, (f32x4){0,0,0,0}, 0, 0, 0);
        }
        // mask + tile max (per lane: all 16 values are q=qg)
        float tm = -INFINITY;
        #pragma unroll
        for (int jm = 0; jm < 4; ++jm)
            #pragma unroll
            for (int r = 0; r < 4; ++r) {
                int kk = k0 + jm * 16 + g * 4 + r;
                float sv = s[jm][r];
                sv = (kk < qg) ? sv * scale : ((kk < TT) ? -1e9f : -INFINITY);
                s[jm][r] = sv;
                tm = fmaxf(tm, sv);
            }
        tm = fmaxf(tm, __shfl_xor(tm, 16));
        tm = fmaxf(tm, __shfl_xor(tm, 32));
        float mn = fmaxf(m, tm);
        float rs = fexp(m - mn);       // m==-inf -> 0
        m = mn;
        float ts = 0.f;
        #pragma unroll
        for (int jm = 0; jm < 4; ++jm)
            #pragma unroll
            for (int r = 0; r < 4; ++r) {
                float e = fexp(s[jm][r] - mn);
                s[jm][r] = e;
                ts += e;
            }
        ts += __shfl_xor(ts, 16);
        ts += __shfl_xor(ts, 32);
        l = l * rs + ts;
        // P -> LDS as bf16 (u32 pair writes; row q, key 16*jm+4*g+{0..3})
        #pragma unroll
        for (int jm = 0; jm < 4; ++jm) {
            *(unsigned*)&Pl[(w * 16 + l15) * 88 + jm * 16 + g * 4]     = pack_bf2(s[jm][0], s[jm][1]);
            *(unsigned*)&Pl[(w * 16 + l15) * 88 + jm * 16 + g * 4 + 2] = pack_bf2(s[jm][2], s[jm][3]);
        }
        // rescale O accs: O row = 4*g+reg -> factor lives in lane (q row)
        float rq[4];
        #pragma unroll
        for (int r = 0; r < 4; ++r) rq[r] = __shfl(rs, 4 * g + r);
        #pragma unroll
        for (int v = 0; v < 2; ++v)
            #pragma unroll
            for (int d = 0; d < 2; ++d)
                #pragma unroll
                for (int r = 0; r < 4; ++r)
                    o[v][d][r] *= rq[r];
        // PV: A = P (row=q=lane&15, k=keys), B = Vt (col=d=lane&15, k=keys)
        #pragma unroll
        for (int ks = 0; ks < 2; ++ks) {
            short8 pf = *(const short8*)&Pl[(w * 16 + l15) * 88 + ks * 32 + g * 8];
            #pragma unroll
            for (int v = 0; v < 2; ++v)
                #pragma unroll
                for (int d = 0; d < 2; ++d) {
                    short8 vf = *(const short8*)&Vt[v][(d * 16 + l15) * 88 + ks * 32 + g * 8];
                    o[v][d] = __builtin_amdgcn_mfma_f32_16x16x32_bf16(pf, vf, o[v][d], 0, 0, 0);
                }
        }
    }

    // epilogue: O row = q0+w*16+4*g+r, col d = lane&15
    float invl = 1.0f / l;             // per q = lane&15
    float iq[4];
    #pragma unroll
    for (int r = 0; r < 4; ++r) iq[r] = __shfl(invl, 4 * g + r);
    #pragma unroll
    for (int r = 0; r < 4; ++r) {
        int rowq = q0 + w * 16 + 4 * g + r;
        if (rowq >= TT) continue;
        bf16* dst = ycin + (size_t)(b * TT + rowq) * 768 + 256;
        #pragma unroll
        for (int v = 0; v < 2; ++v)
            #pragma unroll
            for (int d = 0; d < 2; ++d)
                dst[v * 256 + h * 32 + d * 16 + l15] = __float2bfloat16(o[v][d][r] * iq[r]);
    }
}

// ---------------------------------------------------------------- gathered logit + sigmoid
__global__ __launch_bounds__(256) void pred_kernel(
    const float* __restrict__ yc,     // (NTOK,256)
    const int* __restrict__ skills,
    const float* __restrict__ outW,   // (500,256)
    const float* __restrict__ outB,   // (500)
    float* __restrict__ out)          // (NTOK)
{
    int n = blockIdx.x * 4 + (threadIdx.x >> 6);
    if (n >= NTOK) return;
    int lane = threadIdx.x & 63;
    int b = n / TT, t = n % TT;
    int c = skills[b * SEQL + t + 1];            // cshft
    const float* wrow = outW + (size_t)c * 256;
    const float* xrow = yc + (size_t)n * 256;
    float s = 0.f;
    for (int j = lane; j < 256; j += 64) s += xrow[j] * wrow[j];
    #pragma unroll
    for (int off = 32; off > 0; off >>= 1) s += __shfl_down(s, off);
    if (lane == 0) out[n] = 1.0f / (1.0f + fexp(-(s + outB[c])));
}

// ---------------------------------------------------------------- host
static inline void gemmb(const bf16* A, int lda, const bf16* W, const float* bias,
                         bf16* C, int ldc, int M, int N, int K, int act, hipStream_t s)
{
    dim3 g((M + 127) / 128, N / 128), b(256);   // grid: (rowPanels, colPanels) for XCD L2 locality
    switch (act) {
        case 0: gemm_mfma<0, bf16><<<g, b, 0, s>>>(A, lda, W, bias, C, ldc, M, N, K); break;
        case 1: gemm_mfma<1, bf16><<<g, b, 0, s>>>(A, lda, W, bias, C, ldc, M, N, K); break;
        case 3: gemm_mfma<3, bf16><<<g, b, 0, s>>>(A, lda, W, bias, C, ldc, M, N, K); break;
    }
}

extern "C" void kernel_launch(void* const* d_in, const int* in_sizes, int n_in,
                              void* d_out, int out_size, void* d_ws, size_t ws_size,
                              hipStream_t stream)
{
    const int*   skills    = (const int*)d_in[0];
    const int*   responses = (const int*)d_in[2];
    const float* embC  = (const float*)d_in[3];
    const float* embA  = (const float*)d_in[4];
    const float* embT  = (const float*)d_in[5];
    const float* embF  = (const float*)d_in[6];
    const float* mlpW1 = (const float*)d_in[9];
    const float* mlpb1 = (const float*)d_in[10];
    const float* mlpW2 = (const float*)d_in[11];
    const float* mlpb2 = (const float*)d_in[12];
    const float* inW   = (const float*)d_in[13];
    const float* convW = (const float*)d_in[14];
    const float* convb = (const float*)d_in[15];
    const float* xpW   = (const float*)d_in[16];
    const float* dtW   = (const float*)d_in[17];
    const float* dtb   = (const float*)d_in[18];
    const float* Alog  = (const float*)d_in[19];
    const float* Dp    = (const float*)d_in[20];
    const float* opW   = (const float*)d_in[21];
    const float* mnw   = (const float*)d_in[22];
    const float* fW1   = (const float*)d_in[23];
    const float* fb1   = (const float*)d_in[24];
    const float* fW2   = (const float*)d_in[25];
    const float* fb2   = (const float*)d_in[26];
    const float* fnw   = (const float*)d_in[27];
    const float* finW  = (const float*)d_in[28];
    const float* finb  = (const float*)d_in[29];
    const float* outW  = (const float*)d_in[30];
    const float* outb  = (const float*)d_in[31];

    const size_t NT = NTOK;
    // fp32 region
    float* t1   = (float*)d_ws;          // NT*256 (final gemm out)
    float* dt   = t1 + NT * 256;         // NT*512
    float* xdbl = dt + NT * 512;         // NT*128 (xproj out, padded N=128)
    // bf16 region
    bf16* y    = (bf16*)(xdbl + NT * 128);
    bf16* st   = y    + NT * 256;        // y,st,sf contiguous -> batched MLP
    bf16* sf   = st   + NT * 256;
    bf16* h1   = sf   + NT * 256;
    bf16* thid3 = h1  + NT * 256;        // 3*NT*256: mlp hidden (batched) / per-layer temp
    bf16* bufA = thid3 + 3 * NT * 256;   // NT*1024: xz / ffnmid / ycin(768)
    bf16* xc   = bufA + NT * 1024;       // NT*512
    bf16* ym   = xc   + NT * 512;        // NT*512
    // bf16 weights
    bf16* wMlp1 = ym    + NT * 512;      // 65536
    bf16* wMlp2 = wMlp1 + 65536;         // 65536
    bf16* wIn   = wMlp2 + 65536;         // 2*262144
    bf16* wOp   = wIn   + 2 * 262144;    // 2*131072
    bf16* wF1   = wOp   + 2 * 131072;    // 2*262144
    bf16* wF2   = wF1   + 2 * 262144;    // 2*262144
    bf16* wFin  = wF2   + 2 * 262144;    // 196608
    bf16* wXp   = wFin  + 196608;        // 2*65536 (xproj padded 48->128 rows)

    // 0) weight conversions
    f2bf_kernel<<<(65536 + 255) / 256, 256, 0, stream>>>(mlpW1, wMlp1, 65536);
    f2bf_kernel<<<(65536 + 255) / 256, 256, 0, stream>>>(mlpW2, wMlp2, 65536);
    f2bf_kernel<<<(524288 + 255) / 256, 256, 0, stream>>>(inW, wIn, 524288);
    f2bf_kernel<<<(262144 + 255) / 256, 256, 0, stream>>>(opW, wOp, 262144);
    f2bf_kernel<<<(524288 + 255) / 256, 256, 0, stream>>>(fW1, wF1, 524288);
    f2bf_kernel<<<(524288 + 255) / 256, 256, 0, stream>>>(fW2, wF2, 524288);
    f2bf_kernel<<<(196608 + 255) / 256, 256, 0, stream>>>(finW, wFin, 196608);
    f2bf_pad_kernel<<<(65536 + 255) / 256, 256, 0, stream>>>(xpW, wXp, 48, 128, 512);
    f2bf_pad_kernel<<<(65536 + 255) / 256, 256, 0, stream>>>(xpW + 48 * 512, wXp + 65536, 48, 128, 512);

    // 1) embeddings
    embed_kernel<<<NTOK, 256, 0, stream>>>(skills, responses, embC, embA, embT, embF, y, st, sf);

    // 2) three MLPs batched: y,st,sf contiguous -> M = 3*NTOK
    gemmb(y, 256, wMlp1, mlpb1, thid3, 256, 3 * NTOK, 256, 256, 1, stream);
    gemmb(thid3, 256, wMlp2, mlpb2, y, 256, 3 * NTOK, 256, 256, 0, stream);

    // 3) two mamba layers
    for (int i = 0; i < 2; ++i) {
        gemmb(y, 256, wIn + (size_t)i * 262144, nullptr, bufA, 1024, NTOK, 1024, 256, 0, stream);
        conv_silu_kernel<<<(NTOK * 512) / 256, 256, 0, stream>>>(bufA, convW + i * 2048, convb + i * 512, xc);
        {   // xproj: MFMA, N padded to 128 (rows 48..127 zero), out fp32 stride 128
            dim3 g((NTOK + 127) / 128, 1);
            gemm_mfma<0, float><<<g, 256, 0, stream>>>(xc, 512, wXp + (size_t)i * 65536, nullptr, xdbl, 128, NTOK, 128, 512);
        }
        {   // dtproj: K=16, VALU path, fp32 A (lda=128), softplus
            dim3 g((512 + 63) / 64, (NTOK + 63) / 64);
            gemm_kernel<2><<<g, 256, 0, stream>>>(xdbl, 128, dtW + (size_t)i * 512 * 16, dtb + i * 512, dt, 512, NTOK, 512, 16);
        }
        scan_kernel<<<BATCH * 32, 256, 0, stream>>>(dt, xc, xdbl, bufA, Alog + i * 8192, Dp + i * 512, ym);
        gemmb(ym, 512, wOp + (size_t)i * 131072, nullptr, thid3, 256, NTOK, 256, 512, 0, stream);
        rmsnorm_kernel<<<NTOK, 256, 0, stream>>>(thid3, y, mnw + i * 256, h1, nullptr);
        gemmb(h1, 256, wF1 + (size_t)i * 262144, fb1 + i * 1024, bufA, 1024, NTOK, 1024, 256, 3, stream);
        gemmb(bufA, 1024, wF2 + (size_t)i * 262144, fb2 + i * 256, thid3, 256, NTOK, 256, 1024, 0, stream);
        // final layer's rmsnorm also writes ycin cols 0..255 (replaces copy kernel)
        rmsnorm_kernel<<<NTOK, 256, 0, stream>>>(thid3, h1, fnw + i * 256, y, (i == 1) ? bufA : nullptr);
    }

    // 4) dual attention into ycin = bufA (stride 768)
    attn_kernel<<<BATCH * 8 * 8, 256, 0, stream>>>(y, st, sf, bufA);

    // 5) final projection + gathered sigmoid
    {
        dim3 g((NTOK + 127) / 128, 2);
        gemm_mfma<0, float><<<g, 256, 0, stream>>>(bufA, 768, wFin, finb, t1, 256, NTOK, 256, 768);
    }
    pred_kernel<<<NTOK / 4, 256, 0, stream>>>(t1, skills, outW, outb, (float*)d_out);
}